// Round 2
// baseline (4538.055 us; speedup 1.0000x reference)
//
#include <hip/hip_runtime.h>
#include <hip/hip_bf16.h>
#include <math.h>

typedef __hip_bfloat16 bf16;

#define NPB   65536   // positions per batch (16*64*64)
#define DIMC  48
#define C2    192
#define HIDC  96
#define TT    16

static __device__ __forceinline__ float b2f(bf16 v) { return __bfloat162float(v); }
static __device__ __forceinline__ bf16  f2b(float v) { return __float2bfloat16(v); }

// ---------------- y = LN(x) over 48 channels, bf16 out ----------------
__global__ __launch_bounds__(256) void k_ln(
    const float* __restrict__ x, const float* __restrict__ lw, const float* __restrict__ lb,
    bf16* __restrict__ y) {
  int p = blockIdx.x * 256 + threadIdx.x;   // 0..131071
  int b = p >> 16, n = p & (NPB - 1);
  const float* xb = x + ((size_t)b * DIMC) * NPB + n;
  float v[DIMC]; float s = 0.f, s2 = 0.f;
#pragma unroll
  for (int c = 0; c < DIMC; ++c) { float t = xb[(size_t)c * NPB]; v[c] = t; s += t; s2 += t * t; }
  float mu = s * (1.f / DIMC);
  float var = fmaxf(s2 * (1.f / DIMC) - mu * mu, 0.f);
  float rs = rsqrtf(var + 1e-5f);
  bf16* yb = y + ((size_t)b * DIMC) * NPB + n;
#pragma unroll
  for (int c = 0; c < DIMC; ++c) yb[(size_t)c * NPB] = f2b((v[c] - mu) * rs * lw[c] + lb[c]);
}

// ---------------- 1x1 conv 48->48 (one head-section), bf16 in/out -----
__global__ __launch_bounds__(256) void k_pconv48(
    const bf16* __restrict__ y, const float* __restrict__ pw, const float* __restrict__ pb,
    bf16* __restrict__ dst) {
  int p = blockIdx.x * 256 + threadIdx.x;
  int b = p >> 16, n = p & (NPB - 1);
  const bf16* yb = y + ((size_t)b * DIMC) * NPB + n;
  float v[DIMC];
#pragma unroll
  for (int c = 0; c < DIMC; ++c) v[c] = b2f(yb[(size_t)c * NPB]);
  bf16* ob = dst + ((size_t)b * DIMC) * NPB + n;
#pragma unroll 1
  for (int o = 0; o < DIMC; o += 4) {
    float a0 = pb[o], a1 = pb[o + 1], a2 = pb[o + 2], a3 = pb[o + 3];
    const float* w0 = pw + (size_t)o * DIMC;
#pragma unroll
    for (int c = 0; c < DIMC; ++c) {
      float vc = v[c];
      a0 = fmaf(w0[c], vc, a0);
      a1 = fmaf(w0[DIMC + c], vc, a1);
      a2 = fmaf(w0[2 * DIMC + c], vc, a2);
      a3 = fmaf(w0[3 * DIMC + c], vc, a3);
    }
    ob[(size_t)o * NPB] = f2b(a0);
    ob[(size_t)(o + 1) * NPB] = f2b(a1);
    ob[(size_t)(o + 2) * NPB] = f2b(a2);
    ob[(size_t)(o + 3) * NPB] = f2b(a3);
  }
}

// ------- grouped 3x3x3 conv on a 48-ch section (groups of 4), + optional sumsq ----
__global__ __launch_bounds__(256) void k_gconv48(
    const bf16* __restrict__ src, const float* __restrict__ gw, const float* __restrict__ gb,
    bf16* __restrict__ dst, float* __restrict__ sqout) {
  __shared__ float red[4];
  int n = blockIdx.x * 256 + threadIdx.x;   // t uniform per block
  int c = blockIdx.y, b = blockIdx.z;
  int t = n >> 12, h = (n >> 6) & 63, w = n & 63;
  const float* wt = gw + (size_t)c * 108;   // [ci 0..3][27 taps]
  const bf16* ib = src + ((size_t)b * DIMC + (c & ~3)) * NPB;
  float acc = gb[c];
#pragma unroll
  for (int dt = 0; dt < 3; ++dt) {
    int tt = t + dt - 1;
    if (tt < 0 || tt >= TT) continue;       // uniform per block
#pragma unroll
    for (int dh = 0; dh < 3; ++dh) {
      int hh = h + dh - 1; bool hv = ((unsigned)hh < 64u);
#pragma unroll
      for (int dw = 0; dw < 3; ++dw) {
        int ww = w + dw - 1; bool ok = hv && ((unsigned)ww < 64u);
        int off = tt * 4096 + hh * 64 + ww;
        int wi = dt * 9 + dh * 3 + dw;
#pragma unroll
        for (int ci = 0; ci < 4; ++ci) {
          float xv = ok ? b2f(ib[(size_t)ci * NPB + off]) : 0.f;
          acc = fmaf(wt[ci * 27 + wi], xv, acc);
        }
      }
    }
  }
  bf16 r = f2b(acc);
  dst[((size_t)b * DIMC + c) * NPB + n] = r;
  if (sqout) {   // uniform branch (kernel arg)
    float fv = b2f(r);
    float s = fv * fv;
#pragma unroll
    for (int o = 32; o; o >>= 1) s += __shfl_down(s, o);
    if ((threadIdx.x & 63) == 0) red[threadIdx.x >> 6] = s;
    __syncthreads();
    if (threadIdx.x == 0)
      atomicAdd(&sqout[(size_t)b * 192 + c], red[0] + red[1] + red[2] + red[3]);
  }
}

// ------- Gram for one head: G[b*4+hd][c][d] += sum_n q[c,n]*k[d,n] ----------------
#define DOT4(A, Q, K) \
  A = fmaf(Q.x, K.x, A); A = fmaf(Q.y, K.y, A); A = fmaf(Q.z, K.z, A); A = fmaf(Q.w, K.w, A);
__global__ __launch_bounds__(256) void k_gram48(
    const bf16* __restrict__ qd, const bf16* __restrict__ kd, int hd, float* __restrict__ Gm) {
  __shared__ float ql[DIMC][132];
  __shared__ float kl[DIMC][132];
  int tid = threadIdx.x;
  int b = blockIdx.y;
  int n0 = blockIdx.x * 512;                // 128 chunks of 512 positions
  const bf16* qb = qd + ((size_t)b * DIMC) * NPB + n0;
  const bf16* kb = kd + ((size_t)b * DIMC) * NPB + n0;
  int cb = (tid >> 4) * 3, db = (tid & 15) * 3;  // 16x16 grid of 3x3 tiles
  float acc[3][3] = {{0.f,0.f,0.f},{0.f,0.f,0.f},{0.f,0.f,0.f}};
  for (int s = 0; s < 4; ++s) {
    __syncthreads();
#pragma unroll
    for (int j = 0; j < 24; ++j) {          // 48*128/256
      int idx = j * 256 + tid;
      int c = idx >> 7, nn = idx & 127;
      ql[c][nn] = b2f(qb[(size_t)c * NPB + s * 128 + nn]);
      kl[c][nn] = b2f(kb[(size_t)c * NPB + s * 128 + nn]);
    }
    __syncthreads();
#pragma unroll 2
    for (int nn = 0; nn < 128; nn += 4) {
      float4 q0 = *(const float4*)&ql[cb][nn];
      float4 q1 = *(const float4*)&ql[cb + 1][nn];
      float4 q2 = *(const float4*)&ql[cb + 2][nn];
      float4 k0 = *(const float4*)&kl[db][nn];
      float4 k1 = *(const float4*)&kl[db + 1][nn];
      float4 k2 = *(const float4*)&kl[db + 2][nn];
      DOT4(acc[0][0], q0, k0); DOT4(acc[0][1], q0, k1); DOT4(acc[0][2], q0, k2);
      DOT4(acc[1][0], q1, k0); DOT4(acc[1][1], q1, k1); DOT4(acc[1][2], q1, k2);
      DOT4(acc[2][0], q2, k0); DOT4(acc[2][1], q2, k1); DOT4(acc[2][2], q2, k2);
    }
  }
  float* gbase = Gm + (size_t)(b * 4 + hd) * 2304;
#pragma unroll
  for (int i = 0; i < 3; ++i)
#pragma unroll
    for (int j = 0; j < 3; ++j)
      atomicAdd(&gbase[(cb + i) * 48 + (db + j)], acc[i][j]);
}

// ------- normalize G, temperature, softmax, fold proj_w -> M[b][48][192] ----------
__global__ __launch_bounds__(256) void k_attn_mat(
    const float* __restrict__ Gm, const float* __restrict__ sq, const float* __restrict__ temp,
    const float* __restrict__ pw, float* __restrict__ Mm) {
  __shared__ float A[48][48];
  __shared__ float nq[48], nk[48];
  int tid = threadIdx.x;
  for (int bh = 0; bh < 8; ++bh) {
    int b = bh >> 2, hd = bh & 3;
    if (tid < 48) nq[tid] = fmaxf(sqrtf(sq[bh * 48 + tid]), 1e-12f);
    else if (tid < 96) nk[tid - 48] = fmaxf(sqrtf(sq[384 + bh * 48 + tid - 48]), 1e-12f);
    __syncthreads();
    if (tid < 48) {
      float tv = temp[hd];
      float row[48]; float mx = -1e30f;
      float rq = 1.f / nq[tid];
#pragma unroll
      for (int d = 0; d < 48; ++d) {
        float sv = Gm[(size_t)bh * 2304 + tid * 48 + d] * rq / nk[d] * tv;
        row[d] = sv; mx = fmaxf(mx, sv);
      }
      float sum = 0.f;
#pragma unroll
      for (int d = 0; d < 48; ++d) { row[d] = expf(row[d] - mx); sum += row[d]; }
      float inv = 1.f / sum;
#pragma unroll
      for (int d = 0; d < 48; ++d) A[tid][d] = row[d] * inv;
    }
    __syncthreads();
    for (int j = tid; j < 2304; j += 256) {
      int co = j / 48, d = j - co * 48;
      float a = 0.f;
#pragma unroll
      for (int c = 0; c < 48; ++c) a = fmaf(pw[co * 192 + hd * 48 + c], A[c][d], a);
      Mm[((size_t)b * 48 + co) * 192 + hd * 48 + d] = a;
    }
    __syncthreads();
  }
}

// ---------------- x1 = x + proj_b ------------------------------------------------
__global__ __launch_bounds__(256) void k_x1_init(
    const float* __restrict__ x, const float* __restrict__ pb, float* __restrict__ x1) {
  int p = blockIdx.x * 256 + threadIdx.x;
  int b = p >> 16, n = p & (NPB - 1);
  size_t base = ((size_t)b * DIMC) * NPB + n;
#pragma unroll
  for (int co = 0; co < DIMC; ++co)
    x1[base + (size_t)co * NPB] = x[base + (size_t)co * NPB] + pb[co];
}

// ---------------- x1 += M_h @ v_h ------------------------------------------------
__global__ __launch_bounds__(256) void k_av48(
    const bf16* __restrict__ vd, const float* __restrict__ Mm, int hd, float* __restrict__ x1) {
  __shared__ float Ml[DIMC][DIMC];
  int p = blockIdx.x * 256 + threadIdx.x;
  int b = p >> 16, n = p & (NPB - 1);
  int bb = (blockIdx.x * 256) >> 16;  // block-uniform batch
  for (int j = threadIdx.x; j < 2304; j += 256) {
    int co = j / 48, d = j - co * 48;
    Ml[co][d] = Mm[((size_t)bb * DIMC + co) * 192 + hd * 48 + d];
  }
  __syncthreads();
  const bf16* vb = vd + ((size_t)b * DIMC) * NPB + n;
  float acc[DIMC];
#pragma unroll
  for (int co = 0; co < DIMC; ++co) acc[co] = 0.f;
#pragma unroll 4
  for (int d = 0; d < DIMC; ++d) {
    float vv = b2f(vb[(size_t)d * NPB]);
#pragma unroll
    for (int co = 0; co < DIMC; ++co) acc[co] = fmaf(Ml[co][d], vv, acc[co]);
  }
  size_t base = ((size_t)b * DIMC) * NPB + n;
#pragma unroll
  for (int co = 0; co < DIMC; ++co) x1[base + (size_t)co * NPB] += acc[co];
}

// ---------------- LN over 48 ch + 1x1 conv 48->192 (FFN pin), bf16 out -----------
__global__ __launch_bounds__(256) void k_ln_pconv192(
    const float* __restrict__ x, const float* __restrict__ lw, const float* __restrict__ lb,
    const float* __restrict__ pw, const float* __restrict__ pb, bf16* __restrict__ out) {
  int p = blockIdx.x * 256 + threadIdx.x;
  int b = p >> 16, n = p & (NPB - 1);
  const float* xb = x + ((size_t)b * DIMC) * NPB + n;
  float v[DIMC]; float s = 0.f, s2 = 0.f;
#pragma unroll
  for (int c = 0; c < DIMC; ++c) { float t = xb[(size_t)c * NPB]; v[c] = t; s += t; s2 += t * t; }
  float mu = s * (1.f / DIMC);
  float var = fmaxf(s2 * (1.f / DIMC) - mu * mu, 0.f);
  float rs = rsqrtf(var + 1e-5f);
#pragma unroll
  for (int c = 0; c < DIMC; ++c) v[c] = (v[c] - mu) * rs * lw[c] + lb[c];
  bf16* ob = out + ((size_t)b * C2) * NPB + n;
#pragma unroll 1
  for (int o = 0; o < C2; o += 4) {
    float a0 = pb[o], a1 = pb[o + 1], a2 = pb[o + 2], a3 = pb[o + 3];
    const float* w0 = pw + (size_t)o * DIMC;
#pragma unroll
    for (int c = 0; c < DIMC; ++c) {
      float vc = v[c];
      a0 = fmaf(w0[c], vc, a0);
      a1 = fmaf(w0[DIMC + c], vc, a1);
      a2 = fmaf(w0[2 * DIMC + c], vc, a2);
      a3 = fmaf(w0[3 * DIMC + c], vc, a3);
    }
    ob[(size_t)o * NPB] = f2b(a0);
    ob[(size_t)(o + 1) * NPB] = f2b(a1);
    ob[(size_t)(o + 2) * NPB] = f2b(a2);
    ob[(size_t)(o + 3) * NPB] = f2b(a3);
  }
}

// ---------------- depthwise 3x3x3 conv (192 ch) + exact GELU gate -----------------
__global__ __launch_bounds__(256) void k_dw_gelu(
    const bf16* __restrict__ z, const float* __restrict__ dwW, const float* __restrict__ dwB,
    bf16* __restrict__ g) {
  int n = blockIdx.x * 256 + threadIdx.x;
  int c = blockIdx.y, b = blockIdx.z;
  int t = n >> 12, h = (n >> 6) & 63, w = n & 63;
  const bf16* z1 = z + ((size_t)b * C2 + c) * NPB;
  const bf16* z2 = z + ((size_t)b * C2 + c + HIDC) * NPB;
  const float* w1 = dwW + (size_t)c * 27;
  const float* w2 = dwW + (size_t)(c + HIDC) * 27;
  float a1 = dwB[c], a2 = dwB[c + HIDC];
#pragma unroll
  for (int dt = 0; dt < 3; ++dt) {
    int tt = t + dt - 1;
    if (tt < 0 || tt >= TT) continue;
#pragma unroll
    for (int dh = 0; dh < 3; ++dh) {
      int hh = h + dh - 1; bool hv = ((unsigned)hh < 64u);
#pragma unroll
      for (int dw = 0; dw < 3; ++dw) {
        int ww = w + dw - 1; bool ok = hv && ((unsigned)ww < 64u);
        int off = tt * 4096 + hh * 64 + ww;
        int wi = dt * 9 + dh * 3 + dw;
        float v1 = ok ? b2f(z1[off]) : 0.f;
        float v2 = ok ? b2f(z2[off]) : 0.f;
        a1 = fmaf(w1[wi], v1, a1);
        a2 = fmaf(w2[wi], v2, a2);
      }
    }
  }
  float ge = 0.5f * a1 * (1.f + erff(a1 * 0.70710678118654752f));
  g[((size_t)b * HIDC + c) * NPB + n] = f2b(ge * a2);
}

// ---------------- out = x1 + pout_b + pout_w @ g  (x1 may alias out) --------------
__global__ __launch_bounds__(256) void k_pout(
    const bf16* __restrict__ g, const float* __restrict__ pw, const float* __restrict__ pb,
    const float* __restrict__ x1, float* __restrict__ out) {
  __shared__ float wl[DIMC * HIDC];
  for (int j = threadIdx.x; j < DIMC * HIDC; j += 256) wl[j] = pw[j];
  __syncthreads();
  int p = blockIdx.x * 256 + threadIdx.x;
  int b = p >> 16, n = p & (NPB - 1);
  const bf16* gb_ = g + ((size_t)b * HIDC) * NPB + n;
  float acc[DIMC];
#pragma unroll
  for (int co = 0; co < DIMC; ++co) acc[co] = 0.f;
#pragma unroll 2
  for (int c = 0; c < HIDC; ++c) {
    float gv = b2f(gb_[(size_t)c * NPB]);
#pragma unroll
    for (int co = 0; co < DIMC; ++co) acc[co] = fmaf(wl[co * HIDC + c], gv, acc[co]);
  }
  size_t base = ((size_t)b * DIMC) * NPB + n;
#pragma unroll
  for (int co = 0; co < DIMC; ++co)
    out[base + (size_t)co * NPB] = x1[base + (size_t)co * NPB] + pb[co] + acc[co];
}

extern "C" void kernel_launch(void* const* d_in, const int* in_sizes, int n_in,
                              void* d_out, int out_size, void* d_ws, size_t ws_size,
                              hipStream_t stream) {
  (void)in_sizes; (void)n_in; (void)out_size; (void)ws_size;
  const float* x     = (const float*)d_in[0];
  const float* ln1w  = (const float*)d_in[1];
  const float* ln1b  = (const float*)d_in[2];
  const float* qkvw  = (const float*)d_in[3];
  const float* qkvb  = (const float*)d_in[4];
  const float* gdww  = (const float*)d_in[5];
  const float* gdwb  = (const float*)d_in[6];
  const float* temp  = (const float*)d_in[7];
  const float* projw = (const float*)d_in[8];
  const float* projb = (const float*)d_in[9];
  const float* ln2w  = (const float*)d_in[10];
  const float* ln2b  = (const float*)d_in[11];
  const float* pinw  = (const float*)d_in[12];
  const float* pinb  = (const float*)d_in[13];
  const float* dww   = (const float*)d_in[14];
  const float* dwb   = (const float*)d_in[15];
  const float* poutw = (const float*)d_in[16];
  const float* poutb = (const float*)d_in[17];
  float* out = (float*)d_out;

  // Workspace layout — peak requirement 75,694,080 B (~72.2 MiB):
  char* ws = (char*)d_ws;
  bf16*  y     = (bf16*)(ws);              // 12,582,912 B  [2][48][65536] bf16
  bf16*  stage = (bf16*)(ws + 12582912);   // 12,582,912 B
  bf16*  qd    = (bf16*)(ws + 25165824);   // 12,582,912 B
  bf16*  kvd   = (bf16*)(ws + 37748736);   // 12,582,912 B  (kd, later vd)
  float* Gm    = (float*)(ws + 50331648);  //     73,728 B  [8][48][48]
  float* sq    = (float*)(ws + 50405376);  //      3,072 B  [qk][b][h][c]
  float* Mm    = (float*)(ws + 50411520);  //     73,728 B  [2][48][192]
  bf16*  z     = (bf16*)(ws);              // 50,331,648 B  (FFN; attn bufs dead)
  bf16*  gg    = (bf16*)(ws + 50528256);   // 25,165,824 B
  float* x1    = (float*)d_out;            // x1 lives in d_out; overwritten by k_pout

  hipMemsetAsync(Gm, 0, 73728 + 3072, stream);
  k_ln<<<dim3(512), dim3(256), 0, stream>>>(x, ln1w, ln1b, y);

  for (int h = 0; h < 4; ++h) {
    int rq = h * 48, rk = 192 + h * 48;
    k_pconv48<<<dim3(512), dim3(256), 0, stream>>>(y, qkvw + (size_t)rq * 48, qkvb + rq, stage);
    k_gconv48<<<dim3(256, 48, 2), dim3(256), 0, stream>>>(stage, gdww + (size_t)rq * 108, gdwb + rq, qd, sq + h * 48);
    k_pconv48<<<dim3(512), dim3(256), 0, stream>>>(y, qkvw + (size_t)rk * 48, qkvb + rk, stage);
    k_gconv48<<<dim3(256, 48, 2), dim3(256), 0, stream>>>(stage, gdww + (size_t)rk * 108, gdwb + rk, kvd, sq + 384 + h * 48);
    k_gram48<<<dim3(128, 2), dim3(256), 0, stream>>>(qd, kvd, h, Gm);
  }
  k_attn_mat<<<dim3(1), dim3(256), 0, stream>>>(Gm, sq, temp, projw, Mm);
  k_x1_init<<<dim3(512), dim3(256), 0, stream>>>(x, projb, x1);
  for (int h = 0; h < 4; ++h) {
    int rv = 384 + h * 48;
    k_pconv48<<<dim3(512), dim3(256), 0, stream>>>(y, qkvw + (size_t)rv * 48, qkvb + rv, stage);
    k_gconv48<<<dim3(256, 48, 2), dim3(256), 0, stream>>>(stage, gdww + (size_t)rv * 108, gdwb + rv, kvd, nullptr);
    k_av48<<<dim3(512), dim3(256), 0, stream>>>(kvd, Mm, h, x1);
  }
  k_ln_pconv192<<<dim3(512), dim3(256), 0, stream>>>(x1, ln2w, ln2b, pinw, pinb, z);
  k_dw_gelu<<<dim3(256, 96, 2), dim3(256), 0, stream>>>(z, dww, dwb, gg);
  k_pout<<<dim3(512), dim3(256), 0, stream>>>(gg, poutw, poutb, x1, out);
}

// Round 3
// 1639.925 us; speedup vs baseline: 2.7672x; 2.7672x over previous
//
#include <hip/hip_runtime.h>
#include <hip/hip_bf16.h>
#include <math.h>

typedef __hip_bfloat16 bf16;

#define NPB   65536   // positions per batch (16*64*64)
#define DIMC  48
#define C2    192
#define HIDC  96
#define TT    16

static __device__ __forceinline__ float b2f(bf16 v) { return __bfloat162float(v); }
static __device__ __forceinline__ bf16  f2b(float v) { return __float2bfloat16(v); }
static __device__ __forceinline__ float bfr2f(unsigned short u) {
  union { unsigned int i; float f; } c; c.i = ((unsigned int)u) << 16; return c.f;
}

// ---------------- y = LN(x) over 48 channels, bf16 out ----------------
__global__ __launch_bounds__(256) void k_ln(
    const float* __restrict__ x, const float* __restrict__ lw, const float* __restrict__ lb,
    bf16* __restrict__ y) {
  int p = blockIdx.x * 256 + threadIdx.x;   // 0..131071
  int b = p >> 16, n = p & (NPB - 1);
  const float* xb = x + ((size_t)b * DIMC) * NPB + n;
  float v[DIMC]; float s = 0.f, s2 = 0.f;
#pragma unroll
  for (int c = 0; c < DIMC; ++c) { float t = xb[(size_t)c * NPB]; v[c] = t; s += t; s2 += t * t; }
  float mu = s * (1.f / DIMC);
  float var = fmaxf(s2 * (1.f / DIMC) - mu * mu, 0.f);
  float rs = rsqrtf(var + 1e-5f);
  bf16* yb = y + ((size_t)b * DIMC) * NPB + n;
#pragma unroll
  for (int c = 0; c < DIMC; ++c) yb[(size_t)c * NPB] = f2b((v[c] - mu) * rs * lw[c] + lb[c]);
}

// ---------------- 1x1 conv 48->48, 2 positions/thread, ushort2 loads --------------
__global__ __launch_bounds__(256) void k_pconv48(
    const bf16* __restrict__ y, const float* __restrict__ pw, const float* __restrict__ pb,
    bf16* __restrict__ dst) {
  int p = blockIdx.x * 256 + threadIdx.x;   // 0..65535 position-pairs
  int b = p >> 15, n = (p & 32767) * 2;
  const unsigned short* yb = (const unsigned short*)(y + ((size_t)b * DIMC) * NPB + n);
  float v0[DIMC], v1[DIMC];
#pragma unroll
  for (int c = 0; c < DIMC; ++c) {
    ushort2 u = *(const ushort2*)(yb + (size_t)c * NPB);
    v0[c] = bfr2f(u.x); v1[c] = bfr2f(u.y);
  }
  unsigned short* ob = (unsigned short*)(dst + ((size_t)b * DIMC) * NPB + n);
#pragma unroll 1
  for (int o = 0; o < DIMC; o += 2) {
    float a00 = pb[o], a01 = pb[o], a10 = pb[o + 1], a11 = pb[o + 1];
    const float* w0 = pw + (size_t)o * DIMC;
#pragma unroll
    for (int c = 0; c < DIMC; ++c) {
      float wa = w0[c], wb_ = w0[DIMC + c];
      a00 = fmaf(wa, v0[c], a00); a01 = fmaf(wa, v1[c], a01);
      a10 = fmaf(wb_, v0[c], a10); a11 = fmaf(wb_, v1[c], a11);
    }
    ushort2 r0, r1;
    r0.x = __bfloat16_as_ushort(f2b(a00)); r0.y = __bfloat16_as_ushort(f2b(a01));
    r1.x = __bfloat16_as_ushort(f2b(a10)); r1.y = __bfloat16_as_ushort(f2b(a11));
    *(ushort2*)(ob + (size_t)o * NPB) = r0;
    *(ushort2*)(ob + (size_t)(o + 1) * NPB) = r1;
  }
}

// ------- grouped 3x3x3 conv, LDS-tiled: block = group(4ch) x tile(2t,16h,64w) -----
// grid (32, 12, 2): x = spatial tile (8 t-tiles * 4 h-tiles), y = group, z = batch
__global__ __launch_bounds__(256) void k_gconv48(
    const bf16* __restrict__ src, const float* __restrict__ gw, const float* __restrict__ gb,
    bf16* __restrict__ dst, float* __restrict__ sqout) {
  __shared__ unsigned short tile[4][4][18][66];   // [ci][t0-1..t0+2][h0-1..h0+16][w -1..64]
  __shared__ float red[4][4];
  int tid = threadIdx.x;
  int t0 = (blockIdx.x >> 2) * 2, h0 = (blockIdx.x & 3) * 16;
  int cbase = blockIdx.y * 4, b = blockIdx.z;
  const unsigned short* ib = (const unsigned short*)(src + ((size_t)b * DIMC + cbase) * NPB);
  // main region: 288 rows (4ci*4tt*18hh) x 16 ushort4 chunks of 64 w
  for (int j = tid; j < 288 * 16; j += 256) {
    int r = j >> 4, sub = j & 15;
    int ci = r / 72, rem = r - ci * 72;
    int tt = rem / 18, hh = rem - tt * 18;
    int gt = t0 + tt - 1, gh = h0 + hh - 1;
    ushort4 val = make_ushort4(0, 0, 0, 0);
    if ((unsigned)gt < 16u && (unsigned)gh < 64u)
      val = *(const ushort4*)(ib + (size_t)ci * NPB + gt * 4096 + gh * 64 + sub * 4);
    unsigned short* dp = &tile[ci][tt][hh][1 + sub * 4];
    dp[0] = val.x; dp[1] = val.y; dp[2] = val.z; dp[3] = val.w;
  }
  // w-halo = image boundary -> zero
  for (int j = tid; j < 576; j += 256) {
    int r = j >> 1, side = j & 1;
    int ci = r / 72, rem = r - ci * 72;
    int tt = rem / 18, hh = rem - tt * 18;
    tile[ci][tt][hh][side ? 65 : 0] = 0;
  }
  __syncthreads();
  int w = tid & 63, hr = tid >> 6;   // hr wave-uniform
  float acc[2][4][4];                // [t][i][och]
#pragma unroll
  for (int t = 0; t < 2; ++t)
#pragma unroll
    for (int i = 0; i < 4; ++i)
#pragma unroll
      for (int o = 0; o < 4; ++o) acc[t][i][o] = 0.f;
#pragma unroll 1
  for (int ci = 0; ci < 4; ++ci) {
#pragma unroll 1
    for (int dw = 0; dw < 3; ++dw) {
      int wwl = w + dw;
      float v[4][6];
#pragma unroll
      for (int tt = 0; tt < 4; ++tt)
#pragma unroll
        for (int r = 0; r < 6; ++r) v[tt][r] = bfr2f(tile[ci][tt][hr * 4 + r][wwl]);
#pragma unroll
      for (int dt = 0; dt < 3; ++dt)
#pragma unroll
        for (int dh = 0; dh < 3; ++dh) {
          float wv[4];
#pragma unroll
          for (int o = 0; o < 4; ++o)
            wv[o] = gw[(size_t)(cbase + o) * 108 + ci * 27 + dt * 9 + dh * 3 + dw];
#pragma unroll
          for (int t = 0; t < 2; ++t)
#pragma unroll
            for (int i = 0; i < 4; ++i) {
              float vv = v[t + dt][i + dh];
#pragma unroll
              for (int o = 0; o < 4; ++o) acc[t][i][o] = fmaf(wv[o], vv, acc[t][i][o]);
            }
        }
    }
  }
  float s[4] = {0.f, 0.f, 0.f, 0.f};
#pragma unroll
  for (int o = 0; o < 4; ++o) {
    float bias = gb[cbase + o];
    size_t obase = ((size_t)b * DIMC + cbase + o) * NPB;
#pragma unroll
    for (int t = 0; t < 2; ++t)
#pragma unroll
      for (int i = 0; i < 4; ++i) {
        bf16 rv = f2b(acc[t][i][o] + bias);
        dst[obase + (t0 + t) * 4096 + (h0 + hr * 4 + i) * 64 + w] = rv;
        float f = b2f(rv);
        s[o] = fmaf(f, f, s[o]);
      }
  }
  if (sqout) {   // uniform branch
#pragma unroll
    for (int o = 0; o < 4; ++o) {
      float sv = s[o];
#pragma unroll
      for (int off = 32; off; off >>= 1) sv += __shfl_down(sv, off);
      if ((tid & 63) == 0) red[tid >> 6][o] = sv;
    }
    __syncthreads();
    if (tid < 4)
      atomicAdd(&sqout[(size_t)b * 192 + cbase + tid],
                red[0][tid] + red[1][tid] + red[2][tid] + red[3][tid]);
  }
}

// ------- Gram for one head: G[b*4+hd][c][d] += sum_n q[c,n]*k[d,n] ----------------
#define DOT4(A, Q, K) \
  A = fmaf(Q.x, K.x, A); A = fmaf(Q.y, K.y, A); A = fmaf(Q.z, K.z, A); A = fmaf(Q.w, K.w, A);
__global__ __launch_bounds__(256) void k_gram48(
    const bf16* __restrict__ qd, const bf16* __restrict__ kd, int hd, float* __restrict__ Gm) {
  __shared__ float ql[DIMC][132];
  __shared__ float kl[DIMC][132];
  int tid = threadIdx.x;
  int b = blockIdx.y;
  int n0 = blockIdx.x * 512;                // 128 chunks of 512 positions
  const bf16* qb = qd + ((size_t)b * DIMC) * NPB + n0;
  const bf16* kb = kd + ((size_t)b * DIMC) * NPB + n0;
  int cb = (tid >> 4) * 3, db = (tid & 15) * 3;  // 16x16 grid of 3x3 tiles
  float acc[3][3] = {{0.f,0.f,0.f},{0.f,0.f,0.f},{0.f,0.f,0.f}};
  for (int s = 0; s < 4; ++s) {
    __syncthreads();
#pragma unroll
    for (int j = 0; j < 24; ++j) {          // 48*128/256
      int idx = j * 256 + tid;
      int c = idx >> 7, nn = idx & 127;
      ql[c][nn] = b2f(qb[(size_t)c * NPB + s * 128 + nn]);
      kl[c][nn] = b2f(kb[(size_t)c * NPB + s * 128 + nn]);
    }
    __syncthreads();
#pragma unroll 2
    for (int nn = 0; nn < 128; nn += 4) {
      float4 q0 = *(const float4*)&ql[cb][nn];
      float4 q1 = *(const float4*)&ql[cb + 1][nn];
      float4 q2 = *(const float4*)&ql[cb + 2][nn];
      float4 k0 = *(const float4*)&kl[db][nn];
      float4 k1 = *(const float4*)&kl[db + 1][nn];
      float4 k2 = *(const float4*)&kl[db + 2][nn];
      DOT4(acc[0][0], q0, k0); DOT4(acc[0][1], q0, k1); DOT4(acc[0][2], q0, k2);
      DOT4(acc[1][0], q1, k0); DOT4(acc[1][1], q1, k1); DOT4(acc[1][2], q1, k2);
      DOT4(acc[2][0], q2, k0); DOT4(acc[2][1], q2, k1); DOT4(acc[2][2], q2, k2);
    }
  }
  float* gbase = Gm + (size_t)(b * 4 + hd) * 2304;
#pragma unroll
  for (int i = 0; i < 3; ++i)
#pragma unroll
    for (int j = 0; j < 3; ++j)
      atomicAdd(&gbase[(cb + i) * 48 + (db + j)], acc[i][j]);
}

// ------- normalize G, temperature, softmax, fold proj_w -> M[b][48][192] ----------
__global__ __launch_bounds__(256) void k_attn_mat(
    const float* __restrict__ Gm, const float* __restrict__ sq, const float* __restrict__ temp,
    const float* __restrict__ pw, float* __restrict__ Mm) {
  __shared__ float A[48][48];
  __shared__ float nq[48], nk[48];
  int tid = threadIdx.x;
  for (int bh = 0; bh < 8; ++bh) {
    int b = bh >> 2, hd = bh & 3;
    if (tid < 48) nq[tid] = fmaxf(sqrtf(sq[bh * 48 + tid]), 1e-12f);
    else if (tid < 96) nk[tid - 48] = fmaxf(sqrtf(sq[384 + bh * 48 + tid - 48]), 1e-12f);
    __syncthreads();
    if (tid < 48) {
      float tv = temp[hd];
      float row[48]; float mx = -1e30f;
      float rq = 1.f / nq[tid];
#pragma unroll
      for (int d = 0; d < 48; ++d) {
        float sv = Gm[(size_t)bh * 2304 + tid * 48 + d] * rq / nk[d] * tv;
        row[d] = sv; mx = fmaxf(mx, sv);
      }
      float sum = 0.f;
#pragma unroll
      for (int d = 0; d < 48; ++d) { row[d] = expf(row[d] - mx); sum += row[d]; }
      float inv = 1.f / sum;
#pragma unroll
      for (int d = 0; d < 48; ++d) A[tid][d] = row[d] * inv;
    }
    __syncthreads();
    for (int j = tid; j < 2304; j += 256) {
      int co = j / 48, d = j - co * 48;
      float a = 0.f;
#pragma unroll
      for (int c = 0; c < 48; ++c) a = fmaf(pw[co * 192 + hd * 48 + c], A[c][d], a);
      Mm[((size_t)b * 48 + co) * 192 + hd * 48 + d] = a;
    }
    __syncthreads();
  }
}

// ---------------- x1 = x + proj_b ------------------------------------------------
__global__ __launch_bounds__(256) void k_x1_init(
    const float* __restrict__ x, const float* __restrict__ pb, float* __restrict__ x1) {
  int p = blockIdx.x * 256 + threadIdx.x;
  int b = p >> 16, n = p & (NPB - 1);
  size_t base = ((size_t)b * DIMC) * NPB + n;
#pragma unroll
  for (int co = 0; co < DIMC; ++co)
    x1[base + (size_t)co * NPB] = x[base + (size_t)co * NPB] + pb[co];
}

// ---------------- x1 += M_h @ v_h ------------------------------------------------
__global__ __launch_bounds__(256) void k_av48(
    const bf16* __restrict__ vd, const float* __restrict__ Mm, int hd, float* __restrict__ x1) {
  __shared__ float Ml[DIMC][DIMC];
  int p = blockIdx.x * 256 + threadIdx.x;
  int b = p >> 16, n = p & (NPB - 1);
  int bb = (blockIdx.x * 256) >> 16;  // block-uniform batch
  for (int j = threadIdx.x; j < 2304; j += 256) {
    int co = j / 48, d = j - co * 48;
    Ml[co][d] = Mm[((size_t)bb * DIMC + co) * 192 + hd * 48 + d];
  }
  __syncthreads();
  const bf16* vb = vd + ((size_t)b * DIMC) * NPB + n;
  float acc[DIMC];
#pragma unroll
  for (int co = 0; co < DIMC; ++co) acc[co] = 0.f;
#pragma unroll 4
  for (int d = 0; d < DIMC; ++d) {
    float vv = b2f(vb[(size_t)d * NPB]);
#pragma unroll
    for (int co = 0; co < DIMC; ++co) acc[co] = fmaf(Ml[co][d], vv, acc[co]);
  }
  size_t base = ((size_t)b * DIMC) * NPB + n;
#pragma unroll
  for (int co = 0; co < DIMC; ++co) x1[base + (size_t)co * NPB] += acc[co];
}

// ---------------- LN over 48 ch + 1x1 conv 48->192 (FFN pin), bf16 out -----------
__global__ __launch_bounds__(256) void k_ln_pconv192(
    const float* __restrict__ x, const float* __restrict__ lw, const float* __restrict__ lb,
    const float* __restrict__ pw, const float* __restrict__ pb, bf16* __restrict__ out) {
  int p = blockIdx.x * 256 + threadIdx.x;
  int b = p >> 16, n = p & (NPB - 1);
  const float* xb = x + ((size_t)b * DIMC) * NPB + n;
  float v[DIMC]; float s = 0.f, s2 = 0.f;
#pragma unroll
  for (int c = 0; c < DIMC; ++c) { float t = xb[(size_t)c * NPB]; v[c] = t; s += t; s2 += t * t; }
  float mu = s * (1.f / DIMC);
  float var = fmaxf(s2 * (1.f / DIMC) - mu * mu, 0.f);
  float rs = rsqrtf(var + 1e-5f);
#pragma unroll
  for (int c = 0; c < DIMC; ++c) v[c] = (v[c] - mu) * rs * lw[c] + lb[c];
  bf16* ob = out + ((size_t)b * C2) * NPB + n;
#pragma unroll 1
  for (int o = 0; o < C2; o += 4) {
    float a0 = pb[o], a1 = pb[o + 1], a2 = pb[o + 2], a3 = pb[o + 3];
    const float* w0 = pw + (size_t)o * DIMC;
#pragma unroll
    for (int c = 0; c < DIMC; ++c) {
      float vc = v[c];
      a0 = fmaf(w0[c], vc, a0);
      a1 = fmaf(w0[DIMC + c], vc, a1);
      a2 = fmaf(w0[2 * DIMC + c], vc, a2);
      a3 = fmaf(w0[3 * DIMC + c], vc, a3);
    }
    ob[(size_t)o * NPB] = f2b(a0);
    ob[(size_t)(o + 1) * NPB] = f2b(a1);
    ob[(size_t)(o + 2) * NPB] = f2b(a2);
    ob[(size_t)(o + 3) * NPB] = f2b(a3);
  }
}

// ------- depthwise 3x3x3 + exact GELU gate, LDS-tiled: block = ch-pair x tile -----
// grid (32, 96, 2): x = spatial tile, y = channel c (pairs with c+96), z = batch
__global__ __launch_bounds__(256) void k_dw_gelu(
    const bf16* __restrict__ z, const float* __restrict__ dwW, const float* __restrict__ dwB,
    bf16* __restrict__ g) {
  __shared__ unsigned short tile[2][4][18][66];
  int tid = threadIdx.x;
  int t0 = (blockIdx.x >> 2) * 2, h0 = (blockIdx.x & 3) * 16;
  int c = blockIdx.y, b = blockIdx.z;
  const unsigned short* z1 = (const unsigned short*)(z + ((size_t)b * C2 + c) * NPB);
  const unsigned short* z2 = (const unsigned short*)(z + ((size_t)b * C2 + c + HIDC) * NPB);
  for (int j = tid; j < 144 * 16; j += 256) {   // 9 iters
    int r = j >> 4, sub = j & 15;
    int ch = r / 72, rem = r - ch * 72;
    int tt = rem / 18, hh = rem - tt * 18;
    int gt = t0 + tt - 1, gh = h0 + hh - 1;
    ushort4 val = make_ushort4(0, 0, 0, 0);
    const unsigned short* sp = ch ? z2 : z1;
    if ((unsigned)gt < 16u && (unsigned)gh < 64u)
      val = *(const ushort4*)(sp + gt * 4096 + gh * 64 + sub * 4);
    unsigned short* dp = &tile[ch][tt][hh][1 + sub * 4];
    dp[0] = val.x; dp[1] = val.y; dp[2] = val.z; dp[3] = val.w;
  }
  for (int j = tid; j < 288; j += 256) {
    int r = j >> 1, side = j & 1;
    int ch = r / 72, rem = r - ch * 72;
    int tt = rem / 18, hh = rem - tt * 18;
    tile[ch][tt][hh][side ? 65 : 0] = 0;
  }
  __syncthreads();
  int w = tid & 63, hr = tid >> 6;
  float a[2][2][4];   // [ch][t][i]
#pragma unroll
  for (int ch = 0; ch < 2; ++ch)
#pragma unroll
    for (int t = 0; t < 2; ++t)
#pragma unroll
      for (int i = 0; i < 4; ++i) a[ch][t][i] = 0.f;
#pragma unroll
  for (int ch = 0; ch < 2; ++ch) {
    const float* wt = dwW + (size_t)(c + ch * HIDC) * 27;
#pragma unroll 1
    for (int dw = 0; dw < 3; ++dw) {
      int wwl = w + dw;
      float v[4][6];
#pragma unroll
      for (int tt = 0; tt < 4; ++tt)
#pragma unroll
        for (int r = 0; r < 6; ++r) v[tt][r] = bfr2f(tile[ch][tt][hr * 4 + r][wwl]);
#pragma unroll
      for (int dt = 0; dt < 3; ++dt)
#pragma unroll
        for (int dh = 0; dh < 3; ++dh) {
          float wv = wt[dt * 9 + dh * 3 + dw];
#pragma unroll
          for (int t = 0; t < 2; ++t)
#pragma unroll
            for (int i = 0; i < 4; ++i)
              a[ch][t][i] = fmaf(wv, v[t + dt][i + dh], a[ch][t][i]);
        }
    }
  }
  float b1 = dwB[c], b2v = dwB[c + HIDC];
  size_t obase = ((size_t)b * HIDC + c) * NPB;
#pragma unroll
  for (int t = 0; t < 2; ++t)
#pragma unroll
    for (int i = 0; i < 4; ++i) {
      float x1v = a[0][t][i] + b1;
      float x2v = a[1][t][i] + b2v;
      float ge = 0.5f * x1v * (1.f + erff(x1v * 0.70710678118654752f));
      g[obase + (t0 + t) * 4096 + (h0 + hr * 4 + i) * 64 + w] = f2b(ge * x2v);
    }
}

// ---------------- out = x1 + pout_b + pout_w @ g  (x1 may alias out) --------------
__global__ __launch_bounds__(256) void k_pout(
    const bf16* __restrict__ g, const float* __restrict__ pw, const float* __restrict__ pb,
    const float* __restrict__ x1, float* __restrict__ out) {
  __shared__ float wl[DIMC * HIDC];
  for (int j = threadIdx.x; j < DIMC * HIDC; j += 256) wl[j] = pw[j];
  __syncthreads();
  int p = blockIdx.x * 256 + threadIdx.x;
  int b = p >> 16, n = p & (NPB - 1);
  const bf16* gb_ = g + ((size_t)b * HIDC) * NPB + n;
  float acc[DIMC];
#pragma unroll
  for (int co = 0; co < DIMC; ++co) acc[co] = 0.f;
#pragma unroll 2
  for (int c = 0; c < HIDC; ++c) {
    float gv = b2f(gb_[(size_t)c * NPB]);
#pragma unroll
    for (int co = 0; co < DIMC; ++co) acc[co] = fmaf(wl[co * HIDC + c], gv, acc[co]);
  }
  size_t base = ((size_t)b * DIMC) * NPB + n;
#pragma unroll
  for (int co = 0; co < DIMC; ++co)
    out[base + (size_t)co * NPB] = x1[base + (size_t)co * NPB] + pb[co] + acc[co];
}

extern "C" void kernel_launch(void* const* d_in, const int* in_sizes, int n_in,
                              void* d_out, int out_size, void* d_ws, size_t ws_size,
                              hipStream_t stream) {
  (void)in_sizes; (void)n_in; (void)out_size; (void)ws_size;
  const float* x     = (const float*)d_in[0];
  const float* ln1w  = (const float*)d_in[1];
  const float* ln1b  = (const float*)d_in[2];
  const float* qkvw  = (const float*)d_in[3];
  const float* qkvb  = (const float*)d_in[4];
  const float* gdww  = (const float*)d_in[5];
  const float* gdwb  = (const float*)d_in[6];
  const float* temp  = (const float*)d_in[7];
  const float* projw = (const float*)d_in[8];
  const float* projb = (const float*)d_in[9];
  const float* ln2w  = (const float*)d_in[10];
  const float* ln2b  = (const float*)d_in[11];
  const float* pinw  = (const float*)d_in[12];
  const float* pinb  = (const float*)d_in[13];
  const float* dww   = (const float*)d_in[14];
  const float* dwb   = (const float*)d_in[15];
  const float* poutw = (const float*)d_in[16];
  const float* poutb = (const float*)d_in[17];
  float* out = (float*)d_out;

  // Workspace layout — peak requirement ~75.7 MB (proven safe in round 2):
  char* ws = (char*)d_ws;
  bf16*  y     = (bf16*)(ws);              // 12,582,912 B
  bf16*  stage = (bf16*)(ws + 12582912);   // 12,582,912 B
  bf16*  qd    = (bf16*)(ws + 25165824);   // 12,582,912 B
  bf16*  kvd   = (bf16*)(ws + 37748736);   // 12,582,912 B
  float* Gm    = (float*)(ws + 50331648);  //     73,728 B
  float* sq    = (float*)(ws + 50405376);  //      3,072 B
  float* Mm    = (float*)(ws + 50411520);  //     73,728 B
  bf16*  z     = (bf16*)(ws);              // 50,331,648 B (FFN reuse)
  bf16*  gg    = (bf16*)(ws + 50528256);   // 25,165,824 B
  float* x1    = (float*)d_out;

  hipMemsetAsync(Gm, 0, 73728 + 3072, stream);
  k_ln<<<dim3(512), dim3(256), 0, stream>>>(x, ln1w, ln1b, y);

  for (int h = 0; h < 4; ++h) {
    int rq = h * 48, rk = 192 + h * 48;
    k_pconv48<<<dim3(256), dim3(256), 0, stream>>>(y, qkvw + (size_t)rq * 48, qkvb + rq, stage);
    k_gconv48<<<dim3(32, 12, 2), dim3(256), 0, stream>>>(stage, gdww + (size_t)rq * 108, gdwb + rq, qd, sq + h * 48);
    k_pconv48<<<dim3(256), dim3(256), 0, stream>>>(y, qkvw + (size_t)rk * 48, qkvb + rk, stage);
    k_gconv48<<<dim3(32, 12, 2), dim3(256), 0, stream>>>(stage, gdww + (size_t)rk * 108, gdwb + rk, kvd, sq + 384 + h * 48);
    k_gram48<<<dim3(128, 2), dim3(256), 0, stream>>>(qd, kvd, h, Gm);
  }
  k_attn_mat<<<dim3(1), dim3(256), 0, stream>>>(Gm, sq, temp, projw, Mm);
  k_x1_init<<<dim3(512), dim3(256), 0, stream>>>(x, projb, x1);
  for (int h = 0; h < 4; ++h) {
    int rv = 384 + h * 48;
    k_pconv48<<<dim3(256), dim3(256), 0, stream>>>(y, qkvw + (size_t)rv * 48, qkvb + rv, stage);
    k_gconv48<<<dim3(32, 12, 2), dim3(256), 0, stream>>>(stage, gdww + (size_t)rv * 108, gdwb + rv, kvd, nullptr);
    k_av48<<<dim3(512), dim3(256), 0, stream>>>(kvd, Mm, h, x1);
  }
  k_ln_pconv192<<<dim3(512), dim3(256), 0, stream>>>(x1, ln2w, ln2b, pinw, pinb, z);
  k_dw_gelu<<<dim3(32, 96, 2), dim3(256), 0, stream>>>(z, dww, dwb, gg);
  k_pout<<<dim3(512), dim3(256), 0, stream>>>(gg, poutw, poutb, x1, out);
}

// Round 4
// 1001.109 us; speedup vs baseline: 4.5330x; 1.6381x over previous
//
#include <hip/hip_runtime.h>
#include <hip/hip_bf16.h>
#include <math.h>

typedef __hip_bfloat16 bf16;
typedef __attribute__((ext_vector_type(8))) short short8;
typedef __attribute__((ext_vector_type(4))) float f32x4;

#define NPB   65536   // positions per batch (16*64*64)
#define DIMC  48
#define C2    192
#define HIDC  96
#define TT    16

static __device__ __forceinline__ float b2f(bf16 v) { return __bfloat162float(v); }
static __device__ __forceinline__ bf16  f2b(float v) { return __float2bfloat16(v); }
static __device__ __forceinline__ float bfr2f(unsigned short u) {
  union { unsigned int i; float f; } c; c.i = ((unsigned int)u) << 16; return c.f;
}
static __device__ __forceinline__ unsigned short f2us(float v) {
  return __bfloat16_as_ushort(__float2bfloat16(v));
}

// ---------------- y = LN(x) over 48 channels, bf16 out (used for LN1 and LN2) ----
__global__ __launch_bounds__(256) void k_ln(
    const float* __restrict__ x, const float* __restrict__ lw, const float* __restrict__ lb,
    bf16* __restrict__ y) {
  int p = blockIdx.x * 256 + threadIdx.x;   // 0..131071
  int b = p >> 16, n = p & (NPB - 1);
  const float* xb = x + ((size_t)b * DIMC) * NPB + n;
  float v[DIMC]; float s = 0.f, s2 = 0.f;
#pragma unroll
  for (int c = 0; c < DIMC; ++c) { float t = xb[(size_t)c * NPB]; v[c] = t; s += t; s2 += t * t; }
  float mu = s * (1.f / DIMC);
  float var = fmaxf(s2 * (1.f / DIMC) - mu * mu, 0.f);
  float rs = rsqrtf(var + 1e-5f);
  bf16* yb = y + ((size_t)b * DIMC) * NPB + n;
#pragma unroll
  for (int c = 0; c < DIMC; ++c) yb[(size_t)c * NPB] = f2b((v[c] - mu) * rs * lw[c] + lb[c]);
}

// ---------------- MFMA 1x1 conv: out[m,n] = W[m,c] y[c,n] + bias, bf16 out --------
// K=48 zero-padded to 64 (2 k-steps of 16x16x32). Block: 4 waves, N-tile 256.
// grid.x = 512 (131072/256).
template <int MO>
__global__ __launch_bounds__(256) void k_pconv_mfma(
    const bf16* __restrict__ y, const float* __restrict__ W, const float* __restrict__ bias,
    bf16* __restrict__ dst, int dcs, int dco) {
  __shared__ unsigned short Yl[64][258];   // [k(c)][n], stride 258 -> bank-spread u16 reads
  __shared__ unsigned short Wl[MO][72];    // [m][k], 144B rows (16B-aligned b128 reads)
  int tid = threadIdx.x;
  int bt = blockIdx.x;
  int b = bt >> 8;                 // 256 n-tiles per batch
  int n0 = (bt & 255) * 256;
  const unsigned short* yb = (const unsigned short*)(y + ((size_t)b * DIMC) * NPB) + n0;
  for (int j = tid; j < 48 * 64; j += 256) {       // stage Y (48 x 256)
    int c = j >> 6, sub = j & 63;
    ushort4 u = *(const ushort4*)(yb + (size_t)c * NPB + sub * 4);
    *(ushort2*)&Yl[c][sub * 4]     = make_ushort2(u.x, u.y);
    *(ushort2*)&Yl[c][sub * 4 + 2] = make_ushort2(u.z, u.w);
  }
  for (int j = tid; j < 16 * 64; j += 256) {       // zero rows 48..63
    int c = 48 + (j >> 6), sub = j & 63;
    *(ushort2*)&Yl[c][sub * 4]     = make_ushort2(0, 0);
    *(ushort2*)&Yl[c][sub * 4 + 2] = make_ushort2(0, 0);
  }
  if (tid < MO) {                                  // stage W row tid (convert to bf16)
    const float* wr = W + (size_t)tid * 48;
    unsigned short* wl = Wl[tid];
#pragma unroll
    for (int c = 0; c < 48; ++c) wl[c] = f2us(wr[c]);
#pragma unroll
    for (int c = 48; c < 64; ++c) wl[c] = 0;
  }
  __syncthreads();
  int wv = tid >> 6, ln = tid & 63, lq = ln >> 4, li = ln & 15;
  short8 afr[MO / 16][2];
#pragma unroll
  for (int mt = 0; mt < MO / 16; ++mt)
#pragma unroll
    for (int ks = 0; ks < 2; ++ks)
      afr[mt][ks] = *(const short8*)&Wl[mt * 16 + li][ks * 32 + lq * 8];
#pragma unroll 1
  for (int ns = 0; ns < 4; ++ns) {
    int nn = wv * 64 + ns * 16 + li;
    short8 bfr[2];
#pragma unroll
    for (int ks = 0; ks < 2; ++ks)
#pragma unroll
      for (int j = 0; j < 8; ++j)
        bfr[ks][j] = (short)Yl[ks * 32 + lq * 8 + j][nn];
#pragma unroll
    for (int mt = 0; mt < MO / 16; ++mt) {
      f32x4 acc = {0.f, 0.f, 0.f, 0.f};
      acc = __builtin_amdgcn_mfma_f32_16x16x32_bf16(afr[mt][0], bfr[0], acc, 0, 0, 0);
      acc = __builtin_amdgcn_mfma_f32_16x16x32_bf16(afr[mt][1], bfr[1], acc, 0, 0, 0);
#pragma unroll
      for (int r = 0; r < 4; ++r) {
        int m = mt * 16 + lq * 4 + r;
        dst[((size_t)b * dcs + dco + m) * NPB + n0 + nn] = f2b(acc[r] + bias[m]);
      }
    }
  }
}

// ---------------- MFMA K=96 GEMM + fp32 epilogue: out = addend (+bias) + W@V ------
// W: fp32, row-stride wrs, batch-stride wbs, col-offset wcb. grid.x = 512.
__global__ __launch_bounds__(256) void k_ek96(
    const bf16* __restrict__ V, const float* __restrict__ W, int wrs, int wbs, int wcb,
    const float* __restrict__ bias, const float* __restrict__ addend, float* __restrict__ outp) {
  __shared__ unsigned short Yl[96][258];
  __shared__ unsigned short Wl[48][104];
  int tid = threadIdx.x;
  int bt = blockIdx.x;
  int b = bt >> 8;
  int n0 = (bt & 255) * 256;
  const unsigned short* vb = (const unsigned short*)(V + ((size_t)b * 96) * NPB) + n0;
  for (int j = tid; j < 96 * 64; j += 256) {
    int c = j >> 6, sub = j & 63;
    ushort4 u = *(const ushort4*)(vb + (size_t)c * NPB + sub * 4);
    *(ushort2*)&Yl[c][sub * 4]     = make_ushort2(u.x, u.y);
    *(ushort2*)&Yl[c][sub * 4 + 2] = make_ushort2(u.z, u.w);
  }
  if (tid < 48) {
    const float* wr = W + (size_t)b * wbs + (size_t)tid * wrs + wcb;
    unsigned short* wl = Wl[tid];
#pragma unroll
    for (int c = 0; c < 96; ++c) wl[c] = f2us(wr[c]);
  }
  __syncthreads();
  int wv = tid >> 6, ln = tid & 63, lq = ln >> 4, li = ln & 15;
  short8 afr[3][3];
#pragma unroll
  for (int mt = 0; mt < 3; ++mt)
#pragma unroll
    for (int ks = 0; ks < 3; ++ks)
      afr[mt][ks] = *(const short8*)&Wl[mt * 16 + li][ks * 32 + lq * 8];
#pragma unroll 1
  for (int ns = 0; ns < 4; ++ns) {
    int nn = wv * 64 + ns * 16 + li;
    short8 bfr[3];
#pragma unroll
    for (int ks = 0; ks < 3; ++ks)
#pragma unroll
      for (int j = 0; j < 8; ++j)
        bfr[ks][j] = (short)Yl[ks * 32 + lq * 8 + j][nn];
#pragma unroll
    for (int mt = 0; mt < 3; ++mt) {
      f32x4 acc = {0.f, 0.f, 0.f, 0.f};
      acc = __builtin_amdgcn_mfma_f32_16x16x32_bf16(afr[mt][0], bfr[0], acc, 0, 0, 0);
      acc = __builtin_amdgcn_mfma_f32_16x16x32_bf16(afr[mt][1], bfr[1], acc, 0, 0, 0);
      acc = __builtin_amdgcn_mfma_f32_16x16x32_bf16(afr[mt][2], bfr[2], acc, 0, 0, 0);
#pragma unroll
      for (int r = 0; r < 4; ++r) {
        int m = mt * 16 + lq * 4 + r;
        size_t idx = ((size_t)b * DIMC + m) * NPB + n0 + nn;
        float val = acc[r] + addend[idx];
        if (bias) val += bias[m];       // uniform branch (kernel arg)
        outp[idx] = val;
      }
    }
  }
}

// ---------------- MFMA Gram: G[b4+hd][c][d] += sum_n q[c,n] k[d,n] ----------------
// grid (64, 2): x = 1024-wide K-chunk, y = batch. Contraction dim = n.
__global__ __launch_bounds__(256) void k_gram_mfma(
    const bf16* __restrict__ qd, const bf16* __restrict__ kd, int hd, float* __restrict__ Gm) {
  __shared__ unsigned short qkl[2][48][264];   // 16B-aligned rows for b128 frag reads
  int tid = threadIdx.x, b = blockIdx.y;
  int wv = tid >> 6, ln = tid & 63, lq = ln >> 4, li = ln & 15;
  const unsigned short* qb = (const unsigned short*)(qd + ((size_t)b * DIMC) * NPB) + blockIdx.x * 1024;
  const unsigned short* kb = (const unsigned short*)(kd + ((size_t)b * DIMC) * NPB) + blockIdx.x * 1024;
  f32x4 acc[9];
#pragma unroll
  for (int t = 0; t < 9; ++t) acc[t] = (f32x4){0.f, 0.f, 0.f, 0.f};
#pragma unroll 1
  for (int it = 0; it < 4; ++it) {
    __syncthreads();
    for (int j = tid; j < 48 * 64; j += 256) {
      int c = j >> 6, sub = j & 63;
      *(ushort4*)&qkl[0][c][sub * 4] = *(const ushort4*)(qb + (size_t)c * NPB + it * 256 + sub * 4);
      *(ushort4*)&qkl[1][c][sub * 4] = *(const ushort4*)(kb + (size_t)c * NPB + it * 256 + sub * 4);
    }
    __syncthreads();
    short8 afr[3][2], bfr[3][2];
#pragma unroll
    for (int ks = 0; ks < 2; ++ks) {
      int kbase = wv * 64 + ks * 32 + lq * 8;
#pragma unroll
      for (int t = 0; t < 3; ++t) {
        afr[t][ks] = *(const short8*)&qkl[0][t * 16 + li][kbase];
        bfr[t][ks] = *(const short8*)&qkl[1][t * 16 + li][kbase];
      }
    }
#pragma unroll
    for (int mt = 0; mt < 3; ++mt)
#pragma unroll
      for (int nt = 0; nt < 3; ++nt) {
        acc[mt * 3 + nt] = __builtin_amdgcn_mfma_f32_16x16x32_bf16(afr[mt][0], bfr[nt][0], acc[mt * 3 + nt], 0, 0, 0);
        acc[mt * 3 + nt] = __builtin_amdgcn_mfma_f32_16x16x32_bf16(afr[mt][1], bfr[nt][1], acc[mt * 3 + nt], 0, 0, 0);
      }
  }
  // cross-wave reduce in LDS (reuse tile memory), wave 0 does the atomics
  __syncthreads();
  float* red = (float*)&qkl[0][0][0];   // need 3*2304*4 = 27648 B <= 50688 B
  if (wv > 0) {
    float* rw = red + (size_t)(wv - 1) * 2304;
#pragma unroll
    for (int t = 0; t < 9; ++t)
#pragma unroll
      for (int r = 0; r < 4; ++r)
        rw[t * 256 + r * 64 + ln] = acc[t][r];
  }
  __syncthreads();
  if (wv == 0) {
    float* gbase = Gm + (size_t)(b * 4 + hd) * 2304;
#pragma unroll
    for (int t = 0; t < 9; ++t) {
      int mt = t / 3, nt = t - mt * 3;
#pragma unroll
      for (int r = 0; r < 4; ++r) {
        int o = t * 256 + r * 64 + ln;
        float v = acc[t][r] + red[o] + red[2304 + o] + red[4608 + o];
        atomicAdd(&gbase[(mt * 16 + lq * 4 + r) * 48 + nt * 16 + li], v);
      }
    }
  }
}

// ------- grouped 3x3x3 conv, LDS-tiled (unchanged core; dst stride params) --------
__global__ __launch_bounds__(256) void k_gconv48(
    const bf16* __restrict__ src, const float* __restrict__ gw, const float* __restrict__ gb,
    bf16* __restrict__ dst, int dcs, int dco, float* __restrict__ sqout) {
  __shared__ unsigned short tile[4][4][18][66];
  __shared__ float red[4][4];
  int tid = threadIdx.x;
  int t0 = (blockIdx.x >> 2) * 2, h0 = (blockIdx.x & 3) * 16;
  int cbase = blockIdx.y * 4, b = blockIdx.z;
  const unsigned short* ib = (const unsigned short*)(src + ((size_t)b * DIMC + cbase) * NPB);
  for (int j = tid; j < 288 * 16; j += 256) {
    int r = j >> 4, sub = j & 15;
    int ci = r / 72, rem = r - ci * 72;
    int tt = rem / 18, hh = rem - tt * 18;
    int gt = t0 + tt - 1, gh = h0 + hh - 1;
    ushort4 val = make_ushort4(0, 0, 0, 0);
    if ((unsigned)gt < 16u && (unsigned)gh < 64u)
      val = *(const ushort4*)(ib + (size_t)ci * NPB + gt * 4096 + gh * 64 + sub * 4);
    unsigned short* dp = &tile[ci][tt][hh][1 + sub * 4];
    dp[0] = val.x; dp[1] = val.y; dp[2] = val.z; dp[3] = val.w;
  }
  for (int j = tid; j < 576; j += 256) {
    int r = j >> 1, side = j & 1;
    int ci = r / 72, rem = r - ci * 72;
    int tt = rem / 18, hh = rem - tt * 18;
    tile[ci][tt][hh][side ? 65 : 0] = 0;
  }
  __syncthreads();
  int w = tid & 63, hr = tid >> 6;
  float acc[2][4][4];
#pragma unroll
  for (int t = 0; t < 2; ++t)
#pragma unroll
    for (int i = 0; i < 4; ++i)
#pragma unroll
      for (int o = 0; o < 4; ++o) acc[t][i][o] = 0.f;
#pragma unroll 1
  for (int ci = 0; ci < 4; ++ci) {
#pragma unroll 1
    for (int dw = 0; dw < 3; ++dw) {
      int wwl = w + dw;
      float v[4][6];
#pragma unroll
      for (int tt = 0; tt < 4; ++tt)
#pragma unroll
        for (int r = 0; r < 6; ++r) v[tt][r] = bfr2f(tile[ci][tt][hr * 4 + r][wwl]);
#pragma unroll
      for (int dt = 0; dt < 3; ++dt)
#pragma unroll
        for (int dh = 0; dh < 3; ++dh) {
          float wv[4];
#pragma unroll
          for (int o = 0; o < 4; ++o)
            wv[o] = gw[(size_t)(cbase + o) * 108 + ci * 27 + dt * 9 + dh * 3 + dw];
#pragma unroll
          for (int t = 0; t < 2; ++t)
#pragma unroll
            for (int i = 0; i < 4; ++i) {
              float vv = v[t + dt][i + dh];
#pragma unroll
              for (int o = 0; o < 4; ++o) acc[t][i][o] = fmaf(wv[o], vv, acc[t][i][o]);
            }
        }
    }
  }
  float s[4] = {0.f, 0.f, 0.f, 0.f};
#pragma unroll
  for (int o = 0; o < 4; ++o) {
    float bias = gb[cbase + o];
    size_t obase = ((size_t)b * dcs + dco + cbase + o) * NPB;
#pragma unroll
    for (int t = 0; t < 2; ++t)
#pragma unroll
      for (int i = 0; i < 4; ++i) {
        bf16 rv = f2b(acc[t][i][o] + bias);
        dst[obase + (t0 + t) * 4096 + (h0 + hr * 4 + i) * 64 + w] = rv;
        float f = b2f(rv);
        s[o] = fmaf(f, f, s[o]);
      }
  }
  if (sqout) {
#pragma unroll
    for (int o = 0; o < 4; ++o) {
      float sv = s[o];
#pragma unroll
      for (int off = 32; off; off >>= 1) sv += __shfl_down(sv, off);
      if ((tid & 63) == 0) red[tid >> 6][o] = sv;
    }
    __syncthreads();
    if (tid < 4)
      atomicAdd(&sqout[(size_t)b * 192 + cbase + tid],
                red[0][tid] + red[1][tid] + red[2][tid] + red[3][tid]);
  }
}

// ------- per-pair: normalize G, softmax, fold proj_w -> Mm sections ---------------
__global__ __launch_bounds__(256) void k_attn_pair(
    const float* __restrict__ Gm, const float* __restrict__ sq, const float* __restrict__ temp,
    const float* __restrict__ pw, float* __restrict__ Mm, int hp) {
  __shared__ float A[48][48];
  __shared__ float nq[48], nk[48];
  int tid = threadIdx.x;
  for (int i = 0; i < 4; ++i) {
    int b = i >> 1, hd = hp * 2 + (i & 1);
    int bh = b * 4 + hd;
    if (tid < 48) nq[tid] = fmaxf(sqrtf(sq[bh * 48 + tid]), 1e-12f);
    else if (tid < 96) nk[tid - 48] = fmaxf(sqrtf(sq[384 + bh * 48 + tid - 48]), 1e-12f);
    __syncthreads();
    if (tid < 48) {
      float tv = temp[hd];
      float row[48]; float mx = -1e30f;
      float rq = 1.f / nq[tid];
#pragma unroll
      for (int d = 0; d < 48; ++d) {
        float sv = Gm[(size_t)bh * 2304 + tid * 48 + d] * rq / nk[d] * tv;
        row[d] = sv; mx = fmaxf(mx, sv);
      }
      float sum = 0.f;
#pragma unroll
      for (int d = 0; d < 48; ++d) { row[d] = expf(row[d] - mx); sum += row[d]; }
      float inv = 1.f / sum;
#pragma unroll
      for (int d = 0; d < 48; ++d) A[tid][d] = row[d] * inv;
    }
    __syncthreads();
    for (int j = tid; j < 2304; j += 256) {
      int co = j / 48, d = j - co * 48;
      float a = 0.f;
#pragma unroll
      for (int c = 0; c < 48; ++c) a = fmaf(pw[co * 192 + hd * 48 + c], A[c][d], a);
      Mm[((size_t)b * 48 + co) * 192 + hd * 48 + d] = a;
    }
    __syncthreads();
  }
}

// ------- depthwise 3x3x3 + exact GELU gate, LDS-tiled (unchanged) -----------------
__global__ __launch_bounds__(256) void k_dw_gelu(
    const bf16* __restrict__ z, const float* __restrict__ dwW, const float* __restrict__ dwB,
    bf16* __restrict__ g) {
  __shared__ unsigned short tile[2][4][18][66];
  int tid = threadIdx.x;
  int t0 = (blockIdx.x >> 2) * 2, h0 = (blockIdx.x & 3) * 16;
  int c = blockIdx.y, b = blockIdx.z;
  const unsigned short* z1 = (const unsigned short*)(z + ((size_t)b * C2 + c) * NPB);
  const unsigned short* z2 = (const unsigned short*)(z + ((size_t)b * C2 + c + HIDC) * NPB);
  for (int j = tid; j < 144 * 16; j += 256) {
    int r = j >> 4, sub = j & 15;
    int ch = r / 72, rem = r - ch * 72;
    int tt = rem / 18, hh = rem - tt * 18;
    int gt = t0 + tt - 1, gh = h0 + hh - 1;
    ushort4 val = make_ushort4(0, 0, 0, 0);
    const unsigned short* sp = ch ? z2 : z1;
    if ((unsigned)gt < 16u && (unsigned)gh < 64u)
      val = *(const ushort4*)(sp + gt * 4096 + gh * 64 + sub * 4);
    unsigned short* dp = &tile[ch][tt][hh][1 + sub * 4];
    dp[0] = val.x; dp[1] = val.y; dp[2] = val.z; dp[3] = val.w;
  }
  for (int j = tid; j < 288; j += 256) {
    int r = j >> 1, side = j & 1;
    int ch = r / 72, rem = r - ch * 72;
    int tt = rem / 18, hh = rem - tt * 18;
    tile[ch][tt][hh][side ? 65 : 0] = 0;
  }
  __syncthreads();
  int w = tid & 63, hr = tid >> 6;
  float a[2][2][4];
#pragma unroll
  for (int ch = 0; ch < 2; ++ch)
#pragma unroll
    for (int t = 0; t < 2; ++t)
#pragma unroll
      for (int i = 0; i < 4; ++i) a[ch][t][i] = 0.f;
#pragma unroll
  for (int ch = 0; ch < 2; ++ch) {
    const float* wt = dwW + (size_t)(c + ch * HIDC) * 27;
#pragma unroll 1
    for (int dw = 0; dw < 3; ++dw) {
      int wwl = w + dw;
      float v[4][6];
#pragma unroll
      for (int tt = 0; tt < 4; ++tt)
#pragma unroll
        for (int r = 0; r < 6; ++r) v[tt][r] = bfr2f(tile[ch][tt][hr * 4 + r][wwl]);
#pragma unroll
      for (int dt = 0; dt < 3; ++dt)
#pragma unroll
        for (int dh = 0; dh < 3; ++dh) {
          float wv = wt[dt * 9 + dh * 3 + dw];
#pragma unroll
          for (int t = 0; t < 2; ++t)
#pragma unroll
            for (int i = 0; i < 4; ++i)
              a[ch][t][i] = fmaf(wv, v[t + dt][i + dh], a[ch][t][i]);
        }
    }
  }
  float b1 = dwB[c], b2v = dwB[c + HIDC];
  size_t obase = ((size_t)b * HIDC + c) * NPB;
#pragma unroll
  for (int t = 0; t < 2; ++t)
#pragma unroll
    for (int i = 0; i < 4; ++i) {
      float x1v = a[0][t][i] + b1;
      float x2v = a[1][t][i] + b2v;
      float ge = 0.5f * x1v * (1.f + erff(x1v * 0.70710678118654752f));
      g[obase + (t0 + t) * 4096 + (h0 + hr * 4 + i) * 64 + w] = f2b(ge * x2v);
    }
}

extern "C" void kernel_launch(void* const* d_in, const int* in_sizes, int n_in,
                              void* d_out, int out_size, void* d_ws, size_t ws_size,
                              hipStream_t stream) {
  (void)in_sizes; (void)n_in; (void)out_size; (void)ws_size;
  const float* x     = (const float*)d_in[0];
  const float* ln1w  = (const float*)d_in[1];
  const float* ln1b  = (const float*)d_in[2];
  const float* qkvw  = (const float*)d_in[3];
  const float* qkvb  = (const float*)d_in[4];
  const float* gdww  = (const float*)d_in[5];
  const float* gdwb  = (const float*)d_in[6];
  const float* temp  = (const float*)d_in[7];
  const float* projw = (const float*)d_in[8];
  const float* projb = (const float*)d_in[9];
  const float* ln2w  = (const float*)d_in[10];
  const float* ln2b  = (const float*)d_in[11];
  const float* pinw  = (const float*)d_in[12];
  const float* pinb  = (const float*)d_in[13];
  const float* dww   = (const float*)d_in[14];
  const float* dwb   = (const float*)d_in[15];
  const float* poutw = (const float*)d_in[16];
  const float* poutb = (const float*)d_in[17];
  float* out = (float*)d_out;

  // Workspace layout — peak 75,648,000 B (< 75,694,080 proven safe in R2/R3):
  char* ws = (char*)d_ws;
  bf16*  y     = (bf16*)(ws);              // 12,582,912 B  LN1 output
  bf16*  stage = (bf16*)(ws + 12582912);   // 12,582,912 B  pconv -> gconv scratch
  bf16*  qd    = (bf16*)(ws + 25165824);   // 12,582,912 B
  bf16*  kd    = (bf16*)(ws + 37748736);   // 12,582,912 B
  bf16*  vd2   = (bf16*)(ws + 50331648);   // 25,165,824 B  [2b][96][NPB] pair of v-heads
  float* Gm    = (float*)(ws + 75497472);  //     73,728 B
  float* sq    = (float*)(ws + 75571200);  //      3,072 B
  float* Mm    = (float*)(ws + 75574272);  //     73,728 B
  // FFN phase (attention buffers dead):
  bf16*  z     = (bf16*)(ws);              // 50,331,648 B  [2][192][NPB]
  bf16*  y2    = (bf16*)(ws + 50331648);   // 12,582,912 B  LN2 output
  bf16*  gg    = (bf16*)(ws + 50331648);   // 25,165,824 B  (overwrites y2 after pconv192)
  float* x1    = (float*)d_out;            // attn residual lives in d_out

  hipMemsetAsync(Gm, 0, 73728 + 3072, stream);
  k_ln<<<dim3(512), dim3(256), 0, stream>>>(x, ln1w, ln1b, y);

  for (int hp = 0; hp < 2; ++hp) {
    for (int i = 0; i < 2; ++i) {
      int h = hp * 2 + i;
      int rq = h * 48, rk = 192 + h * 48, rv = 384 + h * 48;
      k_pconv_mfma<48><<<dim3(512), dim3(256), 0, stream>>>(y, qkvw + (size_t)rq * 48, qkvb + rq, stage, 48, 0);
      k_gconv48<<<dim3(32, 12, 2), dim3(256), 0, stream>>>(stage, gdww + (size_t)rq * 108, gdwb + rq, qd, 48, 0, sq + h * 48);
      k_pconv_mfma<48><<<dim3(512), dim3(256), 0, stream>>>(y, qkvw + (size_t)rk * 48, qkvb + rk, stage, 48, 0);
      k_gconv48<<<dim3(32, 12, 2), dim3(256), 0, stream>>>(stage, gdww + (size_t)rk * 108, gdwb + rk, kd, 48, 0, sq + 384 + h * 48);
      k_gram_mfma<<<dim3(64, 2), dim3(256), 0, stream>>>(qd, kd, h, Gm);
      k_pconv_mfma<48><<<dim3(512), dim3(256), 0, stream>>>(y, qkvw + (size_t)rv * 48, qkvb + rv, stage, 48, 0);
      k_gconv48<<<dim3(32, 12, 2), dim3(256), 0, stream>>>(stage, gdww + (size_t)rv * 108, gdwb + rv, vd2, 96, i * 48, nullptr);
    }
    k_attn_pair<<<dim3(1), dim3(256), 0, stream>>>(Gm, sq, temp, projw, Mm, hp);
    if (hp == 0)
      k_ek96<<<dim3(512), dim3(256), 0, stream>>>(vd2, Mm, 192, 48 * 192, 0, projb, x, x1);
    else
      k_ek96<<<dim3(512), dim3(256), 0, stream>>>(vd2, Mm, 192, 48 * 192, 96, nullptr, x1, x1);
  }
  k_ln<<<dim3(512), dim3(256), 0, stream>>>(x1, ln2w, ln2b, y2);
  k_pconv_mfma<192><<<dim3(512), dim3(256), 0, stream>>>(y2, pinw, pinb, z, 192, 0);
  k_dw_gelu<<<dim3(32, 96, 2), dim3(256), 0, stream>>>(z, dww, dwb, gg);
  k_ek96<<<dim3(512), dim3(256), 0, stream>>>(gg, poutw, 96, 0, 0, poutb, x1, out);
}

// Round 5
// 874.598 us; speedup vs baseline: 5.1887x; 1.1447x over previous
//
#include <hip/hip_runtime.h>
#include <hip/hip_bf16.h>
#include <math.h>

typedef __hip_bfloat16 bf16;
typedef __attribute__((ext_vector_type(8))) short short8;
typedef __attribute__((ext_vector_type(4))) float f32x4;

#define NPB   65536   // positions per batch (16*64*64)
#define DIMC  48
#define C2    192
#define HIDC  96
#define TT    16

static __device__ __forceinline__ float b2f(bf16 v) { return __bfloat162float(v); }
static __device__ __forceinline__ bf16  f2b(float v) { return __float2bfloat16(v); }
static __device__ __forceinline__ float bfr2f(unsigned short u) {
  union { unsigned int i; float f; } c; c.i = ((unsigned int)u) << 16; return c.f;
}
static __device__ __forceinline__ unsigned short f2us(float v) {
  return __bfloat16_as_ushort(__float2bfloat16(v));
}

// ---------------- y = LN(x) over 48 channels, bf16 out (LN1 and LN2) -------------
__global__ __launch_bounds__(256) void k_ln(
    const float* __restrict__ x, const float* __restrict__ lw, const float* __restrict__ lb,
    bf16* __restrict__ y) {
  int p = blockIdx.x * 256 + threadIdx.x;   // 0..131071
  int b = p >> 16, n = p & (NPB - 1);
  const float* xb = x + ((size_t)b * DIMC) * NPB + n;
  float v[DIMC]; float s = 0.f, s2 = 0.f;
#pragma unroll
  for (int c = 0; c < DIMC; ++c) { float t = xb[(size_t)c * NPB]; v[c] = t; s += t; s2 += t * t; }
  float mu = s * (1.f / DIMC);
  float var = fmaxf(s2 * (1.f / DIMC) - mu * mu, 0.f);
  float rs = rsqrtf(var + 1e-5f);
  bf16* yb = y + ((size_t)b * DIMC) * NPB + n;
#pragma unroll
  for (int c = 0; c < DIMC; ++c) yb[(size_t)c * NPB] = f2b((v[c] - mu) * rs * lw[c] + lb[c]);
}

// ------- MFMA 1x1 conv, sectioned: out[s*48+m, n] = W_s[m,c] y[c,n] + bias_s[m] ---
// grid (NSEC, 512): x = weight/output section of 48 rows, y = n-tile (256) + batch.
__global__ __launch_bounds__(256) void k_pconv_sec(
    const bf16* __restrict__ y, const float* __restrict__ W, int wso,
    const float* __restrict__ bias, int bso, bf16* __restrict__ dst, int dcs) {
  __shared__ unsigned short Yl[64][258];
  __shared__ unsigned short Wl[48][72];
  int tid = threadIdx.x;
  int s = blockIdx.x;
  int bt = blockIdx.y;
  int b = bt >> 8;
  int n0 = (bt & 255) * 256;
  const unsigned short* yb = (const unsigned short*)(y + ((size_t)b * DIMC) * NPB) + n0;
  for (int j = tid; j < 48 * 64; j += 256) {       // stage Y (48 x 256)
    int c = j >> 6, sub = j & 63;
    ushort4 u = *(const ushort4*)(yb + (size_t)c * NPB + sub * 4);
    *(ushort2*)&Yl[c][sub * 4]     = make_ushort2(u.x, u.y);
    *(ushort2*)&Yl[c][sub * 4 + 2] = make_ushort2(u.z, u.w);
  }
  for (int j = tid; j < 16 * 64; j += 256) {       // zero rows 48..63
    int c = 48 + (j >> 6), sub = j & 63;
    *(ushort2*)&Yl[c][sub * 4]     = make_ushort2(0, 0);
    *(ushort2*)&Yl[c][sub * 4 + 2] = make_ushort2(0, 0);
  }
  if (tid < 48) {
    const float* wr = W + (size_t)s * wso + (size_t)tid * 48;
    unsigned short* wl = Wl[tid];
#pragma unroll
    for (int c = 0; c < 48; ++c) wl[c] = f2us(wr[c]);
#pragma unroll
    for (int c = 48; c < 64; ++c) wl[c] = 0;
  }
  __syncthreads();
  int wv = tid >> 6, ln = tid & 63, lq = ln >> 4, li = ln & 15;
  short8 afr[3][2];
#pragma unroll
  for (int mt = 0; mt < 3; ++mt)
#pragma unroll
    for (int ks = 0; ks < 2; ++ks)
      afr[mt][ks] = *(const short8*)&Wl[mt * 16 + li][ks * 32 + lq * 8];
#pragma unroll 1
  for (int ns = 0; ns < 4; ++ns) {
    int nn = wv * 64 + ns * 16 + li;
    short8 bfr[2];
#pragma unroll
    for (int ks = 0; ks < 2; ++ks)
#pragma unroll
      for (int j = 0; j < 8; ++j)
        bfr[ks][j] = (short)Yl[ks * 32 + lq * 8 + j][nn];
#pragma unroll
    for (int mt = 0; mt < 3; ++mt) {
      f32x4 acc = {0.f, 0.f, 0.f, 0.f};
      acc = __builtin_amdgcn_mfma_f32_16x16x32_bf16(afr[mt][0], bfr[0], acc, 0, 0, 0);
      acc = __builtin_amdgcn_mfma_f32_16x16x32_bf16(afr[mt][1], bfr[1], acc, 0, 0, 0);
#pragma unroll
      for (int r = 0; r < 4; ++r) {
        int m = mt * 16 + lq * 4 + r;
        dst[((size_t)b * dcs + s * 48 + m) * NPB + n0 + nn] = f2b(acc[r] + bias[s * bso + m]);
      }
    }
  }
}

// ------- grouped 3x3x3 conv, LDS-tiled; section-aware weight/sq indexing ----------
// grid (32, NG, 2): x = spatial tile (2t x 16h x 64w), y = group of 4 ch, z = batch.
// global out-ch = c_local + (c_local<48 ? woA : woB); sq idx likewise with sqA/sqB.
__global__ __launch_bounds__(256) void k_gconv48(
    const bf16* __restrict__ src, int scs, int sco,
    const float* __restrict__ gw, const float* __restrict__ gb, int woA, int woB,
    bf16* __restrict__ dst, int dcs,
    float* __restrict__ sqout, int sqA, int sqB) {
  __shared__ unsigned short tile[4][4][18][66];
  __shared__ float red[4][4];
  int tid = threadIdx.x;
  int t0 = (blockIdx.x >> 2) * 2, h0 = (blockIdx.x & 3) * 16;
  int cbase = blockIdx.y * 4, b = blockIdx.z;
  int wo = (cbase < 48) ? woA : woB;   // block-uniform
  const unsigned short* ib = (const unsigned short*)(src + ((size_t)b * scs + sco + cbase) * NPB);
  for (int j = tid; j < 288 * 16; j += 256) {
    int r = j >> 4, sub = j & 15;
    int ci = r / 72, rem = r - ci * 72;
    int tt = rem / 18, hh = rem - tt * 18;
    int gt = t0 + tt - 1, gh = h0 + hh - 1;
    ushort4 val = make_ushort4(0, 0, 0, 0);
    if ((unsigned)gt < 16u && (unsigned)gh < 64u)
      val = *(const ushort4*)(ib + (size_t)ci * NPB + gt * 4096 + gh * 64 + sub * 4);
    unsigned short* dp = &tile[ci][tt][hh][1 + sub * 4];
    dp[0] = val.x; dp[1] = val.y; dp[2] = val.z; dp[3] = val.w;
  }
  for (int j = tid; j < 576; j += 256) {
    int r = j >> 1, side = j & 1;
    int ci = r / 72, rem = r - ci * 72;
    int tt = rem / 18, hh = rem - tt * 18;
    tile[ci][tt][hh][side ? 65 : 0] = 0;
  }
  __syncthreads();
  int w = tid & 63, hr = tid >> 6;
  float acc[2][4][4];
#pragma unroll
  for (int t = 0; t < 2; ++t)
#pragma unroll
    for (int i = 0; i < 4; ++i)
#pragma unroll
      for (int o = 0; o < 4; ++o) acc[t][i][o] = 0.f;
#pragma unroll 1
  for (int ci = 0; ci < 4; ++ci) {
#pragma unroll 1
    for (int dw = 0; dw < 3; ++dw) {
      int wwl = w + dw;
      float v[4][6];
#pragma unroll
      for (int tt = 0; tt < 4; ++tt)
#pragma unroll
        for (int r = 0; r < 6; ++r) v[tt][r] = bfr2f(tile[ci][tt][hr * 4 + r][wwl]);
#pragma unroll
      for (int dt = 0; dt < 3; ++dt)
#pragma unroll
        for (int dh = 0; dh < 3; ++dh) {
          float wv[4];
#pragma unroll
          for (int o = 0; o < 4; ++o)
            wv[o] = gw[(size_t)(cbase + o + wo) * 108 + ci * 27 + dt * 9 + dh * 3 + dw];
#pragma unroll
          for (int t = 0; t < 2; ++t)
#pragma unroll
            for (int i = 0; i < 4; ++i) {
              float vv = v[t + dt][i + dh];
#pragma unroll
              for (int o = 0; o < 4; ++o) acc[t][i][o] = fmaf(wv[o], vv, acc[t][i][o]);
            }
        }
    }
  }
  float s[4] = {0.f, 0.f, 0.f, 0.f};
#pragma unroll
  for (int o = 0; o < 4; ++o) {
    float bias = gb[cbase + o + wo];
    size_t obase = ((size_t)b * dcs + cbase + o) * NPB;
#pragma unroll
    for (int t = 0; t < 2; ++t)
#pragma unroll
      for (int i = 0; i < 4; ++i) {
        bf16 rv = f2b(acc[t][i][o] + bias);
        dst[obase + (t0 + t) * 4096 + (h0 + hr * 4 + i) * 64 + w] = rv;
        float f = b2f(rv);
        s[o] = fmaf(f, f, s[o]);
      }
  }
  if (sqout) {
#pragma unroll
    for (int o = 0; o < 4; ++o) {
      float sv = s[o];
#pragma unroll
      for (int off = 32; off; off >>= 1) sv += __shfl_down(sv, off);
      if ((tid & 63) == 0) red[tid >> 6][o] = sv;
    }
    __syncthreads();
    if (tid < 4) {
      int c = cbase + tid;
      int sqo = (cbase < 48) ? sqA : sqB;
      atomicAdd(&sqout[(size_t)b * 192 + c + sqo],
                red[0][tid] + red[1][tid] + red[2][tid] + red[3][tid]);
    }
  }
}

// ---------------- MFMA Gram: G[b4+hd][c][d] += sum_n q[c,n] k[d,n] ----------------
// grid (64, 2): x = 1024-wide n-chunk, y = batch. bs = channel batch-stride.
__global__ __launch_bounds__(256) void k_gram_mfma(
    const bf16* __restrict__ qd, const bf16* __restrict__ kd, int bs, int hd,
    float* __restrict__ Gm) {
  __shared__ unsigned short qkl[2][48][264];
  int tid = threadIdx.x, b = blockIdx.y;
  int wv = tid >> 6, ln = tid & 63, lq = ln >> 4, li = ln & 15;
  const unsigned short* qb = (const unsigned short*)(qd + ((size_t)b * bs) * NPB) + blockIdx.x * 1024;
  const unsigned short* kb = (const unsigned short*)(kd + ((size_t)b * bs) * NPB) + blockIdx.x * 1024;
  f32x4 acc[9];
#pragma unroll
  for (int t = 0; t < 9; ++t) acc[t] = (f32x4){0.f, 0.f, 0.f, 0.f};
#pragma unroll 1
  for (int it = 0; it < 4; ++it) {
    __syncthreads();
    for (int j = tid; j < 48 * 64; j += 256) {
      int c = j >> 6, sub = j & 63;
      *(ushort4*)&qkl[0][c][sub * 4] = *(const ushort4*)(qb + (size_t)c * NPB + it * 256 + sub * 4);
      *(ushort4*)&qkl[1][c][sub * 4] = *(const ushort4*)(kb + (size_t)c * NPB + it * 256 + sub * 4);
    }
    __syncthreads();
    short8 afr[3][2], bfr[3][2];
#pragma unroll
    for (int ks = 0; ks < 2; ++ks) {
      int kbase = wv * 64 + ks * 32 + lq * 8;
#pragma unroll
      for (int t = 0; t < 3; ++t) {
        afr[t][ks] = *(const short8*)&qkl[0][t * 16 + li][kbase];
        bfr[t][ks] = *(const short8*)&qkl[1][t * 16 + li][kbase];
      }
    }
#pragma unroll
    for (int mt = 0; mt < 3; ++mt)
#pragma unroll
      for (int nt = 0; nt < 3; ++nt) {
        acc[mt * 3 + nt] = __builtin_amdgcn_mfma_f32_16x16x32_bf16(afr[mt][0], bfr[nt][0], acc[mt * 3 + nt], 0, 0, 0);
        acc[mt * 3 + nt] = __builtin_amdgcn_mfma_f32_16x16x32_bf16(afr[mt][1], bfr[nt][1], acc[mt * 3 + nt], 0, 0, 0);
      }
  }
  __syncthreads();
  float* red = (float*)&qkl[0][0][0];
  if (wv > 0) {
    float* rw = red + (size_t)(wv - 1) * 2304;
#pragma unroll
    for (int t = 0; t < 9; ++t)
#pragma unroll
      for (int r = 0; r < 4; ++r)
        rw[t * 256 + r * 64 + ln] = acc[t][r];
  }
  __syncthreads();
  if (wv == 0) {
    float* gbase = Gm + (size_t)(b * 4 + hd) * 2304;
#pragma unroll
    for (int t = 0; t < 9; ++t) {
      int mt = t / 3, nt = t - mt * 3;
#pragma unroll
      for (int r = 0; r < 4; ++r) {
        int o = t * 256 + r * 64 + ln;
        float v = acc[t][r] + red[o] + red[2304 + o] + red[4608 + o];
        atomicAdd(&gbase[(mt * 16 + lq * 4 + r) * 48 + nt * 16 + li], v);
      }
    }
  }
}

// ------- fused: softmax(norm G)*proj fold + x1 (+)= M_h @ v_h (+bias) -------------
// grid (512): each block redundantly builds M_h (tiny) then does its n-tile GEMM.
__global__ __launch_bounds__(256) void k_attn_ek48(
    const bf16* __restrict__ vd, const float* __restrict__ Gm, const float* __restrict__ sq,
    const float* __restrict__ temp, const float* __restrict__ pw, int hd,
    const float* __restrict__ bias, const float* __restrict__ addend, float* __restrict__ outp) {
  __shared__ unsigned short Yl[64][258];
  __shared__ unsigned short Ml[48][72];
  __shared__ float A[48][48];
  __shared__ float nk[48];
  int tid = threadIdx.x;
  int bt = blockIdx.x;
  int b = bt >> 8;
  int n0 = (bt & 255) * 256;
  int bh = b * 4 + hd;
  const unsigned short* vb = (const unsigned short*)(vd + ((size_t)b * 48) * NPB) + n0;
  for (int j = tid; j < 48 * 64; j += 256) {
    int c = j >> 6, sub = j & 63;
    ushort4 u = *(const ushort4*)(vb + (size_t)c * NPB + sub * 4);
    *(ushort2*)&Yl[c][sub * 4]     = make_ushort2(u.x, u.y);
    *(ushort2*)&Yl[c][sub * 4 + 2] = make_ushort2(u.z, u.w);
  }
  for (int j = tid; j < 16 * 64; j += 256) {
    int c = 48 + (j >> 6), sub = j & 63;
    *(ushort2*)&Yl[c][sub * 4]     = make_ushort2(0, 0);
    *(ushort2*)&Yl[c][sub * 4 + 2] = make_ushort2(0, 0);
  }
  if (tid >= 64 && tid < 112) nk[tid - 64] = fmaxf(sqrtf(sq[384 + bh * 48 + tid - 64]), 1e-12f);
  __syncthreads();
  if (tid < 48) {
    float tv = temp[hd];
    float rq = 1.f / fmaxf(sqrtf(sq[bh * 48 + tid]), 1e-12f);
    float row[48]; float mx = -1e30f;
#pragma unroll
    for (int d = 0; d < 48; ++d) {
      float sv = Gm[(size_t)bh * 2304 + tid * 48 + d] * rq / nk[d] * tv;
      row[d] = sv; mx = fmaxf(mx, sv);
    }
    float sum = 0.f;
#pragma unroll
    for (int d = 0; d < 48; ++d) { row[d] = expf(row[d] - mx); sum += row[d]; }
    float inv = 1.f / sum;
#pragma unroll
    for (int d = 0; d < 48; ++d) A[tid][d] = row[d] * inv;
  }
  __syncthreads();
  for (int j = tid; j < 48 * 64; j += 256) {     // fold M = pw_h @ A, bf16 into Ml
    int m = j >> 6, d = j & 63;
    float a = 0.f;
    if (d < 48) {
#pragma unroll
      for (int c = 0; c < 48; ++c) a = fmaf(pw[m * 192 + hd * 48 + c], A[c][d], a);
    }
    Ml[m][d] = f2us(a);
  }
  __syncthreads();
  int wv = tid >> 6, ln = tid & 63, lq = ln >> 4, li = ln & 15;
  short8 afr[3][2];
#pragma unroll
  for (int mt = 0; mt < 3; ++mt)
#pragma unroll
    for (int ks = 0; ks < 2; ++ks)
      afr[mt][ks] = *(const short8*)&Ml[mt * 16 + li][ks * 32 + lq * 8];
#pragma unroll 1
  for (int ns = 0; ns < 4; ++ns) {
    int nn = wv * 64 + ns * 16 + li;
    short8 bfr[2];
#pragma unroll
    for (int ks = 0; ks < 2; ++ks)
#pragma unroll
      for (int j = 0; j < 8; ++j)
        bfr[ks][j] = (short)Yl[ks * 32 + lq * 8 + j][nn];
#pragma unroll
    for (int mt = 0; mt < 3; ++mt) {
      f32x4 acc = {0.f, 0.f, 0.f, 0.f};
      acc = __builtin_amdgcn_mfma_f32_16x16x32_bf16(afr[mt][0], bfr[0], acc, 0, 0, 0);
      acc = __builtin_amdgcn_mfma_f32_16x16x32_bf16(afr[mt][1], bfr[1], acc, 0, 0, 0);
#pragma unroll
      for (int r = 0; r < 4; ++r) {
        int m = mt * 16 + lq * 4 + r;
        size_t idx = ((size_t)b * DIMC + m) * NPB + n0 + nn;
        float val = acc[r] + addend[idx];
        if (bias) val += bias[m];
        outp[idx] = val;
      }
    }
  }
}

// ---------------- MFMA K=96 GEMM + fp32 epilogue (pout): out = addend+bias+W@V ----
__global__ __launch_bounds__(256) void k_ek96(
    const bf16* __restrict__ V, const float* __restrict__ W, int wrs,
    const float* __restrict__ bias, const float* __restrict__ addend, float* __restrict__ outp) {
  __shared__ unsigned short Yl[96][258];
  __shared__ unsigned short Wl[48][104];
  int tid = threadIdx.x;
  int bt = blockIdx.x;
  int b = bt >> 8;
  int n0 = (bt & 255) * 256;
  const unsigned short* vb = (const unsigned short*)(V + ((size_t)b * 96) * NPB) + n0;
  for (int j = tid; j < 96 * 64; j += 256) {
    int c = j >> 6, sub = j & 63;
    ushort4 u = *(const ushort4*)(vb + (size_t)c * NPB + sub * 4);
    *(ushort2*)&Yl[c][sub * 4]     = make_ushort2(u.x, u.y);
    *(ushort2*)&Yl[c][sub * 4 + 2] = make_ushort2(u.z, u.w);
  }
  if (tid < 48) {
    const float* wr = W + (size_t)tid * wrs;
    unsigned short* wl = Wl[tid];
#pragma unroll
    for (int c = 0; c < 96; ++c) wl[c] = f2us(wr[c]);
  }
  __syncthreads();
  int wv = tid >> 6, ln = tid & 63, lq = ln >> 4, li = ln & 15;
  short8 afr[3][3];
#pragma unroll
  for (int mt = 0; mt < 3; ++mt)
#pragma unroll
    for (int ks = 0; ks < 3; ++ks)
      afr[mt][ks] = *(const short8*)&Wl[mt * 16 + li][ks * 32 + lq * 8];
#pragma unroll 1
  for (int ns = 0; ns < 4; ++ns) {
    int nn = wv * 64 + ns * 16 + li;
    short8 bfr[3];
#pragma unroll
    for (int ks = 0; ks < 3; ++ks)
#pragma unroll
      for (int j = 0; j < 8; ++j)
        bfr[ks][j] = (short)Yl[ks * 32 + lq * 8 + j][nn];
#pragma unroll
    for (int mt = 0; mt < 3; ++mt) {
      f32x4 acc = {0.f, 0.f, 0.f, 0.f};
      acc = __builtin_amdgcn_mfma_f32_16x16x32_bf16(afr[mt][0], bfr[0], acc, 0, 0, 0);
      acc = __builtin_amdgcn_mfma_f32_16x16x32_bf16(afr[mt][1], bfr[1], acc, 0, 0, 0);
      acc = __builtin_amdgcn_mfma_f32_16x16x32_bf16(afr[mt][2], bfr[2], acc, 0, 0, 0);
#pragma unroll
      for (int r = 0; r < 4; ++r) {
        int m = mt * 16 + lq * 4 + r;
        size_t idx = ((size_t)b * DIMC + m) * NPB + n0 + nn;
        outp[idx] = acc[r] + addend[idx] + bias[m];
      }
    }
  }
}

// ------- depthwise 3x3x3 + exact GELU gate, LDS-tiled: 4t x 16h x 64w tile --------
// grid (16, 96, 2): x = spatial tile (4 t-tiles * 4 h-tiles), y = ch pair, z = batch
__global__ __launch_bounds__(256) void k_dw_gelu(
    const bf16* __restrict__ z, const float* __restrict__ dwW, const float* __restrict__ dwB,
    bf16* __restrict__ g) {
  __shared__ unsigned short tile[2][6][18][66];
  int tid = threadIdx.x;
  int t0 = (blockIdx.x >> 2) * 4, h0 = (blockIdx.x & 3) * 16;
  int c = blockIdx.y, b = blockIdx.z;
  const unsigned short* z1 = (const unsigned short*)(z + ((size_t)b * C2 + c) * NPB);
  const unsigned short* z2 = (const unsigned short*)(z + ((size_t)b * C2 + c + HIDC) * NPB);
  for (int j = tid; j < 216 * 16; j += 256) {
    int r = j >> 4, sub = j & 15;
    int ch = r / 108, rem = r - ch * 108;
    int tt = rem / 18, hh = rem - tt * 18;
    int gt = t0 + tt - 1, gh = h0 + hh - 1;
    ushort4 val = make_ushort4(0, 0, 0, 0);
    const unsigned short* sp = ch ? z2 : z1;
    if ((unsigned)gt < 16u && (unsigned)gh < 64u)
      val = *(const ushort4*)(sp + gt * 4096 + gh * 64 + sub * 4);
    unsigned short* dp = &tile[ch][tt][hh][1 + sub * 4];
    dp[0] = val.x; dp[1] = val.y; dp[2] = val.z; dp[3] = val.w;
  }
  for (int j = tid; j < 432; j += 256) {
    int r = j >> 1, side = j & 1;
    int ch = r / 108, rem = r - ch * 108;
    int tt = rem / 18, hh = rem - tt * 18;
    tile[ch][tt][hh][side ? 65 : 0] = 0;
  }
  __syncthreads();
  int w = tid & 63, hr = tid >> 6;
  float a[2][4][4];
#pragma unroll
  for (int ch = 0; ch < 2; ++ch)
#pragma unroll
    for (int t = 0; t < 4; ++t)
#pragma unroll
      for (int i = 0; i < 4; ++i) a[ch][t][i] = 0.f;
#pragma unroll 1
  for (int ch = 0; ch < 2; ++ch) {
    const float* wt = dwW + (size_t)(c + ch * HIDC) * 27;
#pragma unroll 1
    for (int dw = 0; dw < 3; ++dw) {
      int wwl = w + dw;
      float v[6][6];
#pragma unroll
      for (int tt = 0; tt < 6; ++tt)
#pragma unroll
        for (int r = 0; r < 6; ++r) v[tt][r] = bfr2f(tile[ch][tt][hr * 4 + r][wwl]);
#pragma unroll
      for (int dt = 0; dt < 3; ++dt)
#pragma unroll
        for (int dh = 0; dh < 3; ++dh) {
          float wv = wt[dt * 9 + dh * 3 + dw];
#pragma unroll
          for (int t = 0; t < 4; ++t)
#pragma unroll
            for (int i = 0; i < 4; ++i)
              a[ch][t][i] = fmaf(wv, v[t + dt][i + dh], a[ch][t][i]);
        }
    }
  }
  float b1 = dwB[c], b2v = dwB[c + HIDC];
  size_t obase = ((size_t)b * HIDC + c) * NPB;
#pragma unroll
  for (int t = 0; t < 4; ++t)
#pragma unroll
    for (int i = 0; i < 4; ++i) {
      float x1v = a[0][t][i] + b1;
      float x2v = a[1][t][i] + b2v;
      float ge = 0.5f * x1v * (1.f + erff(x1v * 0.70710678118654752f));
      g[obase + (t0 + t) * 4096 + (h0 + hr * 4 + i) * 64 + w] = f2b(ge * x2v);
    }
}

extern "C" void kernel_launch(void* const* d_in, const int* in_sizes, int n_in,
                              void* d_out, int out_size, void* d_ws, size_t ws_size,
                              hipStream_t stream) {
  (void)in_sizes; (void)n_in; (void)out_size; (void)ws_size;
  const float* x     = (const float*)d_in[0];
  const float* ln1w  = (const float*)d_in[1];
  const float* ln1b  = (const float*)d_in[2];
  const float* qkvw  = (const float*)d_in[3];
  const float* qkvb  = (const float*)d_in[4];
  const float* gdww  = (const float*)d_in[5];
  const float* gdwb  = (const float*)d_in[6];
  const float* temp  = (const float*)d_in[7];
  const float* projw = (const float*)d_in[8];
  const float* projb = (const float*)d_in[9];
  const float* ln2w  = (const float*)d_in[10];
  const float* ln2b  = (const float*)d_in[11];
  const float* pinw  = (const float*)d_in[12];
  const float* pinb  = (const float*)d_in[13];
  const float* dww   = (const float*)d_in[14];
  const float* dwb   = (const float*)d_in[15];
  const float* poutw = (const float*)d_in[16];
  const float* poutb = (const float*)d_in[17];
  float* out = (float*)d_out;

  // Workspace layout — peak 75,574,272 B (< 75,648,000 proven safe):
  char* ws = (char*)d_ws;
  bf16*  y     = (bf16*)(ws);              // 12,582,912 B  LN output
  bf16*  st144 = (bf16*)(ws + 12582912);   // 37,748,736 B  [2][144][NPB] qkv of one head
  bf16*  qkd   = (bf16*)(ws + 50331648);   // 25,165,824 B  [2][96][NPB] q,k dw-out
  bf16*  vd    = (bf16*)(ws + 50331648);   // 12,582,912 B  [2][48][NPB] (reuses qkd)
  float* Gm    = (float*)(ws + 75497472);  //     73,728 B
  float* sq    = (float*)(ws + 75571200);  //      3,072 B
  // FFN phase (attention buffers dead):
  bf16*  z     = (bf16*)(ws);              // 50,331,648 B  [2][192][NPB]
  bf16*  y2    = (bf16*)(ws + 50331648);   // 12,582,912 B  LN2 output
  bf16*  gg    = (bf16*)(ws + 50331648);   // 25,165,824 B  (overwrites y2 after pin)

  hipMemsetAsync(Gm, 0, 73728 + 3072, stream);
  k_ln<<<dim3(512), dim3(256), 0, stream>>>(x, ln1w, ln1b, y);

  for (int h = 0; h < 4; ++h) {
    // q,k,v pointwise for head h in one launch: sections s=0,1,2 -> rows s*192+h*48
    k_pconv_sec<<<dim3(3, 512), dim3(256), 0, stream>>>(
        y, qkvw + (size_t)h * 2304, 9216, qkvb + h * 48, 192, st144, 144);
    // grouped dw-conv for q+k (96 ch) in one launch, with sumsq
    k_gconv48<<<dim3(32, 24, 2), dim3(256), 0, stream>>>(
        st144, 144, 0, gdww, gdwb, h * 48, 144 + h * 48, qkd, 96,
        sq, h * 48, 336 + h * 48);
    k_gram_mfma<<<dim3(64, 2), dim3(256), 0, stream>>>(qkd, qkd + (size_t)48 * NPB, 96, h, Gm);
    // grouped dw-conv for v (48 ch) -> vd (reuses qkd region; gram already done)
    k_gconv48<<<dim3(32, 12, 2), dim3(256), 0, stream>>>(
        st144, 144, 96, gdww, gdwb, 384 + h * 48, 384 + h * 48, vd, 48,
        nullptr, 0, 0);
    // fused softmax + proj-fold + x1 (+)= M_h v_h
    k_attn_ek48<<<dim3(512), dim3(256), 0, stream>>>(
        vd, Gm, sq, temp, projw, h,
        h == 0 ? projb : nullptr, h == 0 ? x : out, out);
  }
  k_ln<<<dim3(512), dim3(256), 0, stream>>>(out, ln2w, ln2b, y2);
  k_pconv_sec<<<dim3(4, 512), dim3(256), 0, stream>>>(y2, pinw, 2304, pinb, 48, z, 192);
  k_dw_gelu<<<dim3(16, 96, 2), dim3(256), 0, stream>>>(z, dww, dwb, gg);
  k_ek96<<<dim3(512), dim3(256), 0, stream>>>(gg, poutw, 96, poutb, out, out);
}

// Round 6
// 852.055 us; speedup vs baseline: 5.3260x; 1.0265x over previous
//
#include <hip/hip_runtime.h>
#include <hip/hip_bf16.h>
#include <hip/hip_fp8.h>
#include <math.h>

typedef __hip_bfloat16 bf16;
typedef __attribute__((ext_vector_type(8))) short short8;
typedef __attribute__((ext_vector_type(4))) float f32x4;

#define NPB   65536   // positions per batch (16*64*64)
#define DIMC  48
#define C2    192
#define HIDC  96
#define TT    16

static __device__ __forceinline__ float b2f(bf16 v) { return __bfloat162float(v); }
static __device__ __forceinline__ bf16  f2b(float v) { return __float2bfloat16(v); }
static __device__ __forceinline__ float bfr2f(unsigned short u) {
  union { unsigned int i; float f; } c; c.i = ((unsigned int)u) << 16; return c.f;
}
static __device__ __forceinline__ unsigned short f2us(float v) {
  return __bfloat16_as_ushort(__float2bfloat16(v));
}
static __device__ __forceinline__ unsigned char f2fp8(float v) {
  __hip_fp8_e4m3 t(v); return (unsigned char)t.__x;
}
static __device__ __forceinline__ float fp82f(unsigned char u) {
  __hip_fp8_e4m3 t; t.__x = (__hip_fp8_storage_t)u; return (float)t;
}

// ---------------- y = LN(x) over 48 channels, bf16 out (LN1 and LN2) -------------
__global__ __launch_bounds__(256) void k_ln(
    const float* __restrict__ x, const float* __restrict__ lw, const float* __restrict__ lb,
    bf16* __restrict__ y) {
  int p = blockIdx.x * 256 + threadIdx.x;   // 0..131071
  int b = p >> 16, n = p & (NPB - 1);
  const float* xb = x + ((size_t)b * DIMC) * NPB + n;
  float v[DIMC]; float s = 0.f, s2 = 0.f;
#pragma unroll
  for (int c = 0; c < DIMC; ++c) { float t = xb[(size_t)c * NPB]; v[c] = t; s += t; s2 += t * t; }
  float mu = s * (1.f / DIMC);
  float var = fmaxf(s2 * (1.f / DIMC) - mu * mu, 0.f);
  float rs = rsqrtf(var + 1e-5f);
  bf16* yb = y + ((size_t)b * DIMC) * NPB + n;
#pragma unroll
  for (int c = 0; c < DIMC; ++c) yb[(size_t)c * NPB] = f2b((v[c] - mu) * rs * lw[c] + lb[c]);
}

// ------- MFMA 1x1 conv, sectioned: out[s*48+m, n] = W_s[m,c] y[c,n] + bias_s[m] ---
// grid (NSEC, 512): x = weight/output section of 48 rows, y = n-tile (256) + batch.
__global__ __launch_bounds__(256) void k_pconv_sec(
    const bf16* __restrict__ y, const float* __restrict__ W, int wso,
    const float* __restrict__ bias, int bso, bf16* __restrict__ dst, int dcs) {
  __shared__ unsigned short Yl[64][258];
  __shared__ unsigned short Wl[48][72];
  int tid = threadIdx.x;
  int s = blockIdx.x;
  int bt = blockIdx.y;
  int b = bt >> 8;
  int n0 = (bt & 255) * 256;
  const unsigned short* yb = (const unsigned short*)(y + ((size_t)b * DIMC) * NPB) + n0;
  for (int j = tid; j < 48 * 64; j += 256) {       // stage Y (48 x 256)
    int c = j >> 6, sub = j & 63;
    ushort4 u = *(const ushort4*)(yb + (size_t)c * NPB + sub * 4);
    *(ushort2*)&Yl[c][sub * 4]     = make_ushort2(u.x, u.y);
    *(ushort2*)&Yl[c][sub * 4 + 2] = make_ushort2(u.z, u.w);
  }
  for (int j = tid; j < 16 * 64; j += 256) {       // zero rows 48..63
    int c = 48 + (j >> 6), sub = j & 63;
    *(ushort2*)&Yl[c][sub * 4]     = make_ushort2(0, 0);
    *(ushort2*)&Yl[c][sub * 4 + 2] = make_ushort2(0, 0);
  }
  if (tid < 48) {
    const float* wr = W + (size_t)s * wso + (size_t)tid * 48;
    unsigned short* wl = Wl[tid];
#pragma unroll
    for (int c = 0; c < 48; ++c) wl[c] = f2us(wr[c]);
#pragma unroll
    for (int c = 48; c < 64; ++c) wl[c] = 0;
  }
  __syncthreads();
  int wv = tid >> 6, ln = tid & 63, lq = ln >> 4, li = ln & 15;
  short8 afr[3][2];
#pragma unroll
  for (int mt = 0; mt < 3; ++mt)
#pragma unroll
    for (int ks = 0; ks < 2; ++ks)
      afr[mt][ks] = *(const short8*)&Wl[mt * 16 + li][ks * 32 + lq * 8];
#pragma unroll 1
  for (int ns = 0; ns < 4; ++ns) {
    int nn = wv * 64 + ns * 16 + li;
    short8 bfr[2];
#pragma unroll
    for (int ks = 0; ks < 2; ++ks)
#pragma unroll
      for (int j = 0; j < 8; ++j)
        bfr[ks][j] = (short)Yl[ks * 32 + lq * 8 + j][nn];
#pragma unroll
    for (int mt = 0; mt < 3; ++mt) {
      f32x4 acc = {0.f, 0.f, 0.f, 0.f};
      acc = __builtin_amdgcn_mfma_f32_16x16x32_bf16(afr[mt][0], bfr[0], acc, 0, 0, 0);
      acc = __builtin_amdgcn_mfma_f32_16x16x32_bf16(afr[mt][1], bfr[1], acc, 0, 0, 0);
#pragma unroll
      for (int r = 0; r < 4; ++r) {
        int m = mt * 16 + lq * 4 + r;
        dst[((size_t)b * dcs + s * 48 + m) * NPB + n0 + nn] = f2b(acc[r] + bias[s * bso + m]);
      }
    }
  }
}

// ------- grouped 3x3x3 conv, LDS-tiled; optional fp8(x16) output ------------------
// grid (32, NG, 2): x = spatial tile (2t x 16h x 64w), y = group of 4 ch, z = batch.
template <bool FP8>
__global__ __launch_bounds__(256) void k_gconv48(
    const bf16* __restrict__ src, int scs, int sco,
    const float* __restrict__ gw, const float* __restrict__ gb, int woA, int woB,
    void* __restrict__ dstv, int dcs,
    float* __restrict__ sqout, int sqA, int sqB) {
  __shared__ unsigned short tile[4][4][18][66];
  __shared__ float red[4][4];
  int tid = threadIdx.x;
  int t0 = (blockIdx.x >> 2) * 2, h0 = (blockIdx.x & 3) * 16;
  int cbase = blockIdx.y * 4, b = blockIdx.z;
  int wo = (cbase < 48) ? woA : woB;   // block-uniform
  const unsigned short* ib = (const unsigned short*)(src + ((size_t)b * scs + sco + cbase) * NPB);
  for (int j = tid; j < 288 * 16; j += 256) {
    int r = j >> 4, sub = j & 15;
    int ci = r / 72, rem = r - ci * 72;
    int tt = rem / 18, hh = rem - tt * 18;
    int gt = t0 + tt - 1, gh = h0 + hh - 1;
    ushort4 val = make_ushort4(0, 0, 0, 0);
    if ((unsigned)gt < 16u && (unsigned)gh < 64u)
      val = *(const ushort4*)(ib + (size_t)ci * NPB + gt * 4096 + gh * 64 + sub * 4);
    unsigned short* dp = &tile[ci][tt][hh][1 + sub * 4];
    dp[0] = val.x; dp[1] = val.y; dp[2] = val.z; dp[3] = val.w;
  }
  for (int j = tid; j < 576; j += 256) {
    int r = j >> 1, side = j & 1;
    int ci = r / 72, rem = r - ci * 72;
    int tt = rem / 18, hh = rem - tt * 18;
    tile[ci][tt][hh][side ? 65 : 0] = 0;
  }
  __syncthreads();
  int w = tid & 63, hr = tid >> 6;
  float acc[2][4][4];
#pragma unroll
  for (int t = 0; t < 2; ++t)
#pragma unroll
    for (int i = 0; i < 4; ++i)
#pragma unroll
      for (int o = 0; o < 4; ++o) acc[t][i][o] = 0.f;
#pragma unroll 1
  for (int ci = 0; ci < 4; ++ci) {
#pragma unroll 1
    for (int dw = 0; dw < 3; ++dw) {
      int wwl = w + dw;
      float v[4][6];
#pragma unroll
      for (int tt = 0; tt < 4; ++tt)
#pragma unroll
        for (int r = 0; r < 6; ++r) v[tt][r] = bfr2f(tile[ci][tt][hr * 4 + r][wwl]);
#pragma unroll
      for (int dt = 0; dt < 3; ++dt)
#pragma unroll
        for (int dh = 0; dh < 3; ++dh) {
          float wv[4];
#pragma unroll
          for (int o = 0; o < 4; ++o)
            wv[o] = gw[(size_t)(cbase + o + wo) * 108 + ci * 27 + dt * 9 + dh * 3 + dw];
#pragma unroll
          for (int t = 0; t < 2; ++t)
#pragma unroll
            for (int i = 0; i < 4; ++i) {
              float vv = v[t + dt][i + dh];
#pragma unroll
              for (int o = 0; o < 4; ++o) acc[t][i][o] = fmaf(wv[o], vv, acc[t][i][o]);
            }
        }
    }
  }
  float s[4] = {0.f, 0.f, 0.f, 0.f};
#pragma unroll
  for (int o = 0; o < 4; ++o) {
    float bias = gb[cbase + o + wo];
    size_t obase = ((size_t)b * dcs + cbase + o) * NPB;
#pragma unroll
    for (int t = 0; t < 2; ++t)
#pragma unroll
      for (int i = 0; i < 4; ++i) {
        size_t oidx = obase + (t0 + t) * 4096 + (h0 + hr * 4 + i) * 64 + w;
        if constexpr (FP8) {
          unsigned char rv = f2fp8(16.f * (acc[t][i][o] + bias));
          ((unsigned char*)dstv)[oidx] = rv;
          if (sqout) { float f = fp82f(rv); s[o] = fmaf(f, f, s[o]); }
        } else {
          bf16 rv = f2b(acc[t][i][o] + bias);
          ((bf16*)dstv)[oidx] = rv;
          float f = b2f(rv);
          s[o] = fmaf(f, f, s[o]);
        }
      }
  }
  if (sqout) {
#pragma unroll
    for (int o = 0; o < 4; ++o) {
      float sv = s[o];
#pragma unroll
      for (int off = 32; off; off >>= 1) sv += __shfl_down(sv, off);
      if ((tid & 63) == 0) red[tid >> 6][o] = sv;
    }
    __syncthreads();
    if (tid < 4) {
      int c = cbase + tid;
      int sqo = (cbase < 48) ? sqA : sqB;
      atomicAdd(&sqout[(size_t)b * 192 + c + sqo],
                red[0][tid] + red[1][tid] + red[2][tid] + red[3][tid]);
    }
  }
}

// ---------------- MFMA Gram from fp8 q,k: G[b4+hd][c][d] += sum_n q[c,n] k[d,n] ---
// grid (64, 2): x = 1024-wide n-chunk, y = batch. Scale (16x)^2 cancels with norms.
__global__ __launch_bounds__(256) void k_gram_mfma(
    const unsigned char* __restrict__ qd, const unsigned char* __restrict__ kd, int bs,
    int hd, float* __restrict__ Gm) {
  __shared__ unsigned short qkl[2][48][264];
  int tid = threadIdx.x, b = blockIdx.y;
  int wv = tid >> 6, ln = tid & 63, lq = ln >> 4, li = ln & 15;
  const unsigned char* qb = qd + ((size_t)b * bs) * NPB + blockIdx.x * 1024;
  const unsigned char* kb = kd + ((size_t)b * bs) * NPB + blockIdx.x * 1024;
  f32x4 acc[9];
#pragma unroll
  for (int t = 0; t < 9; ++t) acc[t] = (f32x4){0.f, 0.f, 0.f, 0.f};
#pragma unroll 1
  for (int it = 0; it < 4; ++it) {
    __syncthreads();
    for (int j = tid; j < 48 * 64; j += 256) {
      int c = j >> 6, sub = j & 63;
      uchar4 uq = *(const uchar4*)(qb + (size_t)c * NPB + it * 256 + sub * 4);
      uchar4 uk = *(const uchar4*)(kb + (size_t)c * NPB + it * 256 + sub * 4);
      *(ushort2*)&qkl[0][c][sub * 4]     = make_ushort2(f2us(fp82f(uq.x)), f2us(fp82f(uq.y)));
      *(ushort2*)&qkl[0][c][sub * 4 + 2] = make_ushort2(f2us(fp82f(uq.z)), f2us(fp82f(uq.w)));
      *(ushort2*)&qkl[1][c][sub * 4]     = make_ushort2(f2us(fp82f(uk.x)), f2us(fp82f(uk.y)));
      *(ushort2*)&qkl[1][c][sub * 4 + 2] = make_ushort2(f2us(fp82f(uk.z)), f2us(fp82f(uk.w)));
    }
    __syncthreads();
    short8 afr[3][2], bfr[3][2];
#pragma unroll
    for (int ks = 0; ks < 2; ++ks) {
      int kbase = wv * 64 + ks * 32 + lq * 8;
#pragma unroll
      for (int t = 0; t < 3; ++t) {
        afr[t][ks] = *(const short8*)&qkl[0][t * 16 + li][kbase];
        bfr[t][ks] = *(const short8*)&qkl[1][t * 16 + li][kbase];
      }
    }
#pragma unroll
    for (int mt = 0; mt < 3; ++mt)
#pragma unroll
      for (int nt = 0; nt < 3; ++nt) {
        acc[mt * 3 + nt] = __builtin_amdgcn_mfma_f32_16x16x32_bf16(afr[mt][0], bfr[nt][0], acc[mt * 3 + nt], 0, 0, 0);
        acc[mt * 3 + nt] = __builtin_amdgcn_mfma_f32_16x16x32_bf16(afr[mt][1], bfr[nt][1], acc[mt * 3 + nt], 0, 0, 0);
      }
  }
  __syncthreads();
  float* red = (float*)&qkl[0][0][0];
  if (wv > 0) {
    float* rw = red + (size_t)(wv - 1) * 2304;
#pragma unroll
    for (int t = 0; t < 9; ++t)
#pragma unroll
      for (int r = 0; r < 4; ++r)
        rw[t * 256 + r * 64 + ln] = acc[t][r];
  }
  __syncthreads();
  if (wv == 0) {
    float* gbase = Gm + (size_t)(b * 4 + hd) * 2304;
#pragma unroll
    for (int t = 0; t < 9; ++t) {
      int mt = t / 3, nt = t - mt * 3;
#pragma unroll
      for (int r = 0; r < 4; ++r) {
        int o = t * 256 + r * 64 + ln;
        float v = acc[t][r] + red[o] + red[2304 + o] + red[4608 + o];
        atomicAdd(&gbase[(mt * 16 + lq * 4 + r) * 48 + nt * 16 + li], v);
      }
    }
  }
}

// ------- ONE-SHOT attention: out = x + proj_b + sum_h M_h @ v8_h (fp8 v, x16) -----
// grid (512). Per block: per-head softmax+proj fold (tiny, redundant), acc in regs.
__global__ __launch_bounds__(256) void k_attn_final(
    const unsigned char* __restrict__ vd8, const float* __restrict__ Gm,
    const float* __restrict__ sq, const float* __restrict__ temp,
    const float* __restrict__ pw, const float* __restrict__ pb,
    const float* __restrict__ x, float* __restrict__ outp) {
  __shared__ unsigned short Yl[64][258];
  __shared__ unsigned short Ml[48][72];
  __shared__ float A[48][48];
  __shared__ float nk[48];
  int tid = threadIdx.x;
  int bt = blockIdx.x;
  int b = bt >> 8;
  int n0 = (bt & 255) * 256;
  int wv = tid >> 6, ln = tid & 63, lq = ln >> 4, li = ln & 15;
  for (int j = tid; j < 16 * 64; j += 256) {       // zero Yl rows 48..63 (persist)
    int c = 48 + (j >> 6), sub = j & 63;
    *(ushort2*)&Yl[c][sub * 4]     = make_ushort2(0, 0);
    *(ushort2*)&Yl[c][sub * 4 + 2] = make_ushort2(0, 0);
  }
  f32x4 acc[3][4];
#pragma unroll
  for (int mt = 0; mt < 3; ++mt)
#pragma unroll
    for (int ns = 0; ns < 4; ++ns) acc[mt][ns] = (f32x4){0.f, 0.f, 0.f, 0.f};
#pragma unroll 1
  for (int hd = 0; hd < 4; ++hd) {
    int bh = b * 4 + hd;
    __syncthreads();                                // previous iter's reads done
    const unsigned char* vb = vd8 + ((size_t)bh * 48) * NPB + n0;
    for (int j = tid; j < 48 * 64; j += 256) {      // stage v8 -> bf16 LDS
      int c = j >> 6, sub = j & 63;
      uchar4 u = *(const uchar4*)(vb + (size_t)c * NPB + sub * 4);
      *(ushort2*)&Yl[c][sub * 4]     = make_ushort2(f2us(fp82f(u.x)), f2us(fp82f(u.y)));
      *(ushort2*)&Yl[c][sub * 4 + 2] = make_ushort2(f2us(fp82f(u.z)), f2us(fp82f(u.w)));
    }
    if (tid >= 64 && tid < 112)
      nk[tid - 64] = fmaxf(sqrtf(sq[384 + bh * 48 + tid - 64]), 1e-12f);
    __syncthreads();
    if (tid < 48) {                                 // softmax row (3-pass, no row[])
      float tv = temp[hd];
      float rq = 1.f / fmaxf(sqrtf(sq[bh * 48 + tid]), 1e-12f);
      const float* grow = Gm + (size_t)bh * 2304 + tid * 48;
      float mx = -1e30f;
#pragma unroll
      for (int d = 0; d < 48; ++d) mx = fmaxf(mx, grow[d] * rq / nk[d] * tv);
      float sum = 0.f;
#pragma unroll
      for (int d = 0; d < 48; ++d) {
        float e = expf(grow[d] * rq / nk[d] * tv - mx);
        A[tid][d] = e; sum += e;
      }
      float inv = 1.f / sum;
#pragma unroll
      for (int d = 0; d < 48; ++d) A[tid][d] *= inv;
    }
    __syncthreads();
    for (int j = tid; j < 48 * 64; j += 256) {      // fold M = (pw_h @ A) / 16
      int m = j >> 6, d = j & 63;
      float a = 0.f;
      if (d < 48) {
#pragma unroll
        for (int c = 0; c < 48; ++c) a = fmaf(pw[m * 192 + hd * 48 + c], A[c][d], a);
      }
      Ml[m][d] = f2us(a * 0.0625f);
    }
    __syncthreads();
    short8 afr[3][2];
#pragma unroll
    for (int mt = 0; mt < 3; ++mt)
#pragma unroll
      for (int ks = 0; ks < 2; ++ks)
        afr[mt][ks] = *(const short8*)&Ml[mt * 16 + li][ks * 32 + lq * 8];
#pragma unroll 1
    for (int ns = 0; ns < 4; ++ns) {
      int nn = wv * 64 + ns * 16 + li;
      short8 bfr[2];
#pragma unroll
      for (int ks = 0; ks < 2; ++ks)
#pragma unroll
        for (int j = 0; j < 8; ++j)
          bfr[ks][j] = (short)Yl[ks * 32 + lq * 8 + j][nn];
#pragma unroll
      for (int mt = 0; mt < 3; ++mt) {
        acc[mt][ns] = __builtin_amdgcn_mfma_f32_16x16x32_bf16(afr[mt][0], bfr[0], acc[mt][ns], 0, 0, 0);
        acc[mt][ns] = __builtin_amdgcn_mfma_f32_16x16x32_bf16(afr[mt][1], bfr[1], acc[mt][ns], 0, 0, 0);
      }
    }
  }
#pragma unroll
  for (int ns = 0; ns < 4; ++ns) {
    int nn = wv * 64 + ns * 16 + li;
#pragma unroll
    for (int mt = 0; mt < 3; ++mt)
#pragma unroll
      for (int r = 0; r < 4; ++r) {
        int m = mt * 16 + lq * 4 + r;
        size_t idx = ((size_t)b * DIMC + m) * NPB + n0 + nn;
        outp[idx] = x[idx] + pb[m] + acc[mt][ns][r];
      }
  }
}

// ---------------- MFMA K=96 GEMM + fp32 epilogue (pout): out = addend+bias+W@V ----
__global__ __launch_bounds__(256) void k_ek96(
    const bf16* __restrict__ V, const float* __restrict__ W, int wrs,
    const float* __restrict__ bias, const float* __restrict__ addend, float* __restrict__ outp) {
  __shared__ unsigned short Yl[96][258];
  __shared__ unsigned short Wl[48][104];
  int tid = threadIdx.x;
  int bt = blockIdx.x;
  int b = bt >> 8;
  int n0 = (bt & 255) * 256;
  const unsigned short* vb = (const unsigned short*)(V + ((size_t)b * 96) * NPB) + n0;
  for (int j = tid; j < 96 * 64; j += 256) {
    int c = j >> 6, sub = j & 63;
    ushort4 u = *(const ushort4*)(vb + (size_t)c * NPB + sub * 4);
    *(ushort2*)&Yl[c][sub * 4]     = make_ushort2(u.x, u.y);
    *(ushort2*)&Yl[c][sub * 4 + 2] = make_ushort2(u.z, u.w);
  }
  if (tid < 48) {
    const float* wr = W + (size_t)tid * wrs;
    unsigned short* wl = Wl[tid];
#pragma unroll
    for (int c = 0; c < 96; ++c) wl[c] = f2us(wr[c]);
  }
  __syncthreads();
  int wv = tid >> 6, ln = tid & 63, lq = ln >> 4, li = ln & 15;
  short8 afr[3][3];
#pragma unroll
  for (int mt = 0; mt < 3; ++mt)
#pragma unroll
    for (int ks = 0; ks < 3; ++ks)
      afr[mt][ks] = *(const short8*)&Wl[mt * 16 + li][ks * 32 + lq * 8];
#pragma unroll 1
  for (int ns = 0; ns < 4; ++ns) {
    int nn = wv * 64 + ns * 16 + li;
    short8 bfr[3];
#pragma unroll
    for (int ks = 0; ks < 3; ++ks)
#pragma unroll
      for (int j = 0; j < 8; ++j)
        bfr[ks][j] = (short)Yl[ks * 32 + lq * 8 + j][nn];
#pragma unroll
    for (int mt = 0; mt < 3; ++mt) {
      f32x4 acc = {0.f, 0.f, 0.f, 0.f};
      acc = __builtin_amdgcn_mfma_f32_16x16x32_bf16(afr[mt][0], bfr[0], acc, 0, 0, 0);
      acc = __builtin_amdgcn_mfma_f32_16x16x32_bf16(afr[mt][1], bfr[1], acc, 0, 0, 0);
      acc = __builtin_amdgcn_mfma_f32_16x16x32_bf16(afr[mt][2], bfr[2], acc, 0, 0, 0);
#pragma unroll
      for (int r = 0; r < 4; ++r) {
        int m = mt * 16 + lq * 4 + r;
        size_t idx = ((size_t)b * DIMC + m) * NPB + n0 + nn;
        outp[idx] = acc[r] + addend[idx] + bias[m];
      }
    }
  }
}

// ------- depthwise 3x3x3 + exact GELU gate, LDS-tiled (R4 config: 2t x 16h) -------
// grid (32, 96, 2): x = spatial tile, y = ch pair, z = batch
__global__ __launch_bounds__(256) void k_dw_gelu(
    const bf16* __restrict__ z, const float* __restrict__ dwW, const float* __restrict__ dwB,
    bf16* __restrict__ g) {
  __shared__ unsigned short tile[2][4][18][66];
  int tid = threadIdx.x;
  int t0 = (blockIdx.x >> 2) * 2, h0 = (blockIdx.x & 3) * 16;
  int c = blockIdx.y, b = blockIdx.z;
  const unsigned short* z1 = (const unsigned short*)(z + ((size_t)b * C2 + c) * NPB);
  const unsigned short* z2 = (const unsigned short*)(z + ((size_t)b * C2 + c + HIDC) * NPB);
  for (int j = tid; j < 144 * 16; j += 256) {
    int r = j >> 4, sub = j & 15;
    int ch = r / 72, rem = r - ch * 72;
    int tt = rem / 18, hh = rem - tt * 18;
    int gt = t0 + tt - 1, gh = h0 + hh - 1;
    ushort4 val = make_ushort4(0, 0, 0, 0);
    const unsigned short* sp = ch ? z2 : z1;
    if ((unsigned)gt < 16u && (unsigned)gh < 64u)
      val = *(const ushort4*)(sp + gt * 4096 + gh * 64 + sub * 4);
    unsigned short* dp = &tile[ch][tt][hh][1 + sub * 4];
    dp[0] = val.x; dp[1] = val.y; dp[2] = val.z; dp[3] = val.w;
  }
  for (int j = tid; j < 288; j += 256) {
    int r = j >> 1, side = j & 1;
    int ch = r / 72, rem = r - ch * 72;
    int tt = rem / 18, hh = rem - tt * 18;
    tile[ch][tt][hh][side ? 65 : 0] = 0;
  }
  __syncthreads();
  int w = tid & 63, hr = tid >> 6;
  float a[2][2][4];
#pragma unroll
  for (int ch = 0; ch < 2; ++ch)
#pragma unroll
    for (int t = 0; t < 2; ++t)
#pragma unroll
      for (int i = 0; i < 4; ++i) a[ch][t][i] = 0.f;
#pragma unroll
  for (int ch = 0; ch < 2; ++ch) {
    const float* wt = dwW + (size_t)(c + ch * HIDC) * 27;
#pragma unroll 1
    for (int dw = 0; dw < 3; ++dw) {
      int wwl = w + dw;
      float v[4][6];
#pragma unroll
      for (int tt = 0; tt < 4; ++tt)
#pragma unroll
        for (int r = 0; r < 6; ++r) v[tt][r] = bfr2f(tile[ch][tt][hr * 4 + r][wwl]);
#pragma unroll
      for (int dt = 0; dt < 3; ++dt)
#pragma unroll
        for (int dh = 0; dh < 3; ++dh) {
          float wv = wt[dt * 9 + dh * 3 + dw];
#pragma unroll
          for (int t = 0; t < 2; ++t)
#pragma unroll
            for (int i = 0; i < 4; ++i)
              a[ch][t][i] = fmaf(wv, v[t + dt][i + dh], a[ch][t][i]);
        }
    }
  }
  float b1 = dwB[c], b2v = dwB[c + HIDC];
  size_t obase = ((size_t)b * HIDC + c) * NPB;
#pragma unroll
  for (int t = 0; t < 2; ++t)
#pragma unroll
    for (int i = 0; i < 4; ++i) {
      float x1v = a[0][t][i] + b1;
      float x2v = a[1][t][i] + b2v;
      float ge = 0.5f * x1v * (1.f + erff(x1v * 0.70710678118654752f));
      g[obase + (t0 + t) * 4096 + (h0 + hr * 4 + i) * 64 + w] = f2b(ge * x2v);
    }
}

extern "C" void kernel_launch(void* const* d_in, const int* in_sizes, int n_in,
                              void* d_out, int out_size, void* d_ws, size_t ws_size,
                              hipStream_t stream) {
  (void)in_sizes; (void)n_in; (void)out_size; (void)ws_size;
  const float* x     = (const float*)d_in[0];
  const float* ln1w  = (const float*)d_in[1];
  const float* ln1b  = (const float*)d_in[2];
  const float* qkvw  = (const float*)d_in[3];
  const float* qkvb  = (const float*)d_in[4];
  const float* gdww  = (const float*)d_in[5];
  const float* gdwb  = (const float*)d_in[6];
  const float* temp  = (const float*)d_in[7];
  const float* projw = (const float*)d_in[8];
  const float* projb = (const float*)d_in[9];
  const float* ln2w  = (const float*)d_in[10];
  const float* ln2b  = (const float*)d_in[11];
  const float* pinw  = (const float*)d_in[12];
  const float* pinb  = (const float*)d_in[13];
  const float* dww   = (const float*)d_in[14];
  const float* dwb   = (const float*)d_in[15];
  const float* poutw = (const float*)d_in[16];
  const float* poutb = (const float*)d_in[17];
  float* out = (float*)d_out;

  // Workspace layout — peak 75,574,272 B (same as proven-safe R4/R5):
  char* ws = (char*)d_ws;
  bf16*  y     = (bf16*)(ws);                       // 12,582,912 B  LN output
  bf16*  st96  = (bf16*)(ws + 12582912);            // 25,165,824 B  [2][96][NPB] qk stage
  bf16*  st48  = (bf16*)(ws + 12582912);            // 12,582,912 B  [2][48][NPB] v stage (reuse)
  unsigned char* qkd8 = (unsigned char*)(ws + 37748736); // 12,582,912 B [2][96][NPB] fp8
  unsigned char* vd8  = (unsigned char*)(ws + 50331648); // 25,165,824 B [2][4][48][NPB] fp8
  float* Gm    = (float*)(ws + 75497472);           //     73,728 B
  float* sq    = (float*)(ws + 75571200);           //      3,072 B
  // FFN phase (attention buffers dead):
  bf16*  z     = (bf16*)(ws);                       // 50,331,648 B  [2][192][NPB]
  bf16*  y2    = (bf16*)(ws + 50331648);            // 12,582,912 B  LN2 output
  bf16*  gg    = (bf16*)(ws + 50331648);            // 25,165,824 B  (over y2 after pin)

  hipMemsetAsync(Gm, 0, 73728 + 3072, stream);
  k_ln<<<dim3(512), dim3(256), 0, stream>>>(x, ln1w, ln1b, y);

  for (int h = 0; h < 4; ++h) {
    // q,k pointwise (sections 0,1 -> rows h*48 and 192+h*48)
    k_pconv_sec<<<dim3(2, 512), dim3(256), 0, stream>>>(
        y, qkvw + (size_t)h * 2304, 9216, qkvb + h * 48, 192, st96, 96);
    // grouped dw-conv q+k -> fp8 (x16) + sumsq of decoded values
    k_gconv48<true><<<dim3(32, 24, 2), dim3(256), 0, stream>>>(
        st96, 96, 0, gdww, gdwb, h * 48, 144 + h * 48, qkd8, 96,
        sq, h * 48, 336 + h * 48);
    k_gram_mfma<<<dim3(64, 2), dim3(256), 0, stream>>>(qkd8, qkd8 + (size_t)48 * NPB, 96, h, Gm);
    // v pointwise + grouped dw-conv -> fp8 (x16) into per-head vd8 slot
    k_pconv_sec<<<dim3(1, 512), dim3(256), 0, stream>>>(
        y, qkvw + 18432 + (size_t)h * 2304, 0, qkvb + 384 + h * 48, 0, st48, 48);
    k_gconv48<true><<<dim3(32, 12, 2), dim3(256), 0, stream>>>(
        st48, 48, 0, gdww, gdwb, 384 + h * 48, 0, vd8 + (size_t)h * 48 * NPB, 192,
        nullptr, 0, 0);
  }
  // one-shot: out = x + proj_b + sum_h M_h @ v_h
  k_attn_final<<<dim3(512), dim3(256), 0, stream>>>(vd8, Gm, sq, temp, projw, projb, x, out);

  k_ln<<<dim3(512), dim3(256), 0, stream>>>(out, ln2w, ln2b, y2);
  k_pconv_sec<<<dim3(4, 512), dim3(256), 0, stream>>>(y2, pinw, 2304, pinb, 48, z, 192);
  k_dw_gelu<<<dim3(32, 96, 2), dim3(256), 0, stream>>>(z, dww, dwb, gg);
  k_ek96<<<dim3(512), dim3(256), 0, stream>>>(gg, poutw, 96, poutb, out, out);
}

// Round 7
// 791.573 us; speedup vs baseline: 5.7330x; 1.0764x over previous
//
#include <hip/hip_runtime.h>
#include <hip/hip_bf16.h>
#include <hip/hip_fp8.h>
#include <math.h>

typedef __hip_bfloat16 bf16;
typedef __attribute__((ext_vector_type(8))) short short8;
typedef __attribute__((ext_vector_type(4))) float f32x4;

#define NPB   65536   // positions per batch (16*64*64)
#define DIMC  48
#define C2    192
#define HIDC  96
#define TT    16

static __device__ __forceinline__ float b2f(bf16 v) { return __bfloat162float(v); }
static __device__ __forceinline__ bf16  f2b(float v) { return __float2bfloat16(v); }
static __device__ __forceinline__ float bfr2f(unsigned short u) {
  union { unsigned int i; float f; } c; c.i = ((unsigned int)u) << 16; return c.f;
}
static __device__ __forceinline__ unsigned short f2us(float v) {
  return __bfloat16_as_ushort(__float2bfloat16(v));
}
static __device__ __forceinline__ unsigned char f2fp8(float v) {
  __hip_fp8_e4m3 t(v); return (unsigned char)t.__x;
}
static __device__ __forceinline__ float fp82f(unsigned char u) {
  __hip_fp8_e4m3 t; t.__x = (__hip_fp8_storage_t)u; return (float)t;
}

// ---------------- y = LN(x) over 48 channels, bf16 out (LN1 and LN2) -------------
__global__ __launch_bounds__(256) void k_ln(
    const float* __restrict__ x, const float* __restrict__ lw, const float* __restrict__ lb,
    bf16* __restrict__ y) {
  int p = blockIdx.x * 256 + threadIdx.x;   // 0..131071
  int b = p >> 16, n = p & (NPB - 1);
  const float* xb = x + ((size_t)b * DIMC) * NPB + n;
  float v[DIMC]; float s = 0.f, s2 = 0.f;
#pragma unroll
  for (int c = 0; c < DIMC; ++c) { float t = xb[(size_t)c * NPB]; v[c] = t; s += t; s2 += t * t; }
  float mu = s * (1.f / DIMC);
  float var = fmaxf(s2 * (1.f / DIMC) - mu * mu, 0.f);
  float rs = rsqrtf(var + 1e-5f);
  bf16* yb = y + ((size_t)b * DIMC) * NPB + n;
#pragma unroll
  for (int c = 0; c < DIMC; ++c) yb[(size_t)c * NPB] = f2b((v[c] - mu) * rs * lw[c] + lb[c]);
}

// ------- MFMA 1x1 conv, sectioned, fp8(x16) out. n-tile 128, grid (NSEC, 1024) ----
__global__ __launch_bounds__(256) void k_pconv_sec(
    const bf16* __restrict__ y, const float* __restrict__ W, int wso,
    const float* __restrict__ bias, int bso, unsigned char* __restrict__ dst, int dcs) {
  __shared__ unsigned short Yl[64][130];
  __shared__ unsigned short Wl[48][72];
  int tid = threadIdx.x;
  int s = blockIdx.x;
  int bt = blockIdx.y;
  int b = bt >> 9;
  int n0 = (bt & 511) * 128;
  const unsigned short* yb = (const unsigned short*)(y + ((size_t)b * DIMC) * NPB) + n0;
  for (int j = tid; j < 48 * 32; j += 256) {       // stage Y (48 x 128)
    int c = j >> 5, sub = j & 31;
    ushort4 u = *(const ushort4*)(yb + (size_t)c * NPB + sub * 4);
    *(ushort2*)&Yl[c][sub * 4]     = make_ushort2(u.x, u.y);
    *(ushort2*)&Yl[c][sub * 4 + 2] = make_ushort2(u.z, u.w);
  }
  for (int j = tid; j < 16 * 32; j += 256) {       // zero rows 48..63
    int c = 48 + (j >> 5), sub = j & 31;
    *(ushort2*)&Yl[c][sub * 4]     = make_ushort2(0, 0);
    *(ushort2*)&Yl[c][sub * 4 + 2] = make_ushort2(0, 0);
  }
  if (tid < 48) {
    const float* wr = W + (size_t)s * wso + (size_t)tid * 48;
    unsigned short* wl = Wl[tid];
#pragma unroll
    for (int c = 0; c < 48; ++c) wl[c] = f2us(wr[c]);
#pragma unroll
    for (int c = 48; c < 64; ++c) wl[c] = 0;
  }
  __syncthreads();
  int wv = tid >> 6, ln = tid & 63, lq = ln >> 4, li = ln & 15;
  short8 afr[3][2];
#pragma unroll
  for (int mt = 0; mt < 3; ++mt)
#pragma unroll
    for (int ks = 0; ks < 2; ++ks)
      afr[mt][ks] = *(const short8*)&Wl[mt * 16 + li][ks * 32 + lq * 8];
#pragma unroll 1
  for (int ns = 0; ns < 2; ++ns) {
    int nn = wv * 32 + ns * 16 + li;
    short8 bfr[2];
#pragma unroll
    for (int ks = 0; ks < 2; ++ks)
#pragma unroll
      for (int j = 0; j < 8; ++j)
        bfr[ks][j] = (short)Yl[ks * 32 + lq * 8 + j][nn];
#pragma unroll
    for (int mt = 0; mt < 3; ++mt) {
      f32x4 acc = {0.f, 0.f, 0.f, 0.f};
      acc = __builtin_amdgcn_mfma_f32_16x16x32_bf16(afr[mt][0], bfr[0], acc, 0, 0, 0);
      acc = __builtin_amdgcn_mfma_f32_16x16x32_bf16(afr[mt][1], bfr[1], acc, 0, 0, 0);
#pragma unroll
      for (int r = 0; r < 4; ++r) {
        int m = mt * 16 + lq * 4 + r;
        dst[((size_t)b * dcs + s * 48 + m) * NPB + n0 + nn] =
            f2fp8(16.f * (acc[r] + bias[s * bso + m]));
      }
    }
  }
}

// ------- grouped 3x3x3 conv, LDS-tiled; fp8(x16) in AND out; optional sumsq -------
// grid (32, NG, 2). Input values carry x16 scale; bias scaled x16 in-kernel.
__global__ __launch_bounds__(256) void k_gconv48(
    const unsigned char* __restrict__ src, int scs, int sco,
    const float* __restrict__ gw, const float* __restrict__ gb, int woA, int woB,
    unsigned char* __restrict__ dst, int dcs,
    float* __restrict__ sqout, int sqA, int sqB) {
  __shared__ unsigned short tile[4][4][18][66];
  __shared__ float red[4][4];
  int tid = threadIdx.x;
  int t0 = (blockIdx.x >> 2) * 2, h0 = (blockIdx.x & 3) * 16;
  int cbase = blockIdx.y * 4, b = blockIdx.z;
  int wo = (cbase < 48) ? woA : woB;   // block-uniform
  const unsigned char* ib = src + ((size_t)b * scs + sco + cbase) * NPB;
  for (int j = tid; j < 288 * 16; j += 256) {
    int r = j >> 4, sub = j & 15;
    int ci = r / 72, rem = r - ci * 72;
    int tt = rem / 18, hh = rem - tt * 18;
    int gt = t0 + tt - 1, gh = h0 + hh - 1;
    unsigned short* dp = &tile[ci][tt][hh][1 + sub * 4];
    if ((unsigned)gt < 16u && (unsigned)gh < 64u) {
      uchar4 u = *(const uchar4*)(ib + (size_t)ci * NPB + gt * 4096 + gh * 64 + sub * 4);
      dp[0] = f2us(fp82f(u.x)); dp[1] = f2us(fp82f(u.y));
      dp[2] = f2us(fp82f(u.z)); dp[3] = f2us(fp82f(u.w));
    } else {
      dp[0] = 0; dp[1] = 0; dp[2] = 0; dp[3] = 0;
    }
  }
  for (int j = tid; j < 576; j += 256) {
    int r = j >> 1, side = j & 1;
    int ci = r / 72, rem = r - ci * 72;
    int tt = rem / 18, hh = rem - tt * 18;
    tile[ci][tt][hh][side ? 65 : 0] = 0;
  }
  __syncthreads();
  int w = tid & 63, hr = tid >> 6;
  float acc[2][4][4];
#pragma unroll
  for (int t = 0; t < 2; ++t)
#pragma unroll
    for (int i = 0; i < 4; ++i)
#pragma unroll
      for (int o = 0; o < 4; ++o) acc[t][i][o] = 0.f;
#pragma unroll 1
  for (int ci = 0; ci < 4; ++ci) {
#pragma unroll 1
    for (int dw = 0; dw < 3; ++dw) {
      int wwl = w + dw;
      float v[4][6];
#pragma unroll
      for (int tt = 0; tt < 4; ++tt)
#pragma unroll
        for (int r = 0; r < 6; ++r) v[tt][r] = bfr2f(tile[ci][tt][hr * 4 + r][wwl]);
#pragma unroll
      for (int dt = 0; dt < 3; ++dt)
#pragma unroll
        for (int dh = 0; dh < 3; ++dh) {
          float wv[4];
#pragma unroll
          for (int o = 0; o < 4; ++o)
            wv[o] = gw[(size_t)(cbase + o + wo) * 108 + ci * 27 + dt * 9 + dh * 3 + dw];
#pragma unroll
          for (int t = 0; t < 2; ++t)
#pragma unroll
            for (int i = 0; i < 4; ++i) {
              float vv = v[t + dt][i + dh];
#pragma unroll
              for (int o = 0; o < 4; ++o) acc[t][i][o] = fmaf(wv[o], vv, acc[t][i][o]);
            }
        }
    }
  }
  float s[4] = {0.f, 0.f, 0.f, 0.f};
#pragma unroll
  for (int o = 0; o < 4; ++o) {
    float bias16 = 16.f * gb[cbase + o + wo];   // input scale is x16
    size_t obase = ((size_t)b * dcs + cbase + o) * NPB;
#pragma unroll
    for (int t = 0; t < 2; ++t)
#pragma unroll
      for (int i = 0; i < 4; ++i) {
        unsigned char rv = f2fp8(acc[t][i][o] + bias16);   // stays at x16 scale
        dst[obase + (t0 + t) * 4096 + (h0 + hr * 4 + i) * 64 + w] = rv;
        if (sqout) { float f = fp82f(rv); s[o] = fmaf(f, f, s[o]); }
      }
  }
  if (sqout) {
#pragma unroll
    for (int o = 0; o < 4; ++o) {
      float sv = s[o];
#pragma unroll
      for (int off = 32; off; off >>= 1) sv += __shfl_down(sv, off);
      if ((tid & 63) == 0) red[tid >> 6][o] = sv;
    }
    __syncthreads();
    if (tid < 4) {
      int c = cbase + tid;
      int sqo = (cbase < 48) ? sqA : sqB;
      atomicAdd(&sqout[(size_t)b * 192 + c + sqo],
                red[0][tid] + red[1][tid] + red[2][tid] + red[3][tid]);
    }
  }
}

// ---------------- MFMA Gram from fp8 q,k (x16): scale cancels with norms ----------
// grid (64, 2): x = 1024-wide n-chunk, y = batch.
__global__ __launch_bounds__(256) void k_gram_mfma(
    const unsigned char* __restrict__ qd, const unsigned char* __restrict__ kd, int bs,
    int hd, float* __restrict__ Gm) {
  __shared__ unsigned short qkl[2][48][264];
  int tid = threadIdx.x, b = blockIdx.y;
  int wv = tid >> 6, ln = tid & 63, lq = ln >> 4, li = ln & 15;
  const unsigned char* qb = qd + ((size_t)b * bs) * NPB + blockIdx.x * 1024;
  const unsigned char* kb = kd + ((size_t)b * bs) * NPB + blockIdx.x * 1024;
  f32x4 acc[9];
#pragma unroll
  for (int t = 0; t < 9; ++t) acc[t] = (f32x4){0.f, 0.f, 0.f, 0.f};
#pragma unroll 1
  for (int it = 0; it < 4; ++it) {
    __syncthreads();
    for (int j = tid; j < 48 * 64; j += 256) {
      int c = j >> 6, sub = j & 63;
      uchar4 uq = *(const uchar4*)(qb + (size_t)c * NPB + it * 256 + sub * 4);
      uchar4 uk = *(const uchar4*)(kb + (size_t)c * NPB + it * 256 + sub * 4);
      *(ushort2*)&qkl[0][c][sub * 4]     = make_ushort2(f2us(fp82f(uq.x)), f2us(fp82f(uq.y)));
      *(ushort2*)&qkl[0][c][sub * 4 + 2] = make_ushort2(f2us(fp82f(uq.z)), f2us(fp82f(uq.w)));
      *(ushort2*)&qkl[1][c][sub * 4]     = make_ushort2(f2us(fp82f(uk.x)), f2us(fp82f(uk.y)));
      *(ushort2*)&qkl[1][c][sub * 4 + 2] = make_ushort2(f2us(fp82f(uk.z)), f2us(fp82f(uk.w)));
    }
    __syncthreads();
    short8 afr[3][2], bfr[3][2];
#pragma unroll
    for (int ks = 0; ks < 2; ++ks) {
      int kbase = wv * 64 + ks * 32 + lq * 8;
#pragma unroll
      for (int t = 0; t < 3; ++t) {
        afr[t][ks] = *(const short8*)&qkl[0][t * 16 + li][kbase];
        bfr[t][ks] = *(const short8*)&qkl[1][t * 16 + li][kbase];
      }
    }
#pragma unroll
    for (int mt = 0; mt < 3; ++mt)
#pragma unroll
      for (int nt = 0; nt < 3; ++nt) {
        acc[mt * 3 + nt] = __builtin_amdgcn_mfma_f32_16x16x32_bf16(afr[mt][0], bfr[nt][0], acc[mt * 3 + nt], 0, 0, 0);
        acc[mt * 3 + nt] = __builtin_amdgcn_mfma_f32_16x16x32_bf16(afr[mt][1], bfr[nt][1], acc[mt * 3 + nt], 0, 0, 0);
      }
  }
  __syncthreads();
  float* red = (float*)&qkl[0][0][0];
  if (wv > 0) {
    float* rw = red + (size_t)(wv - 1) * 2304;
#pragma unroll
    for (int t = 0; t < 9; ++t)
#pragma unroll
      for (int r = 0; r < 4; ++r)
        rw[t * 256 + r * 64 + ln] = acc[t][r];
  }
  __syncthreads();
  if (wv == 0) {
    float* gbase = Gm + (size_t)(b * 4 + hd) * 2304;
#pragma unroll
    for (int t = 0; t < 9; ++t) {
      int mt = t / 3, nt = t - mt * 3;
#pragma unroll
      for (int r = 0; r < 4; ++r) {
        int o = t * 256 + r * 64 + ln;
        float v = acc[t][r] + red[o] + red[2304 + o] + red[4608 + o];
        atomicAdd(&gbase[(mt * 16 + lq * 4 + r) * 48 + nt * 16 + li], v);
      }
    }
  }
}

// ------- tiny: per-(b,head) softmax(norm G) + proj fold -> Mm[b][48][192] bf16 ----
// grid (8). Mm carries 1/16 to cancel v8's x16.
__global__ __launch_bounds__(256) void k_attn_mm(
    const float* __restrict__ Gm, const float* __restrict__ sq, const float* __restrict__ temp,
    const float* __restrict__ pw, bf16* __restrict__ Mm) {
  __shared__ float A[48][48];
  __shared__ float nk[48];
  int tid = threadIdx.x;
  int bh = blockIdx.x; int b = bh >> 2, hd = bh & 3;
  if (tid >= 64 && tid < 112)
    nk[tid - 64] = fmaxf(sqrtf(sq[384 + bh * 48 + tid - 64]), 1e-12f);
  __syncthreads();
  if (tid < 48) {
    float tv = temp[hd];
    float rq = 1.f / fmaxf(sqrtf(sq[bh * 48 + tid]), 1e-12f);
    const float* grow = Gm + (size_t)bh * 2304 + tid * 48;
    float mx = -1e30f;
#pragma unroll
    for (int d = 0; d < 48; ++d) mx = fmaxf(mx, grow[d] * rq / nk[d] * tv);
    float sum = 0.f;
#pragma unroll
    for (int d = 0; d < 48; ++d) {
      float e = expf(grow[d] * rq / nk[d] * tv - mx);
      A[tid][d] = e; sum += e;
    }
    float inv = 1.f / sum;
#pragma unroll
    for (int d = 0; d < 48; ++d) A[tid][d] *= inv;
  }
  __syncthreads();
  for (int j = tid; j < 2304; j += 256) {
    int m = j / 48, d = j - m * 48;
    float a = 0.f;
#pragma unroll
    for (int c = 0; c < 48; ++c) a = fmaf(pw[m * 192 + hd * 48 + c], A[c][d], a);
    Mm[((size_t)b * 48 + m) * 192 + hd * 48 + d] = f2b(a * 0.0625f);
  }
}

// ------- K=192 GEMM: out = x + pb + Mm[b] @ v8[b]  (fp8 v, bf16 MFMA) -------------
// grid (1024): n-tile 128. K staged in two 96-row halves.
__global__ __launch_bounds__(256) void k_av192(
    const unsigned char* __restrict__ vd8, const bf16* __restrict__ Mm,
    const float* __restrict__ pb, const float* __restrict__ x, float* __restrict__ outp) {
  __shared__ unsigned short Yl[96][130];
  __shared__ unsigned short Ml[48][200];
  int tid = threadIdx.x;
  int bt = blockIdx.x;
  int b = bt >> 9;
  int n0 = (bt & 511) * 128;
  int wv = tid >> 6, ln = tid & 63, lq = ln >> 4, li = ln & 15;
  const unsigned short* mb = (const unsigned short*)(Mm + (size_t)b * 48 * 192);
  for (int j = tid; j < 48 * 48; j += 256) {       // stage M (48 x 192)
    int m = j / 48, c4 = j - m * 48;
    *(ushort4*)&Ml[m][c4 * 4] = *(const ushort4*)(mb + m * 192 + c4 * 4);
  }
  const unsigned char* vb = vd8 + ((size_t)b * C2) * NPB + n0;
  f32x4 acc[3][2];
#pragma unroll
  for (int mt = 0; mt < 3; ++mt)
#pragma unroll
    for (int ns = 0; ns < 2; ++ns) acc[mt][ns] = (f32x4){0.f, 0.f, 0.f, 0.f};
#pragma unroll 1
  for (int s = 0; s < 2; ++s) {
    __syncthreads();
    for (int j = tid; j < 96 * 32; j += 256) {     // stage V half (96 x 128), decode
      int c = j >> 5, sub = j & 31;
      uchar4 u = *(const uchar4*)(vb + (size_t)(s * 96 + c) * NPB + sub * 4);
      *(ushort2*)&Yl[c][sub * 4]     = make_ushort2(f2us(fp82f(u.x)), f2us(fp82f(u.y)));
      *(ushort2*)&Yl[c][sub * 4 + 2] = make_ushort2(f2us(fp82f(u.z)), f2us(fp82f(u.w)));
    }
    __syncthreads();
#pragma unroll 1
    for (int ns = 0; ns < 2; ++ns) {
      int nn = wv * 32 + ns * 16 + li;
      short8 bfr[3];
#pragma unroll
      for (int ks = 0; ks < 3; ++ks)
#pragma unroll
        for (int j = 0; j < 8; ++j)
          bfr[ks][j] = (short)Yl[ks * 32 + lq * 8 + j][nn];
#pragma unroll
      for (int mt = 0; mt < 3; ++mt) {
        short8 a0 = *(const short8*)&Ml[mt * 16 + li][s * 96 + lq * 8];
        short8 a1 = *(const short8*)&Ml[mt * 16 + li][s * 96 + 32 + lq * 8];
        short8 a2 = *(const short8*)&Ml[mt * 16 + li][s * 96 + 64 + lq * 8];
        acc[mt][ns] = __builtin_amdgcn_mfma_f32_16x16x32_bf16(a0, bfr[0], acc[mt][ns], 0, 0, 0);
        acc[mt][ns] = __builtin_amdgcn_mfma_f32_16x16x32_bf16(a1, bfr[1], acc[mt][ns], 0, 0, 0);
        acc[mt][ns] = __builtin_amdgcn_mfma_f32_16x16x32_bf16(a2, bfr[2], acc[mt][ns], 0, 0, 0);
      }
    }
  }
#pragma unroll
  for (int ns = 0; ns < 2; ++ns) {
    int nn = wv * 32 + ns * 16 + li;
#pragma unroll
    for (int mt = 0; mt < 3; ++mt)
#pragma unroll
      for (int r = 0; r < 4; ++r) {
        int m = mt * 16 + lq * 4 + r;
        size_t idx = ((size_t)b * DIMC + m) * NPB + n0 + nn;
        outp[idx] = x[idx] + pb[m] + acc[mt][ns][r];
      }
  }
}

// ---------------- MFMA K=96 GEMM (pout), fp8(x16) input: out = addend+bias+W@g ----
// grid (1024): n-tile 128. W scaled 1/16 at stage.
__global__ __launch_bounds__(256) void k_ek96(
    const unsigned char* __restrict__ V, const float* __restrict__ W, int wrs,
    const float* __restrict__ bias, const float* __restrict__ addend, float* __restrict__ outp) {
  __shared__ unsigned short Yl[96][130];
  __shared__ unsigned short Wl[48][104];
  int tid = threadIdx.x;
  int bt = blockIdx.x;
  int b = bt >> 9;
  int n0 = (bt & 511) * 128;
  const unsigned char* vb = V + ((size_t)b * 96) * NPB + n0;
  for (int j = tid; j < 96 * 32; j += 256) {
    int c = j >> 5, sub = j & 31;
    uchar4 u = *(const uchar4*)(vb + (size_t)c * NPB + sub * 4);
    *(ushort2*)&Yl[c][sub * 4]     = make_ushort2(f2us(fp82f(u.x)), f2us(fp82f(u.y)));
    *(ushort2*)&Yl[c][sub * 4 + 2] = make_ushort2(f2us(fp82f(u.z)), f2us(fp82f(u.w)));
  }
  if (tid < 48) {
    const float* wr = W + (size_t)tid * wrs;
    unsigned short* wl = Wl[tid];
#pragma unroll
    for (int c = 0; c < 96; ++c) wl[c] = f2us(wr[c] * 0.0625f);   // cancel x16
  }
  __syncthreads();
  int wv = tid >> 6, ln = tid & 63, lq = ln >> 4, li = ln & 15;
  short8 afr[3][3];
#pragma unroll
  for (int mt = 0; mt < 3; ++mt)
#pragma unroll
    for (int ks = 0; ks < 3; ++ks)
      afr[mt][ks] = *(const short8*)&Wl[mt * 16 + li][ks * 32 + lq * 8];
#pragma unroll 1
  for (int ns = 0; ns < 2; ++ns) {
    int nn = wv * 32 + ns * 16 + li;
    short8 bfr[3];
#pragma unroll
    for (int ks = 0; ks < 3; ++ks)
#pragma unroll
      for (int j = 0; j < 8; ++j)
        bfr[ks][j] = (short)Yl[ks * 32 + lq * 8 + j][nn];
#pragma unroll
    for (int mt = 0; mt < 3; ++mt) {
      f32x4 acc = {0.f, 0.f, 0.f, 0.f};
      acc = __builtin_amdgcn_mfma_f32_16x16x32_bf16(afr[mt][0], bfr[0], acc, 0, 0, 0);
      acc = __builtin_amdgcn_mfma_f32_16x16x32_bf16(afr[mt][1], bfr[1], acc, 0, 0, 0);
      acc = __builtin_amdgcn_mfma_f32_16x16x32_bf16(afr[mt][2], bfr[2], acc, 0, 0, 0);
#pragma unroll
      for (int r = 0; r < 4; ++r) {
        int m = mt * 16 + lq * 4 + r;
        size_t idx = ((size_t)b * DIMC + m) * NPB + n0 + nn;
        outp[idx] = acc[r] + addend[idx] + bias[m];
      }
    }
  }
}

// ------- depthwise 3x3x3 + exact GELU gate; fp8(x16) in/out; 2t x 16h tile --------
// grid (32, 96, 2).
__global__ __launch_bounds__(256) void k_dw_gelu(
    const unsigned char* __restrict__ z, const float* __restrict__ dwW,
    const float* __restrict__ dwB, unsigned char* __restrict__ g) {
  __shared__ unsigned short tile[2][4][18][66];
  int tid = threadIdx.x;
  int t0 = (blockIdx.x >> 2) * 2, h0 = (blockIdx.x & 3) * 16;
  int c = blockIdx.y, b = blockIdx.z;
  const unsigned char* z1 = z + ((size_t)b * C2 + c) * NPB;
  const unsigned char* z2 = z + ((size_t)b * C2 + c + HIDC) * NPB;
  for (int j = tid; j < 144 * 16; j += 256) {
    int r = j >> 4, sub = j & 15;
    int ch = r / 72, rem = r - ch * 72;
    int tt = rem / 18, hh = rem - tt * 18;
    int gt = t0 + tt - 1, gh = h0 + hh - 1;
    unsigned short* dp = &tile[ch][tt][hh][1 + sub * 4];
    const unsigned char* sp = ch ? z2 : z1;
    if ((unsigned)gt < 16u && (unsigned)gh < 64u) {
      uchar4 u = *(const uchar4*)(sp + gt * 4096 + gh * 64 + sub * 4);
      dp[0] = f2us(fp82f(u.x)); dp[1] = f2us(fp82f(u.y));
      dp[2] = f2us(fp82f(u.z)); dp[3] = f2us(fp82f(u.w));
    } else {
      dp[0] = 0; dp[1] = 0; dp[2] = 0; dp[3] = 0;
    }
  }
  for (int j = tid; j < 288; j += 256) {
    int r = j >> 1, side = j & 1;
    int ch = r / 72, rem = r - ch * 72;
    int tt = rem / 18, hh = rem - tt * 18;
    tile[ch][tt][hh][side ? 65 : 0] = 0;
  }
  __syncthreads();
  int w = tid & 63, hr = tid >> 6;
  float a[2][2][4];
#pragma unroll
  for (int ch = 0; ch < 2; ++ch)
#pragma unroll
    for (int t = 0; t < 2; ++t)
#pragma unroll
      for (int i = 0; i < 4; ++i) a[ch][t][i] = 0.f;
#pragma unroll
  for (int ch = 0; ch < 2; ++ch) {
    const float* wt = dwW + (size_t)(c + ch * HIDC) * 27;
#pragma unroll 1
    for (int dw = 0; dw < 3; ++dw) {
      int wwl = w + dw;
      float v[4][6];
#pragma unroll
      for (int tt = 0; tt < 4; ++tt)
#pragma unroll
        for (int r = 0; r < 6; ++r) v[tt][r] = bfr2f(tile[ch][tt][hr * 4 + r][wwl]);
#pragma unroll
      for (int dt = 0; dt < 3; ++dt)
#pragma unroll
        for (int dh = 0; dh < 3; ++dh) {
          float wv = wt[dt * 9 + dh * 3 + dw];
#pragma unroll
          for (int t = 0; t < 2; ++t)
#pragma unroll
            for (int i = 0; i < 4; ++i)
              a[ch][t][i] = fmaf(wv, v[t + dt][i + dh], a[ch][t][i]);
        }
    }
  }
  float b1 = dwB[c], b2v = dwB[c + HIDC];
  size_t obase = ((size_t)b * HIDC + c) * NPB;
#pragma unroll
  for (int t = 0; t < 2; ++t)
#pragma unroll
    for (int i = 0; i < 4; ++i) {
      float x1v = (a[0][t][i]) * 0.0625f + b1;   // inputs were x16
      float x2v = (a[1][t][i]) * 0.0625f + b2v;
      float ge = 0.5f * x1v * (1.f + erff(x1v * 0.70710678118654752f));
      g[obase + (t0 + t) * 4096 + (h0 + hr * 4 + i) * 64 + w] = f2fp8(16.f * ge * x2v);
    }
}

extern "C" void kernel_launch(void* const* d_in, const int* in_sizes, int n_in,
                              void* d_out, int out_size, void* d_ws, size_t ws_size,
                              hipStream_t stream) {
  (void)in_sizes; (void)n_in; (void)out_size; (void)ws_size;
  const float* x     = (const float*)d_in[0];
  const float* ln1w  = (const float*)d_in[1];
  const float* ln1b  = (const float*)d_in[2];
  const float* qkvw  = (const float*)d_in[3];
  const float* qkvb  = (const float*)d_in[4];
  const float* gdww  = (const float*)d_in[5];
  const float* gdwb  = (const float*)d_in[6];
  const float* temp  = (const float*)d_in[7];
  const float* projw = (const float*)d_in[8];
  const float* projb = (const float*)d_in[9];
  const float* ln2w  = (const float*)d_in[10];
  const float* ln2b  = (const float*)d_in[11];
  const float* pinw  = (const float*)d_in[12];
  const float* pinb  = (const float*)d_in[13];
  const float* dww   = (const float*)d_in[14];
  const float* dwb   = (const float*)d_in[15];
  const float* poutw = (const float*)d_in[16];
  const float* poutb = (const float*)d_in[17];
  float* out = (float*)d_out;

  // Workspace layout — peak < 75.62 MB (proven-safe region):
  char* ws = (char*)d_ws;
  bf16*  y      = (bf16*)(ws);                        // 12,582,912 B  LN output
  unsigned char* st144 = (unsigned char*)(ws + 12582912);  // 18,874,368 B [2][144][NPB] fp8
  unsigned char* qkd8  = (unsigned char*)(ws + 31457280);  // 12,582,912 B [2][96][NPB] fp8
  unsigned char* vd8   = (unsigned char*)(ws + 44040192);  // 25,165,824 B [2][192][NPB] fp8
  float* Gm     = (float*)(ws + 75497472);            //     73,728 B
  float* sq     = (float*)(ws + 75571200);            //      3,072 B
  bf16*  Mm     = (bf16*)(ws + 75574272);             //     36,864 B [2][48][192]
  // FFN phase (attention buffers dead):
  bf16*  y2     = (bf16*)(ws);                        // 12,582,912 B  LN2 output
  unsigned char* z8  = (unsigned char*)(ws + 12582912);    // 25,165,824 B [2][192][NPB] fp8
  unsigned char* gg8 = (unsigned char*)(ws + 37748736);    // 12,582,912 B [2][96][NPB] fp8

  hipMemsetAsync(Gm, 0, 73728 + 3072, stream);
  k_ln<<<dim3(512), dim3(256), 0, stream>>>(x, ln1w, ln1b, y);

  for (int h = 0; h < 4; ++h) {
    // q,k,v pointwise for head h (sections 0,1,2 -> rows s*192 + h*48), fp8 out
    k_pconv_sec<<<dim3(3, 1024), dim3(256), 0, stream>>>(
        y, qkvw + (size_t)h * 2304, 9216, qkvb + h * 48, 192, st144, 144);
    // grouped dw-conv q+k -> fp8 + sumsq
    k_gconv48<<<dim3(32, 24, 2), dim3(256), 0, stream>>>(
        st144, 144, 0, gdww, gdwb, h * 48, 144 + h * 48, qkd8, 96,
        sq, h * 48, 336 + h * 48);
    k_gram_mfma<<<dim3(64, 2), dim3(256), 0, stream>>>(qkd8, qkd8 + (size_t)48 * NPB, 96, h, Gm);
    // grouped dw-conv v -> vd8 slot [b][h*48..]
    k_gconv48<<<dim3(32, 12, 2), dim3(256), 0, stream>>>(
        st144, 144, 96, gdww, gdwb, 384 + h * 48, 384 + h * 48,
        vd8 + (size_t)h * 48 * NPB, 192, nullptr, 0, 0);
  }
  k_attn_mm<<<dim3(8), dim3(256), 0, stream>>>(Gm, sq, temp, projw, Mm);
  k_av192<<<dim3(1024), dim3(256), 0, stream>>>(vd8, Mm, projb, x, out);

  k_ln<<<dim3(512), dim3(256), 0, stream>>>(out, ln2w, ln2b, y2);
  k_pconv_sec<<<dim3(4, 1024), dim3(256), 0, stream>>>(y2, pinw, 2304, pinb, 48, z8, 192);
  k_dw_gelu<<<dim3(32, 96, 2), dim3(256), 0, stream>>>(z8, dww, dwb, gg8);
  k_ek96<<<dim3(1024), dim3(256), 0, stream>>>(gg8, poutw, 96, poutb, out, out);
}

// Round 8
// 739.719 us; speedup vs baseline: 6.1348x; 1.0701x over previous
//
#include <hip/hip_runtime.h>
#include <hip/hip_bf16.h>
#include <hip/hip_fp8.h>
#include <math.h>

typedef __hip_bfloat16 bf16;
typedef __attribute__((ext_vector_type(8))) short short8;
typedef __attribute__((ext_vector_type(4))) float f32x4;

#define NPB   65536   // positions per batch (16*64*64)
#define DIMC  48
#define C2    192
#define HIDC  96
#define TT    16

static __device__ __forceinline__ float b2f(bf16 v) { return __bfloat162float(v); }
static __device__ __forceinline__ bf16  f2b(float v) { return __float2bfloat16(v); }
static __device__ __forceinline__ unsigned short f2us(float v) {
  return __bfloat16_as_ushort(__float2bfloat16(v));
}
static __device__ __forceinline__ unsigned char f2fp8(float v) {
  __hip_fp8_e4m3 t(v); return (unsigned char)t.__x;
}
static __device__ __forceinline__ float fp82f(unsigned char u) {
  __hip_fp8_e4m3 t; t.__x = (__hip_fp8_storage_t)u; return (float)t;
}

// ---------------- y = LN(x) over 48 channels, bf16 out (LN1 and LN2) -------------
__global__ __launch_bounds__(256) void k_ln(
    const float* __restrict__ x, const float* __restrict__ lw, const float* __restrict__ lb,
    bf16* __restrict__ y) {
  int p = blockIdx.x * 256 + threadIdx.x;   // 0..131071
  int b = p >> 16, n = p & (NPB - 1);
  const float* xb = x + ((size_t)b * DIMC) * NPB + n;
  float v[DIMC]; float s = 0.f, s2 = 0.f;
#pragma unroll
  for (int c = 0; c < DIMC; ++c) { float t = xb[(size_t)c * NPB]; v[c] = t; s += t; s2 += t * t; }
  float mu = s * (1.f / DIMC);
  float var = fmaxf(s2 * (1.f / DIMC) - mu * mu, 0.f);
  float rs = rsqrtf(var + 1e-5f);
  bf16* yb = y + ((size_t)b * DIMC) * NPB + n;
#pragma unroll
  for (int c = 0; c < DIMC; ++c) yb[(size_t)c * NPB] = f2b((v[c] - mu) * rs * lw[c] + lb[c]);
}

// ------- MFMA 1x1 conv, sectioned, fp8(x16) out. grid (NSEC, 1024) ----------------
// hp >= 0: qkv head-pair mapping (sec 0..5 -> q(2hp),q(2hp+1),k0,k1,v0,v1)
// hp <  0: plain rows sec*48 (FFN pin).
__global__ __launch_bounds__(256) void k_pconv_sec(
    const bf16* __restrict__ y, const float* __restrict__ W,
    const float* __restrict__ bias, int hp, unsigned char* __restrict__ dst, int dcs) {
  __shared__ unsigned short Yl[64][130];
  __shared__ unsigned short Wl[48][72];
  int tid = threadIdx.x;
  int sec = blockIdx.x;
  int row = (hp >= 0) ? ((sec >> 1) * 192 + (2 * hp + (sec & 1)) * 48) : sec * 48;
  int bt = blockIdx.y;
  int b = bt >> 9;
  int n0 = (bt & 511) * 128;
  const unsigned short* yb = (const unsigned short*)(y + ((size_t)b * DIMC) * NPB) + n0;
  for (int j = tid; j < 48 * 32; j += 256) {       // stage Y (48 x 128)
    int c = j >> 5, sub = j & 31;
    ushort4 u = *(const ushort4*)(yb + (size_t)c * NPB + sub * 4);
    *(ushort2*)&Yl[c][sub * 4]     = make_ushort2(u.x, u.y);
    *(ushort2*)&Yl[c][sub * 4 + 2] = make_ushort2(u.z, u.w);
  }
  for (int j = tid; j < 16 * 32; j += 256) {       // zero rows 48..63
    int c = 48 + (j >> 5), sub = j & 31;
    *(ushort2*)&Yl[c][sub * 4]     = make_ushort2(0, 0);
    *(ushort2*)&Yl[c][sub * 4 + 2] = make_ushort2(0, 0);
  }
  if (tid < 48) {
    const float* wr = W + (size_t)(row + tid) * 48;
    unsigned short* wl = Wl[tid];
#pragma unroll
    for (int c = 0; c < 48; ++c) wl[c] = f2us(wr[c]);
#pragma unroll
    for (int c = 48; c < 64; ++c) wl[c] = 0;
  }
  __syncthreads();
  int wv = tid >> 6, ln = tid & 63, lq = ln >> 4, li = ln & 15;
  short8 afr[3][2];
#pragma unroll
  for (int mt = 0; mt < 3; ++mt)
#pragma unroll
    for (int ks = 0; ks < 2; ++ks)
      afr[mt][ks] = *(const short8*)&Wl[mt * 16 + li][ks * 32 + lq * 8];
#pragma unroll 1
  for (int ns = 0; ns < 2; ++ns) {
    int nn = wv * 32 + ns * 16 + li;
    short8 bfr[2];
#pragma unroll
    for (int ks = 0; ks < 2; ++ks)
#pragma unroll
      for (int j = 0; j < 8; ++j)
        bfr[ks][j] = (short)Yl[ks * 32 + lq * 8 + j][nn];
#pragma unroll
    for (int mt = 0; mt < 3; ++mt) {
      f32x4 acc = {0.f, 0.f, 0.f, 0.f};
      acc = __builtin_amdgcn_mfma_f32_16x16x32_bf16(afr[mt][0], bfr[0], acc, 0, 0, 0);
      acc = __builtin_amdgcn_mfma_f32_16x16x32_bf16(afr[mt][1], bfr[1], acc, 0, 0, 0);
#pragma unroll
      for (int r = 0; r < 4; ++r) {
        int m = mt * 16 + lq * 4 + r;
        dst[((size_t)b * dcs + sec * 48 + m) * NPB + n0 + nn] =
            f2fp8(16.f * (acc[r] + bias[row + m]));
      }
    }
  }
}

// ------- grouped 3x3x3 conv, f32-LDS, w-pair vectorized reads, fp8 in/out ---------
// grid (64, NG, 2): x = t-tile(8) x h-tile(8) [2t x 8h x 64w outputs], y = 4-ch group.
// isV=0: src st288[0..191] (q+k of head pair), sumsq; isV=1: src st288[192..287] (v).
__global__ __launch_bounds__(256) void k_gconv48(
    const unsigned char* __restrict__ src, int sco,
    const float* __restrict__ gw, const float* __restrict__ gb,
    unsigned char* __restrict__ dst, int hp, int isV, float* __restrict__ sqout) {
  __shared__ float tile[4][4][10][68];   // [ci][tt][hh][w+1]  43,520 B
  __shared__ float red[4][4];
  int tid = threadIdx.x;
  int t0 = (blockIdx.x >> 3) * 2, h0 = (blockIdx.x & 7) * 8;
  int cbase = blockIdx.y * 4, b = blockIdx.z;
  int seg = cbase / 48, lc = cbase - seg * 48;
  int gh = isV ? 384 + (2 * hp + seg) * 48 + lc
               : (seg >= 2 ? 192 : 0) + (2 * hp + (seg & 1)) * 48 + lc;
  int dch = isV ? (2 * hp + seg) * 48 + lc : cbase;   // dst channel (dcs = 192)
  const unsigned char* ib = src + ((size_t)b * 288 + sco + cbase) * NPB;
  for (int j = tid; j < 160 * 16; j += 256) {      // stage 160 rows x 16 quads, decode
    int r = j >> 4, sub = j & 15;
    int ci = r / 40, rem = r - ci * 40;
    int tt = rem / 10, hh = rem - tt * 10;
    int gt = t0 + tt - 1, gh2 = h0 + hh - 1;
    float* dp = &tile[ci][tt][hh][1 + sub * 4];
    if ((unsigned)gt < 16u && (unsigned)gh2 < 64u) {
      uchar4 u = *(const uchar4*)(ib + (size_t)ci * NPB + gt * 4096 + gh2 * 64 + sub * 4);
      dp[0] = fp82f(u.x); dp[1] = fp82f(u.y); dp[2] = fp82f(u.z); dp[3] = fp82f(u.w);
    } else { dp[0] = 0.f; dp[1] = 0.f; dp[2] = 0.f; dp[3] = 0.f; }
  }
  for (int j = tid; j < 320; j += 256) {           // w halos
    int r = j >> 1, side = j & 1;
    int ci = r / 40, rem = r - ci * 40;
    int tt = rem / 10, hh = rem - tt * 10;
    tile[ci][tt][hh][side ? 65 : 0] = 0.f;
  }
  __syncthreads();
  int wp = tid & 31, hq = tid >> 5;                // w0 = 2wp; h row = h0+hq
  int w0 = wp * 2;
  float acc[2][2][4];                              // [t][u][oc]
#pragma unroll
  for (int t = 0; t < 2; ++t)
#pragma unroll
    for (int u = 0; u < 2; ++u)
#pragma unroll
      for (int o = 0; o < 4; ++o) acc[t][u][o] = 0.f;
#pragma unroll 1
  for (int ci = 0; ci < 4; ++ci) {
    float v[4][3][4];
    const float* base = &tile[ci][0][hq][w0];      // window cols w0..w0+3 = w0-1..w0+2
#pragma unroll
    for (int tt = 0; tt < 4; ++tt)
#pragma unroll
      for (int rr = 0; rr < 3; ++rr) {
        *(float2*)&v[tt][rr][0] = *(const float2*)(base + (tt * 10 + rr) * 68);
        *(float2*)&v[tt][rr][2] = *(const float2*)(base + (tt * 10 + rr) * 68 + 2);
      }
#pragma unroll
    for (int dt = 0; dt < 3; ++dt)
#pragma unroll
      for (int dh = 0; dh < 3; ++dh)
#pragma unroll
        for (int dw = 0; dw < 3; ++dw) {
          float wv[4];
#pragma unroll
          for (int o = 0; o < 4; ++o)
            wv[o] = gw[(size_t)(gh + o) * 108 + ci * 27 + dt * 9 + dh * 3 + dw];
#pragma unroll
          for (int t = 0; t < 2; ++t)
#pragma unroll
            for (int u = 0; u < 2; ++u) {
              float val = v[t + dt][dh][u + dw];
#pragma unroll
              for (int o = 0; o < 4; ++o) acc[t][u][o] = fmaf(wv[o], val, acc[t][u][o]);
            }
        }
  }
  float s[4] = {0.f, 0.f, 0.f, 0.f};
#pragma unroll
  for (int o = 0; o < 4; ++o) {
    float bias16 = 16.f * gb[gh + o];
    size_t obase = ((size_t)b * 192 + dch + o) * NPB;
#pragma unroll
    for (int t = 0; t < 2; ++t) {
      unsigned char c0 = f2fp8(acc[t][0][o] + bias16);
      unsigned char c1 = f2fp8(acc[t][1][o] + bias16);
      uchar2 st; st.x = c0; st.y = c1;
      *(uchar2*)&dst[obase + (t0 + t) * 4096 + (h0 + hq) * 64 + w0] = st;
      if (sqout) {
        float f0 = fp82f(c0), f1 = fp82f(c1);
        s[o] = fmaf(f0, f0, s[o]); s[o] = fmaf(f1, f1, s[o]);
      }
    }
  }
  if (sqout) {
#pragma unroll
    for (int o = 0; o < 4; ++o) {
      float sv = s[o];
#pragma unroll
      for (int off = 32; off; off >>= 1) sv += __shfl_down(sv, off);
      if ((tid & 63) == 0) red[tid >> 6][o] = sv;
    }
    __syncthreads();
    if (tid < 4) {
      int sqi = (seg < 2 ? 0 : 384) + b * 192 + (2 * hp + (seg & 1)) * 48 + lc + tid;
      atomicAdd(&sqout[sqi], red[0][tid] + red[1][tid] + red[2][tid] + red[3][tid]);
    }
  }
}

// ---------------- MFMA Gram from fp8 q,k (x16): scale cancels with norms ----------
// grid (64, 2, 2): x = 1024-wide n-chunk, y = batch, z = head-in-pair.
__global__ __launch_bounds__(256) void k_gram_mfma(
    const unsigned char* __restrict__ qkd, int hp, float* __restrict__ Gm) {
  __shared__ unsigned short qkl[2][48][264];
  int tid = threadIdx.x, b = blockIdx.y, z = blockIdx.z;
  int wv = tid >> 6, ln = tid & 63, lq = ln >> 4, li = ln & 15;
  const unsigned char* qb = qkd + ((size_t)b * 192 + z * 48) * NPB + blockIdx.x * 1024;
  const unsigned char* kb = qkd + ((size_t)b * 192 + 96 + z * 48) * NPB + blockIdx.x * 1024;
  f32x4 acc[9];
#pragma unroll
  for (int t = 0; t < 9; ++t) acc[t] = (f32x4){0.f, 0.f, 0.f, 0.f};
#pragma unroll 1
  for (int it = 0; it < 4; ++it) {
    __syncthreads();
    for (int j = tid; j < 48 * 64; j += 256) {
      int c = j >> 6, sub = j & 63;
      uchar4 uq = *(const uchar4*)(qb + (size_t)c * NPB + it * 256 + sub * 4);
      uchar4 uk = *(const uchar4*)(kb + (size_t)c * NPB + it * 256 + sub * 4);
      *(ushort2*)&qkl[0][c][sub * 4]     = make_ushort2(f2us(fp82f(uq.x)), f2us(fp82f(uq.y)));
      *(ushort2*)&qkl[0][c][sub * 4 + 2] = make_ushort2(f2us(fp82f(uq.z)), f2us(fp82f(uq.w)));
      *(ushort2*)&qkl[1][c][sub * 4]     = make_ushort2(f2us(fp82f(uk.x)), f2us(fp82f(uk.y)));
      *(ushort2*)&qkl[1][c][sub * 4 + 2] = make_ushort2(f2us(fp82f(uk.z)), f2us(fp82f(uk.w)));
    }
    __syncthreads();
    short8 afr[3][2], bfr[3][2];
#pragma unroll
    for (int ks = 0; ks < 2; ++ks) {
      int kbase = wv * 64 + ks * 32 + lq * 8;
#pragma unroll
      for (int t = 0; t < 3; ++t) {
        afr[t][ks] = *(const short8*)&qkl[0][t * 16 + li][kbase];
        bfr[t][ks] = *(const short8*)&qkl[1][t * 16 + li][kbase];
      }
    }
#pragma unroll
    for (int mt = 0; mt < 3; ++mt)
#pragma unroll
      for (int nt = 0; nt < 3; ++nt) {
        acc[mt * 3 + nt] = __builtin_amdgcn_mfma_f32_16x16x32_bf16(afr[mt][0], bfr[nt][0], acc[mt * 3 + nt], 0, 0, 0);
        acc[mt * 3 + nt] = __builtin_amdgcn_mfma_f32_16x16x32_bf16(afr[mt][1], bfr[nt][1], acc[mt * 3 + nt], 0, 0, 0);
      }
  }
  __syncthreads();
  float* red = (float*)&qkl[0][0][0];
  if (wv > 0) {
    float* rw = red + (size_t)(wv - 1) * 2304;
#pragma unroll
    for (int t = 0; t < 9; ++t)
#pragma unroll
      for (int r = 0; r < 4; ++r)
        rw[t * 256 + r * 64 + ln] = acc[t][r];
  }
  __syncthreads();
  if (wv == 0) {
    int hd = 2 * hp + z;
    float* gbase = Gm + (size_t)(b * 4 + hd) * 2304;
#pragma unroll
    for (int t = 0; t < 9; ++t) {
      int mt = t / 3, nt = t - mt * 3;
#pragma unroll
      for (int r = 0; r < 4; ++r) {
        int o = t * 256 + r * 64 + ln;
        float v = acc[t][r] + red[o] + red[2304 + o] + red[4608 + o];
        atomicAdd(&gbase[(mt * 16 + lq * 4 + r) * 48 + nt * 16 + li], v);
      }
    }
  }
}

// ------- tiny: per-(b,head) softmax(norm G) + proj fold -> Mm[b][48][192] bf16 ----
__global__ __launch_bounds__(256) void k_attn_mm(
    const float* __restrict__ Gm, const float* __restrict__ sq, const float* __restrict__ temp,
    const float* __restrict__ pw, bf16* __restrict__ Mm) {
  __shared__ float A[48][48];
  __shared__ float nk[48];
  int tid = threadIdx.x;
  int bh = blockIdx.x; int b = bh >> 2, hd = bh & 3;
  if (tid >= 64 && tid < 112)
    nk[tid - 64] = fmaxf(sqrtf(sq[384 + bh * 48 + tid - 64]), 1e-12f);
  __syncthreads();
  if (tid < 48) {
    float tv = temp[hd];
    float rq = 1.f / fmaxf(sqrtf(sq[bh * 48 + tid]), 1e-12f);
    const float* grow = Gm + (size_t)bh * 2304 + tid * 48;
    float mx = -1e30f;
#pragma unroll
    for (int d = 0; d < 48; ++d) mx = fmaxf(mx, grow[d] * rq / nk[d] * tv);
    float sum = 0.f;
#pragma unroll
    for (int d = 0; d < 48; ++d) {
      float e = expf(grow[d] * rq / nk[d] * tv - mx);
      A[tid][d] = e; sum += e;
    }
    float inv = 1.f / sum;
#pragma unroll
    for (int d = 0; d < 48; ++d) A[tid][d] *= inv;
  }
  __syncthreads();
  for (int j = tid; j < 2304; j += 256) {
    int m = j / 48, d = j - m * 48;
    float a = 0.f;
#pragma unroll
    for (int c = 0; c < 48; ++c) a = fmaf(pw[m * 192 + hd * 48 + c], A[c][d], a);
    Mm[((size_t)b * 48 + m) * 192 + hd * 48 + d] = f2b(a * 0.0625f);
  }
}

// ------- K=192 GEMM: out = x + pb + Mm[b] @ v8[b]  (fp8 v, bf16 MFMA) -------------
__global__ __launch_bounds__(256) void k_av192(
    const unsigned char* __restrict__ vd8, const bf16* __restrict__ Mm,
    const float* __restrict__ pb, const float* __restrict__ x, float* __restrict__ outp) {
  __shared__ unsigned short Yl[96][130];
  __shared__ unsigned short Ml[48][200];
  int tid = threadIdx.x;
  int bt = blockIdx.x;
  int b = bt >> 9;
  int n0 = (bt & 511) * 128;
  int wv = tid >> 6, ln = tid & 63, lq = ln >> 4, li = ln & 15;
  const unsigned short* mb = (const unsigned short*)(Mm + (size_t)b * 48 * 192);
  for (int j = tid; j < 48 * 48; j += 256) {       // stage M (48 x 192)
    int m = j / 48, c4 = j - m * 48;
    *(ushort4*)&Ml[m][c4 * 4] = *(const ushort4*)(mb + m * 192 + c4 * 4);
  }
  const unsigned char* vb = vd8 + ((size_t)b * C2) * NPB + n0;
  f32x4 acc[3][2];
#pragma unroll
  for (int mt = 0; mt < 3; ++mt)
#pragma unroll
    for (int ns = 0; ns < 2; ++ns) acc[mt][ns] = (f32x4){0.f, 0.f, 0.f, 0.f};
#pragma unroll 1
  for (int s = 0; s < 2; ++s) {
    __syncthreads();
    for (int j = tid; j < 96 * 32; j += 256) {     // stage V half (96 x 128), decode
      int c = j >> 5, sub = j & 31;
      uchar4 u = *(const uchar4*)(vb + (size_t)(s * 96 + c) * NPB + sub * 4);
      *(ushort2*)&Yl[c][sub * 4]     = make_ushort2(f2us(fp82f(u.x)), f2us(fp82f(u.y)));
      *(ushort2*)&Yl[c][sub * 4 + 2] = make_ushort2(f2us(fp82f(u.z)), f2us(fp82f(u.w)));
    }
    __syncthreads();
#pragma unroll 1
    for (int ns = 0; ns < 2; ++ns) {
      int nn = wv * 32 + ns * 16 + li;
      short8 bfr[3];
#pragma unroll
      for (int ks = 0; ks < 3; ++ks)
#pragma unroll
        for (int j = 0; j < 8; ++j)
          bfr[ks][j] = (short)Yl[ks * 32 + lq * 8 + j][nn];
#pragma unroll
      for (int mt = 0; mt < 3; ++mt) {
        short8 a0 = *(const short8*)&Ml[mt * 16 + li][s * 96 + lq * 8];
        short8 a1 = *(const short8*)&Ml[mt * 16 + li][s * 96 + 32 + lq * 8];
        short8 a2 = *(const short8*)&Ml[mt * 16 + li][s * 96 + 64 + lq * 8];
        acc[mt][ns] = __builtin_amdgcn_mfma_f32_16x16x32_bf16(a0, bfr[0], acc[mt][ns], 0, 0, 0);
        acc[mt][ns] = __builtin_amdgcn_mfma_f32_16x16x32_bf16(a1, bfr[1], acc[mt][ns], 0, 0, 0);
        acc[mt][ns] = __builtin_amdgcn_mfma_f32_16x16x32_bf16(a2, bfr[2], acc[mt][ns], 0, 0, 0);
      }
    }
  }
#pragma unroll
  for (int ns = 0; ns < 2; ++ns) {
    int nn = wv * 32 + ns * 16 + li;
#pragma unroll
    for (int mt = 0; mt < 3; ++mt)
#pragma unroll
      for (int r = 0; r < 4; ++r) {
        int m = mt * 16 + lq * 4 + r;
        size_t idx = ((size_t)b * DIMC + m) * NPB + n0 + nn;
        outp[idx] = x[idx] + pb[m] + acc[mt][ns][r];
      }
  }
}

// ---------------- MFMA K=96 GEMM (pout), fp8(x16) input: out = addend+bias+W@g ----
__global__ __launch_bounds__(256) void k_ek96(
    const unsigned char* __restrict__ V, const float* __restrict__ W, int wrs,
    const float* __restrict__ bias, const float* __restrict__ addend, float* __restrict__ outp) {
  __shared__ unsigned short Yl[96][130];
  __shared__ unsigned short Wl[48][104];
  int tid = threadIdx.x;
  int bt = blockIdx.x;
  int b = bt >> 9;
  int n0 = (bt & 511) * 128;
  const unsigned char* vb = V + ((size_t)b * 96) * NPB + n0;
  for (int j = tid; j < 96 * 32; j += 256) {
    int c = j >> 5, sub = j & 31;
    uchar4 u = *(const uchar4*)(vb + (size_t)c * NPB + sub * 4);
    *(ushort2*)&Yl[c][sub * 4]     = make_ushort2(f2us(fp82f(u.x)), f2us(fp82f(u.y)));
    *(ushort2*)&Yl[c][sub * 4 + 2] = make_ushort2(f2us(fp82f(u.z)), f2us(fp82f(u.w)));
  }
  if (tid < 48) {
    const float* wr = W + (size_t)tid * wrs;
    unsigned short* wl = Wl[tid];
#pragma unroll
    for (int c = 0; c < 96; ++c) wl[c] = f2us(wr[c] * 0.0625f);   // cancel x16
  }
  __syncthreads();
  int wv = tid >> 6, ln = tid & 63, lq = ln >> 4, li = ln & 15;
  short8 afr[3][3];
#pragma unroll
  for (int mt = 0; mt < 3; ++mt)
#pragma unroll
    for (int ks = 0; ks < 3; ++ks)
      afr[mt][ks] = *(const short8*)&Wl[mt * 16 + li][ks * 32 + lq * 8];
#pragma unroll 1
  for (int ns = 0; ns < 2; ++ns) {
    int nn = wv * 32 + ns * 16 + li;
    short8 bfr[3];
#pragma unroll
    for (int ks = 0; ks < 3; ++ks)
#pragma unroll
      for (int j = 0; j < 8; ++j)
        bfr[ks][j] = (short)Yl[ks * 32 + lq * 8 + j][nn];
#pragma unroll
    for (int mt = 0; mt < 3; ++mt) {
      f32x4 acc = {0.f, 0.f, 0.f, 0.f};
      acc = __builtin_amdgcn_mfma_f32_16x16x32_bf16(afr[mt][0], bfr[0], acc, 0, 0, 0);
      acc = __builtin_amdgcn_mfma_f32_16x16x32_bf16(afr[mt][1], bfr[1], acc, 0, 0, 0);
      acc = __builtin_amdgcn_mfma_f32_16x16x32_bf16(afr[mt][2], bfr[2], acc, 0, 0, 0);
#pragma unroll
      for (int r = 0; r < 4; ++r) {
        int m = mt * 16 + lq * 4 + r;
        size_t idx = ((size_t)b * DIMC + m) * NPB + n0 + nn;
        outp[idx] = acc[r] + addend[idx] + bias[m];
      }
    }
  }
}

// ------- depthwise 3x3x3 + GELU gate; f32-LDS, w-pair reads; fp8(x16) in/out ------
// grid (32, 96, 2): x = t-tile(8) x h-tile(4) [2t x 16h x 64w], y = ch pair.
__global__ __launch_bounds__(256) void k_dw_gelu(
    const unsigned char* __restrict__ z, const float* __restrict__ dwW,
    const float* __restrict__ dwB, unsigned char* __restrict__ g) {
  __shared__ float tile[2][4][18][68];   // 39,168 B
  int tid = threadIdx.x;
  int t0 = (blockIdx.x >> 2) * 2, h0 = (blockIdx.x & 3) * 16;
  int c = blockIdx.y, b = blockIdx.z;
  const unsigned char* z1 = z + ((size_t)b * C2 + c) * NPB;
  const unsigned char* z2 = z + ((size_t)b * C2 + c + HIDC) * NPB;
  for (int j = tid; j < 144 * 16; j += 256) {
    int r = j >> 4, sub = j & 15;
    int ch = r / 72, rem = r - ch * 72;
    int tt = rem / 18, hh = rem - tt * 18;
    int gt = t0 + tt - 1, gh = h0 + hh - 1;
    float* dp = &tile[ch][tt][hh][1 + sub * 4];
    const unsigned char* sp = ch ? z2 : z1;
    if ((unsigned)gt < 16u && (unsigned)gh < 64u) {
      uchar4 u = *(const uchar4*)(sp + gt * 4096 + gh * 64 + sub * 4);
      dp[0] = fp82f(u.x); dp[1] = fp82f(u.y); dp[2] = fp82f(u.z); dp[3] = fp82f(u.w);
    } else { dp[0] = 0.f; dp[1] = 0.f; dp[2] = 0.f; dp[3] = 0.f; }
  }
  for (int j = tid; j < 288; j += 256) {
    int r = j >> 1, side = j & 1;
    int ch = r / 72, rem = r - ch * 72;
    int tt = rem / 18, hh = rem - tt * 18;
    tile[ch][tt][hh][side ? 65 : 0] = 0.f;
  }
  __syncthreads();
  int wp = tid & 31, hq = tid >> 5;      // w0 = 2wp; h rows {h0+2hq, h0+2hq+1}
  int w0 = wp * 2;
  float a[2][2][2][2];                   // [ch][t][i][u]
#pragma unroll
  for (int ch = 0; ch < 2; ++ch)
#pragma unroll
    for (int t = 0; t < 2; ++t)
#pragma unroll
      for (int i = 0; i < 2; ++i) { a[ch][t][i][0] = 0.f; a[ch][t][i][1] = 0.f; }
#pragma unroll 1
  for (int ch = 0; ch < 2; ++ch) {
    float v[4][4][4];
    const float* base = &tile[ch][0][2 * hq][w0];
#pragma unroll
    for (int tt = 0; tt < 4; ++tt)
#pragma unroll
      for (int rr = 0; rr < 4; ++rr) {
        *(float2*)&v[tt][rr][0] = *(const float2*)(base + (tt * 18 + rr) * 68);
        *(float2*)&v[tt][rr][2] = *(const float2*)(base + (tt * 18 + rr) * 68 + 2);
      }
    const float* wt = dwW + (size_t)(c + ch * HIDC) * 27;
#pragma unroll
    for (int dt = 0; dt < 3; ++dt)
#pragma unroll
      for (int dh = 0; dh < 3; ++dh)
#pragma unroll
        for (int dw = 0; dw < 3; ++dw) {
          float wv = wt[dt * 9 + dh * 3 + dw];
#pragma unroll
          for (int t = 0; t < 2; ++t)
#pragma unroll
            for (int i = 0; i < 2; ++i) {
              a[ch][t][i][0] = fmaf(wv, v[t + dt][i + dh][dw], a[ch][t][i][0]);
              a[ch][t][i][1] = fmaf(wv, v[t + dt][i + dh][1 + dw], a[ch][t][i][1]);
            }
        }
  }
  float b1 = dwB[c], b2v = dwB[c + HIDC];
  size_t obase = ((size_t)b * HIDC + c) * NPB;
#pragma unroll
  for (int t = 0; t < 2; ++t)
#pragma unroll
    for (int i = 0; i < 2; ++i) {
      uchar2 st;
#pragma unroll
      for (int u = 0; u < 2; ++u) {
        float x1v = a[0][t][i][u] * 0.0625f + b1;
        float x2v = a[1][t][i][u] * 0.0625f + b2v;
        float ge = 0.5f * x1v * (1.f + erff(x1v * 0.70710678118654752f));
        unsigned char r = f2fp8(16.f * ge * x2v);
        if (u == 0) st.x = r; else st.y = r;
      }
      *(uchar2*)&g[obase + (t0 + t) * 4096 + (h0 + 2 * hq + i) * 64 + w0] = st;
    }
}

extern "C" void kernel_launch(void* const* d_in, const int* in_sizes, int n_in,
                              void* d_out, int out_size, void* d_ws, size_t ws_size,
                              hipStream_t stream) {
  (void)in_sizes; (void)n_in; (void)out_size; (void)ws_size;
  const float* x     = (const float*)d_in[0];
  const float* ln1w  = (const float*)d_in[1];
  const float* ln1b  = (const float*)d_in[2];
  const float* qkvw  = (const float*)d_in[3];
  const float* qkvb  = (const float*)d_in[4];
  const float* gdww  = (const float*)d_in[5];
  const float* gdwb  = (const float*)d_in[6];
  const float* temp  = (const float*)d_in[7];
  const float* projw = (const float*)d_in[8];
  const float* projb = (const float*)d_in[9];
  const float* ln2w  = (const float*)d_in[10];
  const float* ln2b  = (const float*)d_in[11];
  const float* pinw  = (const float*)d_in[12];
  const float* pinb  = (const float*)d_in[13];
  const float* dww   = (const float*)d_in[14];
  const float* dwb   = (const float*)d_in[15];
  const float* poutw = (const float*)d_in[16];
  const float* poutb = (const float*)d_in[17];
  float* out = (float*)d_out;

  // Workspace: y 12.6M | st288 37.7M | vd8 25.2M | Gm/sq/Mm tail -> 75.61M (< proven 75.65M)
  // qkd8 lives in d_out (exactly 25,165,824 B), dead before k_av192 writes out.
  char* ws = (char*)d_ws;
  bf16*  y     = (bf16*)(ws);                              // 12,582,912 B
  unsigned char* st288 = (unsigned char*)(ws + 12582912);  // 37,748,736 B [2][288][NPB]
  unsigned char* vd8   = (unsigned char*)(ws + 50331648);  // 25,165,824 B [2][192][NPB]
  float* Gm    = (float*)(ws + 75497472);                  //     73,728 B
  float* sq    = (float*)(ws + 75571200);                  //      3,072 B
  bf16*  Mm    = (bf16*)(ws + 75574272);                   //     36,864 B
  unsigned char* qkd8 = (unsigned char*)d_out;             // 25,165,824 B (scratch)
  // FFN phase (attention buffers dead):
  bf16*  y2    = (bf16*)(ws);                              // 12,582,912 B
  unsigned char* z8  = (unsigned char*)(ws + 12582912);    // 25,165,824 B
  unsigned char* gg8 = (unsigned char*)(ws + 37748736);    // 12,582,912 B

  hipMemsetAsync(Gm, 0, 73728 + 3072, stream);
  k_ln<<<dim3(512), dim3(256), 0, stream>>>(x, ln1w, ln1b, y);

  for (int hp = 0; hp < 2; ++hp) {
    // q,k,v pointwise for head pair (6 sections), fp8 out -> st288
    k_pconv_sec<<<dim3(6, 1024), dim3(256), 0, stream>>>(y, qkvw, qkvb, hp, st288, 288);
    // grouped dw-conv q+k (192 ch) -> qkd8 (in d_out) + sumsq
    k_gconv48<<<dim3(64, 48, 2), dim3(256), 0, stream>>>(
        st288, 0, gdww, gdwb, qkd8, hp, 0, sq);
    // Gram for both heads of the pair
    k_gram_mfma<<<dim3(64, 2, 2), dim3(256), 0, stream>>>(qkd8, hp, Gm);
    // grouped dw-conv v (96 ch) -> vd8 slots
    k_gconv48<<<dim3(64, 24, 2), dim3(256), 0, stream>>>(
        st288, 192, gdww, gdwb, vd8, hp, 1, nullptr);
  }
  k_attn_mm<<<dim3(8), dim3(256), 0, stream>>>(Gm, sq, temp, projw, Mm);
  k_av192<<<dim3(1024), dim3(256), 0, stream>>>(vd8, Mm, projb, x, out);

  k_ln<<<dim3(512), dim3(256), 0, stream>>>(out, ln2w, ln2b, y2);
  k_pconv_sec<<<dim3(4, 1024), dim3(256), 0, stream>>>(y2, pinw, pinb, -1, z8, 192);
  k_dw_gelu<<<dim3(32, 96, 2), dim3(256), 0, stream>>>(z8, dww, dwb, gg8);
  k_ek96<<<dim3(1024), dim3(256), 0, stream>>>(gg8, poutw, 96, poutb, out, out);
}